// Round 6
// baseline (755.588 us; speedup 1.0000x reference)
//
#include <hip/hip_runtime.h>
#include <hip/hip_bf16.h>

typedef __bf16 bf16_t;
typedef __bf16 bf16x8 __attribute__((ext_vector_type(8)));
typedef __bf16 bf16x4 __attribute__((ext_vector_type(4)));
typedef float  f32x4  __attribute__((ext_vector_type(4)));

static constexpr int N_NODES = 100000;
static constexpr int N_EDGES = 300000;
static constexpr int N_GRAPH = 4096;
static constexpr int H  = 256;
static constexpr int ND = 64;
static constexpr int ZIC = 128;
static constexpr int NE = 8;
static constexpr int SCAN_B = 1024;

__device__ __forceinline__ int clampi(int v, int lo, int hi) {
  return v < lo ? lo : (v > hi ? hi : v);
}

// async 16B global -> LDS (wave-uniform LDS base + lane*16)
__device__ __forceinline__ void dma16(const bf16_t* g, bf16_t* lds_base) {
  __builtin_amdgcn_global_load_lds(
      (const __attribute__((address_space(1))) void*)g,
      (__attribute__((address_space(3))) void*)lds_base, 16, 0, 0);
}

// ------- graph segment starts (batch sorted) + zero counts/cursor --------
__global__ void compute_starts_kernel(const int* __restrict__ batch,
                                      int* __restrict__ starts,
                                      int* __restrict__ counts,
                                      int* __restrict__ cursor, int N, int G) {
  int i = blockIdx.x * blockDim.x + threadIdx.x;
  if (i >= N) return;
  counts[i] = 0;
  cursor[i] = 0;
  int b = clampi(batch[i], 0, G - 1);
  if (i == 0) {
    for (int g = 0; g <= b; ++g) starts[g] = 0;
  } else {
    int p = clampi(batch[i - 1], 0, G - 1);
    for (int g = p + 1; g <= b; ++g) starts[g] = i;
  }
  if (i == N - 1) {
    for (int g = b + 1; g <= G; ++g) starts[g] = N;
  }
}

// ---------------- CSR build ----------------
__global__ void count_deg_kernel(const int* __restrict__ dst, int* __restrict__ counts, int E, int N) {
  int e = blockIdx.x * blockDim.x + threadIdx.x;
  if (e < E) atomicAdd(&counts[clampi(dst[e], 0, N - 1)], 1);
}

__global__ __launch_bounds__(SCAN_B) void scan1_kernel(const int* __restrict__ counts,
                                                       int* __restrict__ offs,
                                                       int* __restrict__ bsum, int N) {
  __shared__ int tmp[SCAN_B];
  int i = blockIdx.x * SCAN_B + threadIdx.x;
  int v = (i < N) ? counts[i] : 0;
  tmp[threadIdx.x] = v;
  __syncthreads();
  for (int d = 1; d < SCAN_B; d <<= 1) {
    int t = (threadIdx.x >= d) ? tmp[threadIdx.x - d] : 0;
    __syncthreads();
    tmp[threadIdx.x] += t;
    __syncthreads();
  }
  if (i < N) offs[i + 1] = tmp[threadIdx.x];
  if (threadIdx.x == SCAN_B - 1) bsum[blockIdx.x] = tmp[SCAN_B - 1];
  if (i == 0) offs[0] = 0;
}

__global__ void scan2_kernel(int* __restrict__ bsum, int nblk) {
  if (blockIdx.x == 0 && threadIdx.x == 0) {
    int run = 0;
    for (int b = 0; b < nblk; ++b) { int v = bsum[b]; bsum[b] = run; run += v; }
  }
}

__global__ __launch_bounds__(SCAN_B) void scan3_kernel(int* __restrict__ offs,
                                                       const int* __restrict__ bsum, int N) {
  int i = blockIdx.x * SCAN_B + threadIdx.x;
  if (i < N) offs[i + 1] += bsum[blockIdx.x];
}

// fused: compute position AND scatter src_sorted + eattr(bf16) in one pass
__global__ void fill_scatter_kernel(const int* __restrict__ src, const int* __restrict__ dst,
                                    const float* __restrict__ eattr,
                                    const int* __restrict__ offs, int* __restrict__ cursor,
                                    int* __restrict__ src_srt, bf16_t* __restrict__ eat16,
                                    int E, int N) {
  int e = blockIdx.x * blockDim.x + threadIdx.x;
  if (e >= E) return;
  int d = clampi(dst[e], 0, N - 1);
  int pos = offs[d] + atomicAdd(&cursor[d], 1);
  if ((unsigned)pos >= (unsigned)E) return;
  int s = src[e];
  src_srt[pos] = ((unsigned)s < (unsigned)N_NODES) ? s : 0;
  const float* ea = eattr + (size_t)e * 16;
  union { bf16_t b[16]; uint4 u[2]; } pk;
#pragma unroll
  for (int k = 0; k < 16; ++k) pk.b[k] = (bf16_t)ea[k];
  uint4* dst16 = (uint4*)(eat16 + ((size_t)pos << 4));
  dst16[0] = pk.u[0];
  dst16[1] = pk.u[1];
}

// edge_W[l] (16 x 256) -> eWt[l] (256 rows x 16 cols), bf16  (v6 layout)
__global__ void build_ewt16_kernel(const float* __restrict__ edge_W,
                                   bf16_t* __restrict__ ewt) {
  int idx = blockIdx.x * blockDim.x + threadIdx.x;
  if (idx >= 3 * 256 * 16) return;
  int l = idx / (256 * 16);
  int rem = idx - l * 256 * 16;
  int n = rem >> 4, k = rem & 15;
  ewt[idx] = (bf16_t)edge_W[(size_t)l * 16 * 256 + k * 256 + n];
}

// -------- fp32 transpose + bf16 cast: W[K x Nc] -> Wt[Nc x K] (bf16) ------
__global__ void transpose_kernel(const float* __restrict__ W,
                                 bf16_t* __restrict__ Wt, int K, int Nc,
                                 size_t srcStride, size_t dstStride) {
  __shared__ float tile[32][33];
  const float* Wz = W + (size_t)blockIdx.z * srcStride;
  bf16_t* Wtz = Wt + (size_t)blockIdx.z * dstStride;
  int n0 = blockIdx.x * 32, k0 = blockIdx.y * 32;
  int tx = threadIdx.x, ty = threadIdx.y;
  for (int i = ty; i < 32; i += 8)
    tile[i][tx] = Wz[(size_t)(k0 + i) * Nc + n0 + tx];
  __syncthreads();
  for (int i = ty; i < 32; i += 8)
    Wtz[(size_t)(n0 + i) * K + k0 + tx] = (bf16_t)tile[tx][i];
}

// same, but output row nibble-permuted: channel n stored at row
// s = ((n&15)<<4)|(n>>4)  (involution; requires Nc==256). Used for mlp_W1
// so the fused-MLP kernel's per-thread nt-outputs are channel-consecutive.
__global__ void transpose_perm_kernel(const float* __restrict__ W,
                                      bf16_t* __restrict__ Wt, int K,
                                      size_t srcStride, size_t dstStride) {
  __shared__ float tile[32][33];
  const float* Wz = W + (size_t)blockIdx.z * srcStride;
  bf16_t* Wtz = Wt + (size_t)blockIdx.z * dstStride;
  int n0 = blockIdx.x * 32, k0 = blockIdx.y * 32;
  int tx = threadIdx.x, ty = threadIdx.y;
  for (int i = ty; i < 32; i += 8)
    tile[i][tx] = Wz[(size_t)(k0 + i) * 256 + n0 + tx];
  __syncthreads();
  for (int i = ty; i < 32; i += 8) {
    int n = n0 + i;
    int s = ((n & 15) << 4) | (n >> 4);
    Wtz[(size_t)s * K + k0 + tx] = (bf16_t)tile[tx][i];
  }
}

// ---- staging loaders: 8 contiguous elements -> 8 bf16 (16B) in LDS ----
__device__ __forceinline__ void load8_to_lds(const bf16_t* p, bool valid, uint4* dst) {
  uint4 v = make_uint4(0u, 0u, 0u, 0u);
  if (valid) v = *(const uint4*)p;
  *dst = v;
}
__device__ __forceinline__ void load8_to_lds(const float* p, bool valid, uint4* dst) {
  float4 f0 = make_float4(0.f, 0.f, 0.f, 0.f), f1 = f0;
  if (valid) { f0 = *(const float4*)p; f1 = *(const float4*)(p + 4); }
  union { bf16_t b[8]; uint4 u; } pk;
  pk.b[0] = (bf16_t)f0.x; pk.b[1] = (bf16_t)f0.y;
  pk.b[2] = (bf16_t)f0.z; pk.b[3] = (bf16_t)f0.w;
  pk.b[4] = (bf16_t)f1.x; pk.b[5] = (bf16_t)f1.y;
  pk.b[6] = (bf16_t)f1.z; pk.b[7] = (bf16_t)f1.w;
  *dst = pk.u;
}

// ---------------- MFMA GEMM 128x128 (VGPR staging; fp32 or bf16 in) ------
template<int K, bool RELU, bool OUTF32, typename TIN>
__global__ __launch_bounds__(256) void gemm128_kernel(
    const TIN* __restrict__ U, const bf16_t* __restrict__ Wt,
    const float* __restrict__ bias, void* __restrict__ Out, int M, int Nc) {
  constexpr int LDT = 72;
  __shared__ bf16_t Ut[128 * LDT];
  __shared__ bf16_t Wl[128 * LDT];
  const int m0 = blockIdx.x * 128;
  const int n0 = blockIdx.y * 128;
  const int t = threadIdx.x;
  const int lane = t & 63;
  const int wave = t >> 6;
  const int wm = (wave >> 1) * 64;
  const int wn = (wave & 1) * 64;
  const int srow = t >> 1;
  const int sk = (t & 1) * 32;
  const int lr = lane & 15;
  const int lq = lane >> 4;
  const bool aok = (m0 + srow) < M;
  f32x4 acc[4][4] = {};

  for (int k0 = 0; k0 < K; k0 += 64) {
    const TIN* up = U + (size_t)(m0 + srow) * K + k0 + sk;
    const bf16_t* wp = Wt + (size_t)(n0 + srow) * K + k0 + sk;
#pragma unroll
    for (int q = 0; q < 4; ++q) {
      load8_to_lds(up + q * 8, aok, (uint4*)&Ut[srow * LDT + sk + q * 8]);
      load8_to_lds(wp + q * 8, true, (uint4*)&Wl[srow * LDT + sk + q * 8]);
    }
    __syncthreads();
#pragma unroll
    for (int s = 0; s < 2; ++s) {
      bf16x8 a[4], b[4];
#pragma unroll
      for (int mt = 0; mt < 4; ++mt)
        a[mt] = *(const bf16x8*)(&Ut[(wm + mt * 16 + lr) * LDT + s * 32 + lq * 8]);
#pragma unroll
      for (int nt = 0; nt < 4; ++nt)
        b[nt] = *(const bf16x8*)(&Wl[(wn + nt * 16 + lr) * LDT + s * 32 + lq * 8]);
#pragma unroll
      for (int mt = 0; mt < 4; ++mt)
#pragma unroll
        for (int nt = 0; nt < 4; ++nt)
          acc[mt][nt] = __builtin_amdgcn_mfma_f32_16x16x32_bf16(
              a[mt], b[nt], acc[mt][nt], 0, 0, 0);
    }
    __syncthreads();
  }

#pragma unroll
  for (int mt = 0; mt < 4; ++mt)
#pragma unroll
    for (int nt = 0; nt < 4; ++nt) {
      int col = n0 + wn + nt * 16 + lr;
      float bcol = bias[col];
#pragma unroll
      for (int r = 0; r < 4; ++r) {
        int row = m0 + wm + mt * 16 + lq * 4 + r;
        if (row < M) {
          float vv = acc[mt][nt][r] + bcol;
          if (RELU) vv = vv > 0.f ? vv : 0.f;
          if (OUTF32) ((float*)Out)[(size_t)row * Nc + col] = vv;
          else        ((bf16_t*)Out)[(size_t)row * Nc + col] = (bf16_t)vv;
        }
      }
    }
}

// ---------------- MFMA GEMM 64x64, BK=64 (heads, 2-way batched) ----------
template<int K, bool RELU, bool OUTF32, typename TIN>
__global__ __launch_bounds__(256) void gemm64x2_kernel(
    const TIN* __restrict__ U0, const bf16_t* __restrict__ Wt0,
    const float* __restrict__ b0, void* __restrict__ O0,
    const TIN* __restrict__ U1, const bf16_t* __restrict__ Wt1,
    const float* __restrict__ b1, void* __restrict__ O1, int M, int Nc) {
  constexpr int LDT = 72;
  __shared__ bf16_t Ut[64 * LDT];
  __shared__ bf16_t Wl[64 * LDT];
  const TIN*    U    = blockIdx.z ? U1 : U0;
  const bf16_t* Wt   = blockIdx.z ? Wt1 : Wt0;
  const float*  bias = blockIdx.z ? b1 : b0;
  void*         Out  = blockIdx.z ? O1 : O0;
  const int m0 = blockIdx.x * 64;
  const int n0 = blockIdx.y * 64;
  const int t = threadIdx.x;
  const int lane = t & 63;
  const int wave = t >> 6;
  const int wm = (wave >> 1) * 32;
  const int wn = (wave & 1) * 32;
  const int srow = t >> 2;
  const int sk = (t & 3) * 8;
  const int lr = lane & 15;
  const int lq = lane >> 4;
  const bool aok = (m0 + srow) < M;
  f32x4 acc[2][2] = {};

  for (int k0 = 0; k0 < K; k0 += 64) {
    const TIN* up = U + (size_t)(m0 + srow) * K + k0 + sk;
    const bf16_t* wp = Wt + (size_t)(n0 + srow) * K + k0 + sk;
    load8_to_lds(up,      aok, (uint4*)&Ut[srow * LDT + sk]);
    load8_to_lds(up + 32, aok, (uint4*)&Ut[srow * LDT + sk + 32]);
    load8_to_lds(wp,      true, (uint4*)&Wl[srow * LDT + sk]);
    load8_to_lds(wp + 32, true, (uint4*)&Wl[srow * LDT + sk + 32]);
    __syncthreads();
#pragma unroll
    for (int s = 0; s < 2; ++s) {
      bf16x8 a[2], b[2];
#pragma unroll
      for (int mt = 0; mt < 2; ++mt)
        a[mt] = *(const bf16x8*)(&Ut[(wm + mt * 16 + lr) * LDT + s * 32 + lq * 8]);
#pragma unroll
      for (int nt = 0; nt < 2; ++nt)
        b[nt] = *(const bf16x8*)(&Wl[(wn + nt * 16 + lr) * LDT + s * 32 + lq * 8]);
#pragma unroll
      for (int mt = 0; mt < 2; ++mt)
#pragma unroll
        for (int nt = 0; nt < 2; ++nt)
          acc[mt][nt] = __builtin_amdgcn_mfma_f32_16x16x32_bf16(
              a[mt], b[nt], acc[mt][nt], 0, 0, 0);
    }
    __syncthreads();
  }

#pragma unroll
  for (int mt = 0; mt < 2; ++mt)
#pragma unroll
    for (int nt = 0; nt < 2; ++nt) {
      int col = n0 + wn + nt * 16 + lr;
      float bcol = bias[col];
#pragma unroll
      for (int r = 0; r < 4; ++r) {
        int row = m0 + wm + mt * 16 + lq * 4 + r;
        if (row < M) {
          float vv = acc[mt][nt][r] + bcol;
          if (RELU) vv = vv > 0.f ? vv : 0.f;
          if (OUTF32) ((float*)Out)[(size_t)row * Nc + col] = vv;
          else        ((bf16_t*)Out)[(size_t)row * Nc + col] = (bf16_t)vv;
        }
      }
    }
}

// ---------- fused MLP: Out = relu(U @ W1 + b1) @ W2 + b2 (in-place OK) ----
// One 128-row block computes the ENTIRE intermediate T (128 x 256) in LDS,
// then immediately consumes it -> avoids the 102 MB/layer HBM round-trip of
// separate GEMM1/GEMM2. W1 in PERMUTED-transposed layout (row s holds
// channel ((s&15)<<4)|(s>>4)) so each thread's 4 nt-outputs are channel-
// consecutive -> packed uint2 T-writes. T rows XOR-swizzled (G4) since a
// 512B row stride would be a 32-way conflict on the phase-2 ds_read_b128.
// W1/W2 fragments load straight from L2 (128 KB each, resident) -> LDS is
// T(64K)+Ut(16K) = 80 KB -> 2 blocks/CU; launch_bounds(512,4) caps VGPR.
template<int K>   // K == H == 256
__global__ __launch_bounds__(512, 4) void mlp_fused_kernel(
    const bf16_t* __restrict__ U, const bf16_t* __restrict__ W1p,
    const float* __restrict__ b1, const bf16_t* __restrict__ W2t,
    const float* __restrict__ b2, bf16_t* __restrict__ Out, int M) {
  __shared__ bf16_t T[128 * 256];   // 64 KB (XOR-swizzled rows)
  __shared__ bf16_t Ut[128 * 64];   // 16 KB A staging
  const int t = threadIdx.x;
  const int lane = t & 63;
  const int wave = t >> 6;                 // 0..7
  const int m0 = blockIdx.x * 128;
  const int wm = (wave >> 2) * 64;         // 0,64
  const int wn = (wave & 3) * 64;          // 0,64,128,192
  const int lr = lane & 15;
  const int lq = lane >> 4;
  const int subrow = lane >> 3;            // 0..7
  const int lchunk = (lane & 7) ^ subrow;  // pre-swizzled col chunk
  f32x4 acc[4][4] = {};

  // ---------------- phase 1: T = relu(U @ W1 + b1) -----------------------
  for (int k0 = 0; k0 < K; k0 += 64) {
#pragma unroll
    for (int c = 0; c < 2; ++c) {
      int urow = m0 + c * 64 + wave * 8 + subrow;
      if (urow >= M) urow = M - 1;
      dma16(U + (size_t)urow * K + k0 + lchunk * 8, &Ut[(c * 64 + wave * 8) * 64]);
    }
    __syncthreads();
#pragma unroll
    for (int s = 0; s < 2; ++s) {
      bf16x8 a[4], b[4];
#pragma unroll
      for (int nt = 0; nt < 4; ++nt)
        b[nt] = *(const bf16x8*)(W1p + (size_t)(wn + nt * 16 + lr) * K + k0 + s * 32 + lq * 8);
#pragma unroll
      for (int mt = 0; mt < 4; ++mt)
        a[mt] = *(const bf16x8*)(&Ut[(wm + mt * 16 + lr) * 64 + (((s * 4 + lq) ^ (lr & 7)) << 3)]);
#pragma unroll
      for (int mt = 0; mt < 4; ++mt)
#pragma unroll
        for (int nt = 0; nt < 4; ++nt)
          acc[mt][nt] = __builtin_amdgcn_mfma_f32_16x16x32_bf16(
              a[mt], b[nt], acc[mt][nt], 0, 0, 0);
    }
    __syncthreads();
  }

  // bias1 + relu + T store (permuted cols: nt -> 4 consecutive channels)
  {
    const int ch0 = lr * 16 + (wave & 3) * 4;   // + nt
    float b1v[4];
#pragma unroll
    for (int nt = 0; nt < 4; ++nt) b1v[nt] = b1[ch0 + nt];
#pragma unroll
    for (int mt = 0; mt < 4; ++mt)
#pragma unroll
      for (int r = 0; r < 4; ++r) {
        int row = wm + mt * 16 + lq * 4 + r;
        union { bf16_t b[4]; uint2 u2; } pk;
#pragma unroll
        for (int nt = 0; nt < 4; ++nt) {
          float vv = acc[mt][nt][r] + b1v[nt];
          pk.b[nt] = (bf16_t)(vv > 0.f ? vv : 0.f);
        }
        *(uint2*)((char*)T + (row << 9) + ((ch0 * 2) ^ ((row & 7) << 4))) = pk.u2;
      }
  }
  __syncthreads();

  // ---------------- phase 2: Out = T @ W2 + b2 ---------------------------
#pragma unroll
  for (int mt = 0; mt < 4; ++mt)
#pragma unroll
    for (int nt = 0; nt < 4; ++nt) {
      f32x4 z = {};
      acc[mt][nt] = z;
    }
  for (int k2 = 0; k2 < K; k2 += 32) {
    bf16x8 a[4], b[4];
#pragma unroll
    for (int nt = 0; nt < 4; ++nt)
      b[nt] = *(const bf16x8*)(W2t + (size_t)(wn + nt * 16 + lr) * K + k2 + lq * 8);
#pragma unroll
    for (int mt = 0; mt < 4; ++mt) {
      int row = wm + mt * 16 + lr;
      a[mt] = *(const bf16x8*)((const char*)T + (row << 9) +
                               (((k2 + lq * 8) * 2) ^ ((row & 7) << 4)));
    }
#pragma unroll
    for (int mt = 0; mt < 4; ++mt)
#pragma unroll
      for (int nt = 0; nt < 4; ++nt)
        acc[mt][nt] = __builtin_amdgcn_mfma_f32_16x16x32_bf16(
            a[mt], b[nt], acc[mt][nt], 0, 0, 0);
  }

#pragma unroll
  for (int mt = 0; mt < 4; ++mt)
#pragma unroll
    for (int nt = 0; nt < 4; ++nt) {
      int col = wn + nt * 16 + lr;
      float bcol = b2[col];
#pragma unroll
      for (int r = 0; r < 4; ++r) {
        int row = m0 + wm + mt * 16 + lq * 4 + r;
        if (row < M) {
          float vv = acc[mt][nt][r] + bcol;
          Out[(size_t)row * H + col] = (bf16_t)vv;
        }
      }
    }
}

// ---------------- fused GINE gather with MFMA edge-linear (v6) -----------
// v6 = proven best (64 us): 4 nodes/block cooperative, bias as inner-loop
// ebv adds, pre-barrier prefetch of the first gather group.
__global__ __launch_bounds__(256) void gine_gather_mfma_kernel(
    const bf16_t* __restrict__ h, const bf16_t* __restrict__ eat16,
    const int* __restrict__ src_sorted, const int* __restrict__ offs,
    const bf16_t* __restrict__ ewt, const float* __restrict__ eb,
    const float* __restrict__ eps_p, bf16_t* __restrict__ u) {
  constexpr int HP = H + 8;
  __shared__ bf16_t slin[2][16 * HP];  // 16.9 KB
  const int t = threadIdx.x;
  const int wave = t >> 6;
  const int lane = t & 63;
  const int lr = lane & 15;
  const int lq = lane >> 4;
  const int lane4 = lane * 4;
  const int n0 = blockIdx.x * 4;
  const int nodeN = n0 + wave;

  bf16x4 hs = *(const bf16x4*)(h + (size_t)nodeN * H + lane4);

  bf16x8 bfrag[4];
#pragma unroll
  for (int nt = 0; nt < 4; ++nt) {
    bf16x8 bv = {};
    if (lq < 2)
      bv = *(const bf16x8*)(ewt + ((wave * 64 + nt * 16 + lr) << 4) + (lq << 3));
    bfrag[nt] = bv;
  }
  float ebv[4];
#pragma unroll
  for (int i = 0; i < 4; ++i) ebv[i] = eb[lane4 + i];

  int bs = offs[n0], be = offs[n0 + 4];
  bs = clampi(bs, 0, N_EDGES);
  be = clampi(be, bs, N_EDGES);
  int ns = offs[nodeN], ne = offs[nodeN + 1];
  ns = clampi(ns, bs, be);
  ne = clampi(ne, ns, be);

  float acc[4] = {0.f, 0.f, 0.f, 0.f};
  int parity = 0;

  for (int cb = bs; cb < be; cb += 16, parity ^= 1) {
    int arow = cb + lr;
    if (arow >= N_EDGES) arow = N_EDGES - 1;
    bf16x8 afrag = {};
    if (lq < 2)
      afrag = *(const bf16x8*)(eat16 + ((size_t)arow << 4) + (lq << 3));

    int j0 = ns > cb ? ns : cb;
    int j1 = ne < cb + 16 ? ne : cb + 16;
    int sidx[4];
    bf16x4 hv[4];
    if (j0 < j1) {
#pragma unroll
      for (int q = 0; q < 4; ++q) {
        int jj = j0 + q; if (jj > j1 - 1) jj = j1 - 1;
        sidx[q] = src_sorted[jj];
      }
    }

    f32x4 c[4];
#pragma unroll
    for (int nt = 0; nt < 4; ++nt) {
      f32x4 z = {};
      c[nt] = __builtin_amdgcn_mfma_f32_16x16x32_bf16(afrag, bfrag[nt], z, 0, 0, 0);
    }
#pragma unroll
    for (int nt = 0; nt < 4; ++nt)
#pragma unroll
      for (int r = 0; r < 4; ++r)
        slin[parity][(lq * 4 + r) * HP + wave * 64 + nt * 16 + lr] = (bf16_t)c[nt][r];

    if (j0 < j1) {
#pragma unroll
      for (int q = 0; q < 4; ++q)
        hv[q] = *(const bf16x4*)(h + (size_t)sidx[q] * H + lane4);
    }

    __syncthreads();

    for (int jb = j0; jb < j1; jb += 4) {
      if (jb != j0) {
#pragma unroll
        for (int q = 0; q < 4; ++q) {
          int jj = jb + q; if (jj > j1 - 1) jj = j1 - 1;
          sidx[q] = src_sorted[jj];
        }
#pragma unroll
        for (int q = 0; q < 4; ++q)
          hv[q] = *(const bf16x4*)(h + (size_t)sidx[q] * H + lane4);
      }
#pragma unroll
      for (int q = 0; q < 4; ++q) {
        if (jb + q < j1) {
          bf16x4 lv = *(const bf16x4*)(&slin[parity][(jb + q - cb) * HP + lane4]);
#pragma unroll
          for (int i = 0; i < 4; ++i)
            acc[i] += fmaxf((float)hv[q][i] + (float)lv[i] + ebv[i], 0.f);
        }
      }
    }
  }

  const float sc = 1.0f + eps_p[0];
  union { bf16x4 v; uint2 b; } o;
#pragma unroll
  for (int i = 0; i < 4; ++i) o.v[i] = (bf16_t)(sc * (float)hs[i] + acc[i]);
  *(uint2*)(u + (size_t)nodeN * H + lane4) = o.b;
}

// --- GraphNorm (+relu, + optional fused mean-pool) -----------------------
// v2: 4 waves per graph (256 threads) with LDS cross-wave reduction.
__global__ __launch_bounds__(256) void graphnorm_kernel(
    const bf16_t* __restrict__ v, bf16_t* __restrict__ hout,
    const int* __restrict__ starts,
    const float* __restrict__ w, const float* __restrict__ b,
    const float* __restrict__ ms, float* __restrict__ hg) {
  constexpr int RS = 9;    // red stride (floats) - odd to spread banks
  constexpr int PS = 13;   // prm stride (floats)
  __shared__ float red[4 * 64 * RS];   // 9.2 KB
  __shared__ float prm[64 * PS];       // 3.3 KB
  const int g = blockIdx.x;
  const int t = threadIdx.x;
  const int lane = t & 63;
  const int wave = t >> 6;
  const int c0 = lane * 4;
  int s = starts[g], e = starts[g + 1];
  s = clampi(s, 0, N_NODES);
  e = clampi(e, s, N_NODES);
  const float cnt = (float)((e - s) > 1 ? (e - s) : 1);

  float sx[4] = {0.f, 0.f, 0.f, 0.f}, sxx[4] = {0.f, 0.f, 0.f, 0.f};
  {
    int i = s + wave;
    for (; i + 4 < e; i += 8) {
      bf16x4 x0 = *(const bf16x4*)(v + (size_t)i * H + c0);
      bf16x4 x1 = *(const bf16x4*)(v + (size_t)(i + 4) * H + c0);
#pragma unroll
      for (int j = 0; j < 4; ++j) {
        float f0 = (float)x0[j], f1 = (float)x1[j];
        sx[j] += f0 + f1; sxx[j] += f0 * f0 + f1 * f1;
      }
    }
    if (i < e) {
      bf16x4 x0 = *(const bf16x4*)(v + (size_t)i * H + c0);
#pragma unroll
      for (int j = 0; j < 4; ++j) {
        float f0 = (float)x0[j];
        sx[j] += f0; sxx[j] += f0 * f0;
      }
    }
  }
  float* myred = &red[(wave * 64 + lane) * RS];
#pragma unroll
  for (int j = 0; j < 4; ++j) { myred[j] = sx[j]; myred[4 + j] = sxx[j]; }
  __syncthreads();

  if (wave == 0) {
#pragma unroll
    for (int j = 0; j < 4; ++j) {
      float fsx = red[lane * RS + j] + red[(64 + lane) * RS + j] +
                  red[(128 + lane) * RS + j] + red[(192 + lane) * RS + j];
      float fsxx = red[lane * RS + 4 + j] + red[(64 + lane) * RS + 4 + j] +
                   red[(128 + lane) * RS + 4 + j] + red[(192 + lane) * RS + 4 + j];
      float mean = fsx / cnt;
      float sub = ms[c0 + j] * mean;
      float var = fsxx / cnt - 2.f * sub * mean + sub * sub;
      var = fmaxf(var, 0.f);
      prm[lane * PS + j] = sub;
      prm[lane * PS + 4 + j] = rsqrtf(var + 1e-5f) * w[c0 + j];
      prm[lane * PS + 8 + j] = b[c0 + j];
    }
  }
  __syncthreads();
  float sub[4], inv[4], bb[4];
#pragma unroll
  for (int j = 0; j < 4; ++j) {
    sub[j] = prm[lane * PS + j];
    inv[j] = prm[lane * PS + 4 + j];
    bb[j] = prm[lane * PS + 8 + j];
  }

  float psum[4] = {0.f, 0.f, 0.f, 0.f};
  {
    int i = s + wave;
    for (; i + 4 < e; i += 8) {
      bf16x4 x0 = *(const bf16x4*)(v + (size_t)i * H + c0);
      bf16x4 x1 = *(const bf16x4*)(v + (size_t)(i + 4) * H + c0);
      union { bf16x4 o; uint2 u; } p0, p1;
#pragma unroll
      for (int j = 0; j < 4; ++j) {
        float o0 = ((float)x0[j] - sub[j]) * inv[j] + bb[j];
        float o1 = ((float)x1[j] - sub[j]) * inv[j] + bb[j];
        o0 = o0 > 0.f ? o0 : 0.f;
        o1 = o1 > 0.f ? o1 : 0.f;
        psum[j] += o0 + o1;
        p0.o[j] = (bf16_t)o0; p1.o[j] = (bf16_t)o1;
      }
      *(uint2*)(hout + (size_t)i * H + c0) = p0.u;
      *(uint2*)(hout + (size_t)(i + 4) * H + c0) = p1.u;
    }
    if (i < e) {
      bf16x4 x0 = *(const bf16x4*)(v + (size_t)i * H + c0);
      union { bf16x4 o; uint2 u; } p0;
#pragma unroll
      for (int j = 0; j < 4; ++j) {
        float o0 = ((float)x0[j] - sub[j]) * inv[j] + bb[j];
        o0 = o0 > 0.f ? o0 : 0.f;
        psum[j] += o0;
        p0.o[j] = (bf16_t)o0;
      }
      *(uint2*)(hout + (size_t)i * H + c0) = p0.u;
    }
  }

  if (hg) {
#pragma unroll
    for (int j = 0; j < 4; ++j) myred[j] = psum[j];
    __syncthreads();
    if (wave == 0) {
#pragma unroll
      for (int j = 0; j < 4; ++j) {
        float p = red[lane * RS + j] + red[(64 + lane) * RS + j] +
                  red[(128 + lane) * RS + j] + red[(192 + lane) * RS + j];
        hg[(size_t)g * H + c0 + j] = p / cnt;
      }
    }
  }
}

// ---- fused tail heads: yhat (Nc=1) + envhat (Nc=8) in one launch --------
__global__ void head_out2_kernel(const bf16_t* __restrict__ In1, const float* __restrict__ W1,
                                 const float* __restrict__ b1, float* __restrict__ O1,
                                 const bf16_t* __restrict__ In2, const float* __restrict__ W2,
                                 const float* __restrict__ b2, float* __restrict__ O2,
                                 int M) {
  int idx = blockIdx.x * blockDim.x + threadIdx.x;
  if (idx < M) {
    float acc = b1[0];
    const bf16_t* in = In1 + (size_t)idx * ZIC;
    for (int k = 0; k < ZIC; ++k) acc += (float)in[k] * W1[k];
    O1[idx] = acc;
  } else {
    int j = idx - M;
    if (j >= M * NE) return;
    int r = j >> 3, n = j & 7;
    float acc = b2[n];
    const bf16_t* in = In2 + (size_t)r * ZIC;
    for (int k = 0; k < ZIC; ++k) acc += (float)in[k] * W2[(size_t)k * NE + n];
    O2[j] = acc;
  }
}

extern "C" void kernel_launch(void* const* d_in, const int* in_sizes, int n_in,
                              void* d_out, int out_size, void* d_ws, size_t ws_size,
                              hipStream_t stream) {
  (void)in_sizes; (void)n_in; (void)out_size; (void)ws_size;
  const float* x        = (const float*)d_in[0];
  const int*   eidx     = (const int*)d_in[1];
  const float* eattr    = (const float*)d_in[2];
  const int*   batch    = (const int*)d_in[3];
  const float* node_W   = (const float*)d_in[4];
  const float* node_b   = (const float*)d_in[5];
  const float* conv_eps = (const float*)d_in[6];
  const float* edge_W   = (const float*)d_in[7];
  const float* edge_b   = (const float*)d_in[8];
  const float* mlp_W1   = (const float*)d_in[9];
  const float* mlp_b1   = (const float*)d_in[10];
  const float* mlp_W2   = (const float*)d_in[11];
  const float* mlp_b2   = (const float*)d_in[12];
  const float* gn_w     = (const float*)d_in[13];
  const float* gn_b     = (const float*)d_in[14];
  const float* gn_ms    = (const float*)d_in[15];
  const float* finv_W1  = (const float*)d_in[16];
  const float* finv_b1  = (const float*)d_in[17];
  const float* finv_W2  = (const float*)d_in[18];
  const float* finv_b2  = (const float*)d_in[19];
  const float* fspu_W1  = (const float*)d_in[20];
  const float* fspu_b1  = (const float*)d_in[21];
  const float* fspu_W2  = (const float*)d_in[22];
  const float* fspu_b2  = (const float*)d_in[23];
  const float* pred_W1  = (const float*)d_in[24];
  const float* pred_b1  = (const float*)d_in[25];
  const float* pred_W2  = (const float*)d_in[26];
  const float* pred_b2  = (const float*)d_in[27];
  const float* adv_W1   = (const float*)d_in[28];
  const float* adv_b1   = (const float*)d_in[29];
  const float* adv_W2   = (const float*)d_in[30];
  const float* adv_b2   = (const float*)d_in[31];
  float* out = (float*)d_out;

  float* out_hg = out;                                  // [G,H]
  float* out_zi = out + (size_t)N_GRAPH * H;            // [G,ZI]
  float* out_zs = out_zi + (size_t)N_GRAPH * ZIC;       // [G,ZS]
  float* out_yh = out_zs + (size_t)N_GRAPH * ZIC;       // [G]
  float* out_ev = out_yh + N_GRAPH;                     // [G,NE]

  // workspace carve-up (~118 MiB total)
  char* wp = (char*)d_ws;
  auto alloc = [&](size_t bytes) { char* p = wp; wp += (bytes + 255) & ~(size_t)255; return p; };
  bf16_t* A        = (bf16_t*)alloc((size_t)N_NODES * H * 2);   // h / t
  bf16_t* B        = (bf16_t*)alloc((size_t)N_NODES * H * 2);   // u / v
  bf16_t* Wt       = (bf16_t*)alloc((size_t)(H * ND + 6 * H * H) * 2);
  bf16_t* WtH      = (bf16_t*)alloc((size_t)(2 * ZIC * H + 4 * ZIC * ZIC) * 2);
  bf16_t* ewt16    = (bf16_t*)alloc((size_t)3 * 256 * 16 * 2);
  bf16_t* eat16    = (bf16_t*)alloc((size_t)N_EDGES * 16 * 2);
  int*    starts   = (int*)alloc((size_t)(N_GRAPH + 1) * 4);
  int*    counts   = (int*)alloc((size_t)N_NODES * 4);
  int*    cursor   = (int*)alloc((size_t)N_NODES * 4);
  int*    offs     = (int*)alloc((size_t)(N_NODES + 1) * 4);
  int*    bsum     = (int*)alloc((size_t)SCAN_B * 4);
  int*    src_srt  = (int*)alloc((size_t)N_EDGES * 4);
  bf16_t* tmp1     = (bf16_t*)alloc((size_t)N_GRAPH * ZIC * 2);
  bf16_t* tmp2     = (bf16_t*)alloc((size_t)N_GRAPH * ZIC * 2);

  const int* srcp = eidx;
  const int* dstp = eidx + N_EDGES;
  const int nscan = (N_NODES + SCAN_B - 1) / SCAN_B;

  compute_starts_kernel<<<(N_NODES + 255) / 256, 256, 0, stream>>>(
      batch, starts, counts, cursor, N_NODES, N_GRAPH);
  count_deg_kernel<<<(N_EDGES + 255) / 256, 256, 0, stream>>>(dstp, counts, N_EDGES, N_NODES);
  scan1_kernel<<<nscan, SCAN_B, 0, stream>>>(counts, offs, bsum, N_NODES);
  scan2_kernel<<<1, 64, 0, stream>>>(bsum, nscan);
  scan3_kernel<<<nscan, SCAN_B, 0, stream>>>(offs, bsum, N_NODES);
  fill_scatter_kernel<<<(N_EDGES + 255) / 256, 256, 0, stream>>>(
      srcp, dstp, eattr, offs, cursor, src_srt, eat16, N_EDGES, N_NODES);
  build_ewt16_kernel<<<(3 * 256 * 16 + 255) / 256, 256, 0, stream>>>(edge_W, ewt16);

  bf16_t* WtN = Wt;
  bf16_t* Wt1base = Wt + H * ND;                      // l-th at stride 2*H*H (PERMUTED rows)
  bf16_t* Wt2base = Wt + H * ND + (size_t)H * H;      // l-th at stride 2*H*H
  auto Wt1l = [&](int l) { return Wt1base + (size_t)(2 * l) * H * H; };
  auto Wt2l = [&](int l) { return Wt2base + (size_t)(2 * l) * H * H; };
  transpose_kernel<<<dim3(H / 32, ND / 32, 1), dim3(32, 8), 0, stream>>>(node_W, WtN, ND, H, 0, 0);
  transpose_perm_kernel<<<dim3(H / 32, H / 32, 3), dim3(32, 8), 0, stream>>>(
      mlp_W1, Wt1base, H, (size_t)H * H, (size_t)2 * H * H);
  transpose_kernel<<<dim3(H / 32, H / 32, 3), dim3(32, 8), 0, stream>>>(
      mlp_W2, Wt2base, H, H, (size_t)H * H, (size_t)2 * H * H);

  bf16_t* fT1 = WtH;                          // [128 x 256]
  bf16_t* fT2 = fT1 + ZIC * H;                // [128 x 128]
  bf16_t* sT1 = fT2 + ZIC * ZIC;              // [128 x 256]
  bf16_t* sT2 = sT1 + ZIC * H;                // [128 x 128]
  bf16_t* pT1 = sT2 + ZIC * ZIC;              // [128 x 128]
  bf16_t* aT1 = pT1 + ZIC * ZIC;              // [128 x 128]
  transpose_kernel<<<dim3(ZIC / 32, H / 32, 1), dim3(32, 8), 0, stream>>>(finv_W1, fT1, H, ZIC, 0, 0);
  transpose_kernel<<<dim3(ZIC / 32, ZIC / 32, 1), dim3(32, 8), 0, stream>>>(finv_W2, fT2, ZIC, ZIC, 0, 0);
  transpose_kernel<<<dim3(ZIC / 32, H / 32, 1), dim3(32, 8), 0, stream>>>(fspu_W1, sT1, H, ZIC, 0, 0);
  transpose_kernel<<<dim3(ZIC / 32, ZIC / 32, 1), dim3(32, 8), 0, stream>>>(fspu_W2, sT2, ZIC, ZIC, 0, 0);
  transpose_kernel<<<dim3(ZIC / 32, ZIC / 32, 1), dim3(32, 8), 0, stream>>>(pred_W1, pT1, ZIC, ZIC, 0, 0);
  transpose_kernel<<<dim3(ZIC / 32, ZIC / 32, 1), dim3(32, 8), 0, stream>>>(adv_W1, aT1, ZIC, ZIC, 0, 0);

  dim3 ggrid((N_NODES + 127) / 128, H / 128);
  // h = x @ node_W + node_b (fp32 input -> VGPR-staging kernel)
  gemm128_kernel<ND, false, false><<<ggrid, 256, 0, stream>>>(x, WtN, node_b, A, N_NODES, H);

  const int mblocks = (N_NODES + 127) / 128;
  for (int l = 0; l < 3; ++l) {
    gine_gather_mfma_kernel<<<N_NODES / 4, 256, 0, stream>>>(
        A, eat16, src_srt, offs, ewt16 + (size_t)l * 256 * 16,
        edge_b + l * H, conv_eps + l, B);
    // fused MLP in place: B = relu(B@W1+b1)@W2+b2
    mlp_fused_kernel<H><<<mblocks, 512, 0, stream>>>(
        B, Wt1l(l), mlp_b1 + l * H, Wt2l(l), mlp_b2 + l * H, B, N_NODES);
    graphnorm_kernel<<<N_GRAPH, 256, 0, stream>>>(B, A, starts, gn_w + l * H, gn_b + l * H,
                                                  gn_ms + l * H, (l == 2) ? out_hg : nullptr);
  }

  // heads via 64x64-tile GEMM, 2-way batched (fewer launches)
  dim3 hgrid2(N_GRAPH / 64, ZIC / 64, 2);
  gemm64x2_kernel<H, true, false, float><<<hgrid2, 256, 0, stream>>>(
      out_hg, fT1, finv_b1, tmp1, out_hg, sT1, fspu_b1, tmp2, N_GRAPH, ZIC);
  gemm64x2_kernel<ZIC, false, true, bf16_t><<<hgrid2, 256, 0, stream>>>(
      tmp1, fT2, finv_b2, out_zi, tmp2, sT2, fspu_b2, out_zs, N_GRAPH, ZIC);
  gemm64x2_kernel<ZIC, true, false, float><<<hgrid2, 256, 0, stream>>>(
      out_zi, pT1, pred_b1, tmp1, out_zi, aT1, adv_b1, tmp2, N_GRAPH, ZIC);
  head_out2_kernel<<<(N_GRAPH * (1 + NE) + 255) / 256, 256, 0, stream>>>(
      tmp1, pred_W2, pred_b2, out_yh, tmp2, adv_W2, adv_b2, out_ev, N_GRAPH);
}

// Round 7
// 735.066 us; speedup vs baseline: 1.0279x; 1.0279x over previous
//
#include <hip/hip_runtime.h>
#include <hip/hip_bf16.h>

typedef __bf16 bf16_t;
typedef __bf16 bf16x8 __attribute__((ext_vector_type(8)));
typedef __bf16 bf16x4 __attribute__((ext_vector_type(4)));
typedef float  f32x4  __attribute__((ext_vector_type(4)));

static constexpr int N_NODES = 100000;
static constexpr int N_EDGES = 300000;
static constexpr int N_GRAPH = 4096;
static constexpr int H  = 256;
static constexpr int ND = 64;
static constexpr int ZIC = 128;
static constexpr int NE = 8;
static constexpr int SCAN_B = 1024;

__device__ __forceinline__ int clampi(int v, int lo, int hi) {
  return v < lo ? lo : (v > hi ? hi : v);
}

// async 16B global -> LDS (wave-uniform LDS base + lane*16)
__device__ __forceinline__ void dma16(const bf16_t* g, bf16_t* lds_base) {
  __builtin_amdgcn_global_load_lds(
      (const __attribute__((address_space(1))) void*)g,
      (__attribute__((address_space(3))) void*)lds_base, 16, 0, 0);
}

// ------- graph segment starts (batch sorted) + zero counts/cursor --------
__global__ void compute_starts_kernel(const int* __restrict__ batch,
                                      int* __restrict__ starts,
                                      int* __restrict__ counts,
                                      int* __restrict__ cursor, int N, int G) {
  int i = blockIdx.x * blockDim.x + threadIdx.x;
  if (i >= N) return;
  counts[i] = 0;
  cursor[i] = 0;
  int b = clampi(batch[i], 0, G - 1);
  if (i == 0) {
    for (int g = 0; g <= b; ++g) starts[g] = 0;
  } else {
    int p = clampi(batch[i - 1], 0, G - 1);
    for (int g = p + 1; g <= b; ++g) starts[g] = i;
  }
  if (i == N - 1) {
    for (int g = b + 1; g <= G; ++g) starts[g] = N;
  }
}

// ---------------- CSR build ----------------
__global__ void count_deg_kernel(const int* __restrict__ dst, int* __restrict__ counts, int E, int N) {
  int e = blockIdx.x * blockDim.x + threadIdx.x;
  if (e < E) atomicAdd(&counts[clampi(dst[e], 0, N - 1)], 1);
}

__global__ __launch_bounds__(SCAN_B) void scan1_kernel(const int* __restrict__ counts,
                                                       int* __restrict__ offs,
                                                       int* __restrict__ bsum, int N) {
  __shared__ int tmp[SCAN_B];
  int i = blockIdx.x * SCAN_B + threadIdx.x;
  int v = (i < N) ? counts[i] : 0;
  tmp[threadIdx.x] = v;
  __syncthreads();
  for (int d = 1; d < SCAN_B; d <<= 1) {
    int t = (threadIdx.x >= d) ? tmp[threadIdx.x - d] : 0;
    __syncthreads();
    tmp[threadIdx.x] += t;
    __syncthreads();
  }
  if (i < N) offs[i + 1] = tmp[threadIdx.x];
  if (threadIdx.x == SCAN_B - 1) bsum[blockIdx.x] = tmp[SCAN_B - 1];
  if (i == 0) offs[0] = 0;
}

__global__ void scan2_kernel(int* __restrict__ bsum, int nblk) {
  if (blockIdx.x == 0 && threadIdx.x == 0) {
    int run = 0;
    for (int b = 0; b < nblk; ++b) { int v = bsum[b]; bsum[b] = run; run += v; }
  }
}

__global__ __launch_bounds__(SCAN_B) void scan3_kernel(int* __restrict__ offs,
                                                       const int* __restrict__ bsum, int N) {
  int i = blockIdx.x * SCAN_B + threadIdx.x;
  if (i < N) offs[i + 1] += bsum[blockIdx.x];
}

// fused: compute position AND scatter src_sorted + eattr(bf16) in one pass
__global__ void fill_scatter_kernel(const int* __restrict__ src, const int* __restrict__ dst,
                                    const float* __restrict__ eattr,
                                    const int* __restrict__ offs, int* __restrict__ cursor,
                                    int* __restrict__ src_srt, bf16_t* __restrict__ eat16,
                                    int E, int N) {
  int e = blockIdx.x * blockDim.x + threadIdx.x;
  if (e >= E) return;
  int d = clampi(dst[e], 0, N - 1);
  int pos = offs[d] + atomicAdd(&cursor[d], 1);
  if ((unsigned)pos >= (unsigned)E) return;
  int s = src[e];
  src_srt[pos] = ((unsigned)s < (unsigned)N_NODES) ? s : 0;
  const float* ea = eattr + (size_t)e * 16;
  union { bf16_t b[16]; uint4 u[2]; } pk;
#pragma unroll
  for (int k = 0; k < 16; ++k) pk.b[k] = (bf16_t)ea[k];
  uint4* dst16 = (uint4*)(eat16 + ((size_t)pos << 4));
  dst16[0] = pk.u[0];
  dst16[1] = pk.u[1];
}

// edge_W[l] (16 x 256) -> eWt[l] (256 rows x 16 cols), bf16  (v6 layout)
__global__ void build_ewt16_kernel(const float* __restrict__ edge_W,
                                   bf16_t* __restrict__ ewt) {
  int idx = blockIdx.x * blockDim.x + threadIdx.x;
  if (idx >= 3 * 256 * 16) return;
  int l = idx / (256 * 16);
  int rem = idx - l * 256 * 16;
  int n = rem >> 4, k = rem & 15;
  ewt[idx] = (bf16_t)edge_W[(size_t)l * 16 * 256 + k * 256 + n];
}

// -------- fp32 transpose + bf16 cast: W[K x Nc] -> Wt[Nc x K] (bf16) ------
__global__ void transpose_kernel(const float* __restrict__ W,
                                 bf16_t* __restrict__ Wt, int K, int Nc,
                                 size_t srcStride, size_t dstStride) {
  __shared__ float tile[32][33];
  const float* Wz = W + (size_t)blockIdx.z * srcStride;
  bf16_t* Wtz = Wt + (size_t)blockIdx.z * dstStride;
  int n0 = blockIdx.x * 32, k0 = blockIdx.y * 32;
  int tx = threadIdx.x, ty = threadIdx.y;
  for (int i = ty; i < 32; i += 8)
    tile[i][tx] = Wz[(size_t)(k0 + i) * Nc + n0 + tx];
  __syncthreads();
  for (int i = ty; i < 32; i += 8)
    Wtz[(size_t)(n0 + i) * K + k0 + tx] = (bf16_t)tile[tx][i];
}

// same, but output row nibble-permuted: channel n stored at row
// s = ((n&15)<<4)|(n>>4)  (involution; requires Nc==256). Used for mlp_W1
// so the fused-MLP kernel's per-thread nt-outputs are channel-consecutive.
__global__ void transpose_perm_kernel(const float* __restrict__ W,
                                      bf16_t* __restrict__ Wt, int K,
                                      size_t srcStride, size_t dstStride) {
  __shared__ float tile[32][33];
  const float* Wz = W + (size_t)blockIdx.z * srcStride;
  bf16_t* Wtz = Wt + (size_t)blockIdx.z * dstStride;
  int n0 = blockIdx.x * 32, k0 = blockIdx.y * 32;
  int tx = threadIdx.x, ty = threadIdx.y;
  for (int i = ty; i < 32; i += 8)
    tile[i][tx] = Wz[(size_t)(k0 + i) * 256 + n0 + tx];
  __syncthreads();
  for (int i = ty; i < 32; i += 8) {
    int n = n0 + i;
    int s = ((n & 15) << 4) | (n >> 4);
    Wtz[(size_t)s * K + k0 + tx] = (bf16_t)tile[tx][i];
  }
}

// ---- staging loaders: 8 contiguous elements -> 8 bf16 (16B) in LDS ----
__device__ __forceinline__ void load8_to_lds(const bf16_t* p, bool valid, uint4* dst) {
  uint4 v = make_uint4(0u, 0u, 0u, 0u);
  if (valid) v = *(const uint4*)p;
  *dst = v;
}
__device__ __forceinline__ void load8_to_lds(const float* p, bool valid, uint4* dst) {
  float4 f0 = make_float4(0.f, 0.f, 0.f, 0.f), f1 = f0;
  if (valid) { f0 = *(const float4*)p; f1 = *(const float4*)(p + 4); }
  union { bf16_t b[8]; uint4 u; } pk;
  pk.b[0] = (bf16_t)f0.x; pk.b[1] = (bf16_t)f0.y;
  pk.b[2] = (bf16_t)f0.z; pk.b[3] = (bf16_t)f0.w;
  pk.b[4] = (bf16_t)f1.x; pk.b[5] = (bf16_t)f1.y;
  pk.b[6] = (bf16_t)f1.z; pk.b[7] = (bf16_t)f1.w;
  *dst = pk.u;
}

// ---------------- MFMA GEMM 128x128 (VGPR staging; fp32 or bf16 in) ------
template<int K, bool RELU, bool OUTF32, typename TIN>
__global__ __launch_bounds__(256) void gemm128_kernel(
    const TIN* __restrict__ U, const bf16_t* __restrict__ Wt,
    const float* __restrict__ bias, void* __restrict__ Out, int M, int Nc) {
  constexpr int LDT = 72;
  __shared__ bf16_t Ut[128 * LDT];
  __shared__ bf16_t Wl[128 * LDT];
  const int m0 = blockIdx.x * 128;
  const int n0 = blockIdx.y * 128;
  const int t = threadIdx.x;
  const int lane = t & 63;
  const int wave = t >> 6;
  const int wm = (wave >> 1) * 64;
  const int wn = (wave & 1) * 64;
  const int srow = t >> 1;
  const int sk = (t & 1) * 32;
  const int lr = lane & 15;
  const int lq = lane >> 4;
  const bool aok = (m0 + srow) < M;
  f32x4 acc[4][4] = {};

  for (int k0 = 0; k0 < K; k0 += 64) {
    const TIN* up = U + (size_t)(m0 + srow) * K + k0 + sk;
    const bf16_t* wp = Wt + (size_t)(n0 + srow) * K + k0 + sk;
#pragma unroll
    for (int q = 0; q < 4; ++q) {
      load8_to_lds(up + q * 8, aok, (uint4*)&Ut[srow * LDT + sk + q * 8]);
      load8_to_lds(wp + q * 8, true, (uint4*)&Wl[srow * LDT + sk + q * 8]);
    }
    __syncthreads();
#pragma unroll
    for (int s = 0; s < 2; ++s) {
      bf16x8 a[4], b[4];
#pragma unroll
      for (int mt = 0; mt < 4; ++mt)
        a[mt] = *(const bf16x8*)(&Ut[(wm + mt * 16 + lr) * LDT + s * 32 + lq * 8]);
#pragma unroll
      for (int nt = 0; nt < 4; ++nt)
        b[nt] = *(const bf16x8*)(&Wl[(wn + nt * 16 + lr) * LDT + s * 32 + lq * 8]);
#pragma unroll
      for (int mt = 0; mt < 4; ++mt)
#pragma unroll
        for (int nt = 0; nt < 4; ++nt)
          acc[mt][nt] = __builtin_amdgcn_mfma_f32_16x16x32_bf16(
              a[mt], b[nt], acc[mt][nt], 0, 0, 0);
    }
    __syncthreads();
  }

#pragma unroll
  for (int mt = 0; mt < 4; ++mt)
#pragma unroll
    for (int nt = 0; nt < 4; ++nt) {
      int col = n0 + wn + nt * 16 + lr;
      float bcol = bias[col];
#pragma unroll
      for (int r = 0; r < 4; ++r) {
        int row = m0 + wm + mt * 16 + lq * 4 + r;
        if (row < M) {
          float vv = acc[mt][nt][r] + bcol;
          if (RELU) vv = vv > 0.f ? vv : 0.f;
          if (OUTF32) ((float*)Out)[(size_t)row * Nc + col] = vv;
          else        ((bf16_t*)Out)[(size_t)row * Nc + col] = (bf16_t)vv;
        }
      }
    }
}

// ---------------- MFMA GEMM 64x64, BK=64 (heads, 2-way batched) ----------
template<int K, bool RELU, bool OUTF32, typename TIN>
__global__ __launch_bounds__(256) void gemm64x2_kernel(
    const TIN* __restrict__ U0, const bf16_t* __restrict__ Wt0,
    const float* __restrict__ b0, void* __restrict__ O0,
    const TIN* __restrict__ U1, const bf16_t* __restrict__ Wt1,
    const float* __restrict__ b1, void* __restrict__ O1, int M, int Nc) {
  constexpr int LDT = 72;
  __shared__ bf16_t Ut[64 * LDT];
  __shared__ bf16_t Wl[64 * LDT];
  const TIN*    U    = blockIdx.z ? U1 : U0;
  const bf16_t* Wt   = blockIdx.z ? Wt1 : Wt0;
  const float*  bias = blockIdx.z ? b1 : b0;
  void*         Out  = blockIdx.z ? O1 : O0;
  const int m0 = blockIdx.x * 64;
  const int n0 = blockIdx.y * 64;
  const int t = threadIdx.x;
  const int lane = t & 63;
  const int wave = t >> 6;
  const int wm = (wave >> 1) * 32;
  const int wn = (wave & 1) * 32;
  const int srow = t >> 2;
  const int sk = (t & 3) * 8;
  const int lr = lane & 15;
  const int lq = lane >> 4;
  const bool aok = (m0 + srow) < M;
  f32x4 acc[2][2] = {};

  for (int k0 = 0; k0 < K; k0 += 64) {
    const TIN* up = U + (size_t)(m0 + srow) * K + k0 + sk;
    const bf16_t* wp = Wt + (size_t)(n0 + srow) * K + k0 + sk;
    load8_to_lds(up,      aok, (uint4*)&Ut[srow * LDT + sk]);
    load8_to_lds(up + 32, aok, (uint4*)&Ut[srow * LDT + sk + 32]);
    load8_to_lds(wp,      true, (uint4*)&Wl[srow * LDT + sk]);
    load8_to_lds(wp + 32, true, (uint4*)&Wl[srow * LDT + sk + 32]);
    __syncthreads();
#pragma unroll
    for (int s = 0; s < 2; ++s) {
      bf16x8 a[2], b[2];
#pragma unroll
      for (int mt = 0; mt < 2; ++mt)
        a[mt] = *(const bf16x8*)(&Ut[(wm + mt * 16 + lr) * LDT + s * 32 + lq * 8]);
#pragma unroll
      for (int nt = 0; nt < 2; ++nt)
        b[nt] = *(const bf16x8*)(&Wl[(wn + nt * 16 + lr) * LDT + s * 32 + lq * 8]);
#pragma unroll
      for (int mt = 0; mt < 2; ++mt)
#pragma unroll
        for (int nt = 0; nt < 2; ++nt)
          acc[mt][nt] = __builtin_amdgcn_mfma_f32_16x16x32_bf16(
              a[mt], b[nt], acc[mt][nt], 0, 0, 0);
    }
    __syncthreads();
  }

#pragma unroll
  for (int mt = 0; mt < 2; ++mt)
#pragma unroll
    for (int nt = 0; nt < 2; ++nt) {
      int col = n0 + wn + nt * 16 + lr;
      float bcol = bias[col];
#pragma unroll
      for (int r = 0; r < 4; ++r) {
        int row = m0 + wm + mt * 16 + lq * 4 + r;
        if (row < M) {
          float vv = acc[mt][nt][r] + bcol;
          if (RELU) vv = vv > 0.f ? vv : 0.f;
          if (OUTF32) ((float*)Out)[(size_t)row * Nc + col] = vv;
          else        ((bf16_t*)Out)[(size_t)row * Nc + col] = (bf16_t)vv;
        }
      }
    }
}

// ---------- fused MLP v2: Out = relu(U @ W1 + b1) @ W2 + b2 (in place) ----
// v1 (128-row, 512thr, 80KB LDS) was LATENCY-bound: 2 blocks/CU, MfmaUtil
// 11.7%, VALUBusy 10.7%, occupancy 28.7% -- all pipes idle. v2 shrinks to
// a 64-row tile / 256 threads / 4 waves: LDS = T(32K)+Ut(8K) = 40KB ->
// 4 blocks/CU, 1563 blocks; co-resident blocks sit in different phases so
// one block's phase-2 MFMAs hide another's staging latency (the wave-level
// overlap that made the unfused GEMMs fast). Same traffic win as v1
// (~93 MB/layer vs ~154 MB for the GEMM pair). W1 permuted-transposed
// (packed uint2 T-writes), T rows XOR-swizzled (G4).
template<int K>   // K == H == 256
__global__ __launch_bounds__(256, 4) void mlp_fused_kernel(
    const bf16_t* __restrict__ U, const bf16_t* __restrict__ W1p,
    const float* __restrict__ b1, const bf16_t* __restrict__ W2t,
    const float* __restrict__ b2, bf16_t* __restrict__ Out, int M) {
  __shared__ bf16_t T[64 * 256];   // 32 KB (XOR-swizzled rows)
  __shared__ bf16_t Ut[64 * 64];   // 8 KB A staging
  const int t = threadIdx.x;
  const int lane = t & 63;
  const int wave = t >> 6;                 // 0..3
  const int m0 = blockIdx.x * 64;
  const int wn = wave * 64;                // this wave's 64-col slice
  const int lr = lane & 15;
  const int lq = lane >> 4;
  const int subrow = lane >> 3;            // 0..7
  const int lchunk = (lane & 7) ^ subrow;  // pre-swizzled col chunk
  f32x4 acc[4][4] = {};

  // ---------------- phase 1: T = relu(U @ W1 + b1) -----------------------
  for (int k0 = 0; k0 < K; k0 += 64) {
#pragma unroll
    for (int c = 0; c < 2; ++c) {
      int urow = m0 + c * 32 + wave * 8 + subrow;
      if (urow >= M) urow = M - 1;
      dma16(U + (size_t)urow * K + k0 + lchunk * 8, &Ut[(c * 32 + wave * 8) * 64]);
    }
    __syncthreads();
#pragma unroll
    for (int s = 0; s < 2; ++s) {
      bf16x8 a[4], b[4];
#pragma unroll
      for (int nt = 0; nt < 4; ++nt)
        b[nt] = *(const bf16x8*)(W1p + (size_t)(wn + nt * 16 + lr) * K + k0 + s * 32 + lq * 8);
#pragma unroll
      for (int mt = 0; mt < 4; ++mt)
        a[mt] = *(const bf16x8*)(&Ut[(mt * 16 + lr) * 64 + (((s * 4 + lq) ^ (lr & 7)) << 3)]);
#pragma unroll
      for (int mt = 0; mt < 4; ++mt)
#pragma unroll
        for (int nt = 0; nt < 4; ++nt)
          acc[mt][nt] = __builtin_amdgcn_mfma_f32_16x16x32_bf16(
              a[mt], b[nt], acc[mt][nt], 0, 0, 0);
    }
    __syncthreads();
  }

  // bias1 + relu + T store (permuted cols: nt -> 4 consecutive channels)
  {
    const int ch0 = lr * 16 + wave * 4;   // + nt
    float b1v[4];
#pragma unroll
    for (int nt = 0; nt < 4; ++nt) b1v[nt] = b1[ch0 + nt];
#pragma unroll
    for (int mt = 0; mt < 4; ++mt)
#pragma unroll
      for (int r = 0; r < 4; ++r) {
        int row = mt * 16 + lq * 4 + r;
        union { bf16_t b[4]; uint2 u2; } pk;
#pragma unroll
        for (int nt = 0; nt < 4; ++nt) {
          float vv = acc[mt][nt][r] + b1v[nt];
          pk.b[nt] = (bf16_t)(vv > 0.f ? vv : 0.f);
        }
        *(uint2*)((char*)T + (row << 9) + ((ch0 * 2) ^ ((row & 7) << 4))) = pk.u2;
      }
  }
  __syncthreads();

  // ---------------- phase 2: Out = T @ W2 + b2 ---------------------------
#pragma unroll
  for (int mt = 0; mt < 4; ++mt)
#pragma unroll
    for (int nt = 0; nt < 4; ++nt) {
      f32x4 z = {};
      acc[mt][nt] = z;
    }
#pragma unroll 2
  for (int k2 = 0; k2 < K; k2 += 32) {
    bf16x8 a[4], b[4];
#pragma unroll
    for (int nt = 0; nt < 4; ++nt)
      b[nt] = *(const bf16x8*)(W2t + (size_t)(wn + nt * 16 + lr) * K + k2 + lq * 8);
#pragma unroll
    for (int mt = 0; mt < 4; ++mt) {
      int row = mt * 16 + lr;
      a[mt] = *(const bf16x8*)((const char*)T + (row << 9) +
                               (((k2 + lq * 8) * 2) ^ ((row & 7) << 4)));
    }
#pragma unroll
    for (int mt = 0; mt < 4; ++mt)
#pragma unroll
      for (int nt = 0; nt < 4; ++nt)
        acc[mt][nt] = __builtin_amdgcn_mfma_f32_16x16x32_bf16(
            a[mt], b[nt], acc[mt][nt], 0, 0, 0);
  }

#pragma unroll
  for (int mt = 0; mt < 4; ++mt)
#pragma unroll
    for (int nt = 0; nt < 4; ++nt) {
      int col = wn + nt * 16 + lr;
      float bcol = b2[col];
#pragma unroll
      for (int r = 0; r < 4; ++r) {
        int row = m0 + mt * 16 + lq * 4 + r;
        if (row < M) {
          float vv = acc[mt][nt][r] + bcol;
          Out[(size_t)row * H + col] = (bf16_t)vv;
        }
      }
    }
}

// ---------------- fused GINE gather with MFMA edge-linear (v6) -----------
// v6 = proven best (64 us): 4 nodes/block cooperative, bias as inner-loop
// ebv adds, pre-barrier prefetch of the first gather group.
__global__ __launch_bounds__(256) void gine_gather_mfma_kernel(
    const bf16_t* __restrict__ h, const bf16_t* __restrict__ eat16,
    const int* __restrict__ src_sorted, const int* __restrict__ offs,
    const bf16_t* __restrict__ ewt, const float* __restrict__ eb,
    const float* __restrict__ eps_p, bf16_t* __restrict__ u) {
  constexpr int HP = H + 8;
  __shared__ bf16_t slin[2][16 * HP];  // 16.9 KB
  const int t = threadIdx.x;
  const int wave = t >> 6;
  const int lane = t & 63;
  const int lr = lane & 15;
  const int lq = lane >> 4;
  const int lane4 = lane * 4;
  const int n0 = blockIdx.x * 4;
  const int nodeN = n0 + wave;

  bf16x4 hs = *(const bf16x4*)(h + (size_t)nodeN * H + lane4);

  bf16x8 bfrag[4];
#pragma unroll
  for (int nt = 0; nt < 4; ++nt) {
    bf16x8 bv = {};
    if (lq < 2)
      bv = *(const bf16x8*)(ewt + ((wave * 64 + nt * 16 + lr) << 4) + (lq << 3));
    bfrag[nt] = bv;
  }
  float ebv[4];
#pragma unroll
  for (int i = 0; i < 4; ++i) ebv[i] = eb[lane4 + i];

  int bs = offs[n0], be = offs[n0 + 4];
  bs = clampi(bs, 0, N_EDGES);
  be = clampi(be, bs, N_EDGES);
  int ns = offs[nodeN], ne = offs[nodeN + 1];
  ns = clampi(ns, bs, be);
  ne = clampi(ne, ns, be);

  float acc[4] = {0.f, 0.f, 0.f, 0.f};
  int parity = 0;

  for (int cb = bs; cb < be; cb += 16, parity ^= 1) {
    int arow = cb + lr;
    if (arow >= N_EDGES) arow = N_EDGES - 1;
    bf16x8 afrag = {};
    if (lq < 2)
      afrag = *(const bf16x8*)(eat16 + ((size_t)arow << 4) + (lq << 3));

    int j0 = ns > cb ? ns : cb;
    int j1 = ne < cb + 16 ? ne : cb + 16;
    int sidx[4];
    bf16x4 hv[4];
    if (j0 < j1) {
#pragma unroll
      for (int q = 0; q < 4; ++q) {
        int jj = j0 + q; if (jj > j1 - 1) jj = j1 - 1;
        sidx[q] = src_sorted[jj];
      }
    }

    f32x4 c[4];
#pragma unroll
    for (int nt = 0; nt < 4; ++nt) {
      f32x4 z = {};
      c[nt] = __builtin_amdgcn_mfma_f32_16x16x32_bf16(afrag, bfrag[nt], z, 0, 0, 0);
    }
#pragma unroll
    for (int nt = 0; nt < 4; ++nt)
#pragma unroll
      for (int r = 0; r < 4; ++r)
        slin[parity][(lq * 4 + r) * HP + wave * 64 + nt * 16 + lr] = (bf16_t)c[nt][r];

    if (j0 < j1) {
#pragma unroll
      for (int q = 0; q < 4; ++q)
        hv[q] = *(const bf16x4*)(h + (size_t)sidx[q] * H + lane4);
    }

    __syncthreads();

    for (int jb = j0; jb < j1; jb += 4) {
      if (jb != j0) {
#pragma unroll
        for (int q = 0; q < 4; ++q) {
          int jj = jb + q; if (jj > j1 - 1) jj = j1 - 1;
          sidx[q] = src_sorted[jj];
        }
#pragma unroll
        for (int q = 0; q < 4; ++q)
          hv[q] = *(const bf16x4*)(h + (size_t)sidx[q] * H + lane4);
      }
#pragma unroll
      for (int q = 0; q < 4; ++q) {
        if (jb + q < j1) {
          bf16x4 lv = *(const bf16x4*)(&slin[parity][(jb + q - cb) * HP + lane4]);
#pragma unroll
          for (int i = 0; i < 4; ++i)
            acc[i] += fmaxf((float)hv[q][i] + (float)lv[i] + ebv[i], 0.f);
        }
      }
    }
  }

  const float sc = 1.0f + eps_p[0];
  union { bf16x4 v; uint2 b; } o;
#pragma unroll
  for (int i = 0; i < 4; ++i) o.v[i] = (bf16_t)(sc * (float)hs[i] + acc[i]);
  *(uint2*)(u + (size_t)nodeN * H + lane4) = o.b;
}

// --- GraphNorm (+relu, + optional fused mean-pool) -----------------------
// v2: 4 waves per graph (256 threads) with LDS cross-wave reduction.
__global__ __launch_bounds__(256) void graphnorm_kernel(
    const bf16_t* __restrict__ v, bf16_t* __restrict__ hout,
    const int* __restrict__ starts,
    const float* __restrict__ w, const float* __restrict__ b,
    const float* __restrict__ ms, float* __restrict__ hg) {
  constexpr int RS = 9;    // red stride (floats) - odd to spread banks
  constexpr int PS = 13;   // prm stride (floats)
  __shared__ float red[4 * 64 * RS];   // 9.2 KB
  __shared__ float prm[64 * PS];       // 3.3 KB
  const int g = blockIdx.x;
  const int t = threadIdx.x;
  const int lane = t & 63;
  const int wave = t >> 6;
  const int c0 = lane * 4;
  int s = starts[g], e = starts[g + 1];
  s = clampi(s, 0, N_NODES);
  e = clampi(e, s, N_NODES);
  const float cnt = (float)((e - s) > 1 ? (e - s) : 1);

  float sx[4] = {0.f, 0.f, 0.f, 0.f}, sxx[4] = {0.f, 0.f, 0.f, 0.f};
  {
    int i = s + wave;
    for (; i + 4 < e; i += 8) {
      bf16x4 x0 = *(const bf16x4*)(v + (size_t)i * H + c0);
      bf16x4 x1 = *(const bf16x4*)(v + (size_t)(i + 4) * H + c0);
#pragma unroll
      for (int j = 0; j < 4; ++j) {
        float f0 = (float)x0[j], f1 = (float)x1[j];
        sx[j] += f0 + f1; sxx[j] += f0 * f0 + f1 * f1;
      }
    }
    if (i < e) {
      bf16x4 x0 = *(const bf16x4*)(v + (size_t)i * H + c0);
#pragma unroll
      for (int j = 0; j < 4; ++j) {
        float f0 = (float)x0[j];
        sx[j] += f0; sxx[j] += f0 * f0;
      }
    }
  }
  float* myred = &red[(wave * 64 + lane) * RS];
#pragma unroll
  for (int j = 0; j < 4; ++j) { myred[j] = sx[j]; myred[4 + j] = sxx[j]; }
  __syncthreads();

  if (wave == 0) {
#pragma unroll
    for (int j = 0; j < 4; ++j) {
      float fsx = red[lane * RS + j] + red[(64 + lane) * RS + j] +
                  red[(128 + lane) * RS + j] + red[(192 + lane) * RS + j];
      float fsxx = red[lane * RS + 4 + j] + red[(64 + lane) * RS + 4 + j] +
                   red[(128 + lane) * RS + 4 + j] + red[(192 + lane) * RS + 4 + j];
      float mean = fsx / cnt;
      float sub = ms[c0 + j] * mean;
      float var = fsxx / cnt - 2.f * sub * mean + sub * sub;
      var = fmaxf(var, 0.f);
      prm[lane * PS + j] = sub;
      prm[lane * PS + 4 + j] = rsqrtf(var + 1e-5f) * w[c0 + j];
      prm[lane * PS + 8 + j] = b[c0 + j];
    }
  }
  __syncthreads();
  float sub[4], inv[4], bb[4];
#pragma unroll
  for (int j = 0; j < 4; ++j) {
    sub[j] = prm[lane * PS + j];
    inv[j] = prm[lane * PS + 4 + j];
    bb[j] = prm[lane * PS + 8 + j];
  }

  float psum[4] = {0.f, 0.f, 0.f, 0.f};
  {
    int i = s + wave;
    for (; i + 4 < e; i += 8) {
      bf16x4 x0 = *(const bf16x4*)(v + (size_t)i * H + c0);
      bf16x4 x1 = *(const bf16x4*)(v + (size_t)(i + 4) * H + c0);
      union { bf16x4 o; uint2 u; } p0, p1;
#pragma unroll
      for (int j = 0; j < 4; ++j) {
        float o0 = ((float)x0[j] - sub[j]) * inv[j] + bb[j];
        float o1 = ((float)x1[j] - sub[j]) * inv[j] + bb[j];
        o0 = o0 > 0.f ? o0 : 0.f;
        o1 = o1 > 0.f ? o1 : 0.f;
        psum[j] += o0 + o1;
        p0.o[j] = (bf16_t)o0; p1.o[j] = (bf16_t)o1;
      }
      *(uint2*)(hout + (size_t)i * H + c0) = p0.u;
      *(uint2*)(hout + (size_t)(i + 4) * H + c0) = p1.u;
    }
    if (i < e) {
      bf16x4 x0 = *(const bf16x4*)(v + (size_t)i * H + c0);
      union { bf16x4 o; uint2 u; } p0;
#pragma unroll
      for (int j = 0; j < 4; ++j) {
        float o0 = ((float)x0[j] - sub[j]) * inv[j] + bb[j];
        o0 = o0 > 0.f ? o0 : 0.f;
        psum[j] += o0;
        p0.o[j] = (bf16_t)o0;
      }
      *(uint2*)(hout + (size_t)i * H + c0) = p0.u;
    }
  }

  if (hg) {
#pragma unroll
    for (int j = 0; j < 4; ++j) myred[j] = psum[j];
    __syncthreads();
    if (wave == 0) {
#pragma unroll
      for (int j = 0; j < 4; ++j) {
        float p = red[lane * RS + j] + red[(64 + lane) * RS + j] +
                  red[(128 + lane) * RS + j] + red[(192 + lane) * RS + j];
        hg[(size_t)g * H + c0 + j] = p / cnt;
      }
    }
  }
}

// ---- fused tail heads: yhat (Nc=1) + envhat (Nc=8) in one launch --------
__global__ void head_out2_kernel(const bf16_t* __restrict__ In1, const float* __restrict__ W1,
                                 const float* __restrict__ b1, float* __restrict__ O1,
                                 const bf16_t* __restrict__ In2, const float* __restrict__ W2,
                                 const float* __restrict__ b2, float* __restrict__ O2,
                                 int M) {
  int idx = blockIdx.x * blockDim.x + threadIdx.x;
  if (idx < M) {
    float acc = b1[0];
    const bf16_t* in = In1 + (size_t)idx * ZIC;
    for (int k = 0; k < ZIC; ++k) acc += (float)in[k] * W1[k];
    O1[idx] = acc;
  } else {
    int j = idx - M;
    if (j >= M * NE) return;
    int r = j >> 3, n = j & 7;
    float acc = b2[n];
    const bf16_t* in = In2 + (size_t)r * ZIC;
    for (int k = 0; k < ZIC; ++k) acc += (float)in[k] * W2[(size_t)k * NE + n];
    O2[j] = acc;
  }
}

extern "C" void kernel_launch(void* const* d_in, const int* in_sizes, int n_in,
                              void* d_out, int out_size, void* d_ws, size_t ws_size,
                              hipStream_t stream) {
  (void)in_sizes; (void)n_in; (void)out_size; (void)ws_size;
  const float* x        = (const float*)d_in[0];
  const int*   eidx     = (const int*)d_in[1];
  const float* eattr    = (const float*)d_in[2];
  const int*   batch    = (const int*)d_in[3];
  const float* node_W   = (const float*)d_in[4];
  const float* node_b   = (const float*)d_in[5];
  const float* conv_eps = (const float*)d_in[6];
  const float* edge_W   = (const float*)d_in[7];
  const float* edge_b   = (const float*)d_in[8];
  const float* mlp_W1   = (const float*)d_in[9];
  const float* mlp_b1   = (const float*)d_in[10];
  const float* mlp_W2   = (const float*)d_in[11];
  const float* mlp_b2   = (const float*)d_in[12];
  const float* gn_w     = (const float*)d_in[13];
  const float* gn_b     = (const float*)d_in[14];
  const float* gn_ms    = (const float*)d_in[15];
  const float* finv_W1  = (const float*)d_in[16];
  const float* finv_b1  = (const float*)d_in[17];
  const float* finv_W2  = (const float*)d_in[18];
  const float* finv_b2  = (const float*)d_in[19];
  const float* fspu_W1  = (const float*)d_in[20];
  const float* fspu_b1  = (const float*)d_in[21];
  const float* fspu_W2  = (const float*)d_in[22];
  const float* fspu_b2  = (const float*)d_in[23];
  const float* pred_W1  = (const float*)d_in[24];
  const float* pred_b1  = (const float*)d_in[25];
  const float* pred_W2  = (const float*)d_in[26];
  const float* pred_b2  = (const float*)d_in[27];
  const float* adv_W1   = (const float*)d_in[28];
  const float* adv_b1   = (const float*)d_in[29];
  const float* adv_W2   = (const float*)d_in[30];
  const float* adv_b2   = (const float*)d_in[31];
  float* out = (float*)d_out;

  float* out_hg = out;                                  // [G,H]
  float* out_zi = out + (size_t)N_GRAPH * H;            // [G,ZI]
  float* out_zs = out_zi + (size_t)N_GRAPH * ZIC;       // [G,ZS]
  float* out_yh = out_zs + (size_t)N_GRAPH * ZIC;       // [G]
  float* out_ev = out_yh + N_GRAPH;                     // [G,NE]

  // workspace carve-up (~118 MiB total)
  char* wp = (char*)d_ws;
  auto alloc = [&](size_t bytes) { char* p = wp; wp += (bytes + 255) & ~(size_t)255; return p; };
  bf16_t* A        = (bf16_t*)alloc((size_t)N_NODES * H * 2);   // h / t
  bf16_t* B        = (bf16_t*)alloc((size_t)N_NODES * H * 2);   // u / v
  bf16_t* Wt       = (bf16_t*)alloc((size_t)(H * ND + 6 * H * H) * 2);
  bf16_t* WtH      = (bf16_t*)alloc((size_t)(2 * ZIC * H + 4 * ZIC * ZIC) * 2);
  bf16_t* ewt16    = (bf16_t*)alloc((size_t)3 * 256 * 16 * 2);
  bf16_t* eat16    = (bf16_t*)alloc((size_t)N_EDGES * 16 * 2);
  int*    starts   = (int*)alloc((size_t)(N_GRAPH + 1) * 4);
  int*    counts   = (int*)alloc((size_t)N_NODES * 4);
  int*    cursor   = (int*)alloc((size_t)N_NODES * 4);
  int*    offs     = (int*)alloc((size_t)(N_NODES + 1) * 4);
  int*    bsum     = (int*)alloc((size_t)SCAN_B * 4);
  int*    src_srt  = (int*)alloc((size_t)N_EDGES * 4);
  bf16_t* tmp1     = (bf16_t*)alloc((size_t)N_GRAPH * ZIC * 2);
  bf16_t* tmp2     = (bf16_t*)alloc((size_t)N_GRAPH * ZIC * 2);

  const int* srcp = eidx;
  const int* dstp = eidx + N_EDGES;
  const int nscan = (N_NODES + SCAN_B - 1) / SCAN_B;

  compute_starts_kernel<<<(N_NODES + 255) / 256, 256, 0, stream>>>(
      batch, starts, counts, cursor, N_NODES, N_GRAPH);
  count_deg_kernel<<<(N_EDGES + 255) / 256, 256, 0, stream>>>(dstp, counts, N_EDGES, N_NODES);
  scan1_kernel<<<nscan, SCAN_B, 0, stream>>>(counts, offs, bsum, N_NODES);
  scan2_kernel<<<1, 64, 0, stream>>>(bsum, nscan);
  scan3_kernel<<<nscan, SCAN_B, 0, stream>>>(offs, bsum, N_NODES);
  fill_scatter_kernel<<<(N_EDGES + 255) / 256, 256, 0, stream>>>(
      srcp, dstp, eattr, offs, cursor, src_srt, eat16, N_EDGES, N_NODES);
  build_ewt16_kernel<<<(3 * 256 * 16 + 255) / 256, 256, 0, stream>>>(edge_W, ewt16);

  bf16_t* WtN = Wt;
  bf16_t* Wt1base = Wt + H * ND;                      // l-th at stride 2*H*H (PERMUTED rows)
  bf16_t* Wt2base = Wt + H * ND + (size_t)H * H;      // l-th at stride 2*H*H
  auto Wt1l = [&](int l) { return Wt1base + (size_t)(2 * l) * H * H; };
  auto Wt2l = [&](int l) { return Wt2base + (size_t)(2 * l) * H * H; };
  transpose_kernel<<<dim3(H / 32, ND / 32, 1), dim3(32, 8), 0, stream>>>(node_W, WtN, ND, H, 0, 0);
  transpose_perm_kernel<<<dim3(H / 32, H / 32, 3), dim3(32, 8), 0, stream>>>(
      mlp_W1, Wt1base, H, (size_t)H * H, (size_t)2 * H * H);
  transpose_kernel<<<dim3(H / 32, H / 32, 3), dim3(32, 8), 0, stream>>>(
      mlp_W2, Wt2base, H, H, (size_t)H * H, (size_t)2 * H * H);

  bf16_t* fT1 = WtH;                          // [128 x 256]
  bf16_t* fT2 = fT1 + ZIC * H;                // [128 x 128]
  bf16_t* sT1 = fT2 + ZIC * ZIC;              // [128 x 256]
  bf16_t* sT2 = sT1 + ZIC * H;                // [128 x 128]
  bf16_t* pT1 = sT2 + ZIC * ZIC;              // [128 x 128]
  bf16_t* aT1 = pT1 + ZIC * ZIC;              // [128 x 128]
  transpose_kernel<<<dim3(ZIC / 32, H / 32, 1), dim3(32, 8), 0, stream>>>(finv_W1, fT1, H, ZIC, 0, 0);
  transpose_kernel<<<dim3(ZIC / 32, ZIC / 32, 1), dim3(32, 8), 0, stream>>>(finv_W2, fT2, ZIC, ZIC, 0, 0);
  transpose_kernel<<<dim3(ZIC / 32, H / 32, 1), dim3(32, 8), 0, stream>>>(fspu_W1, sT1, H, ZIC, 0, 0);
  transpose_kernel<<<dim3(ZIC / 32, ZIC / 32, 1), dim3(32, 8), 0, stream>>>(fspu_W2, sT2, ZIC, ZIC, 0, 0);
  transpose_kernel<<<dim3(ZIC / 32, ZIC / 32, 1), dim3(32, 8), 0, stream>>>(pred_W1, pT1, ZIC, ZIC, 0, 0);
  transpose_kernel<<<dim3(ZIC / 32, ZIC / 32, 1), dim3(32, 8), 0, stream>>>(adv_W1, aT1, ZIC, ZIC, 0, 0);

  dim3 ggrid((N_NODES + 127) / 128, H / 128);
  // h = x @ node_W + node_b (fp32 input -> VGPR-staging kernel)
  gemm128_kernel<ND, false, false><<<ggrid, 256, 0, stream>>>(x, WtN, node_b, A, N_NODES, H);

  const int mblocks64 = (N_NODES + 63) / 64;
  for (int l = 0; l < 3; ++l) {
    gine_gather_mfma_kernel<<<N_NODES / 4, 256, 0, stream>>>(
        A, eat16, src_srt, offs, ewt16 + (size_t)l * 256 * 16,
        edge_b + l * H, conv_eps + l, B);
    // fused MLP in place: B = relu(B@W1+b1)@W2+b2
    mlp_fused_kernel<H><<<mblocks64, 256, 0, stream>>>(
        B, Wt1l(l), mlp_b1 + l * H, Wt2l(l), mlp_b2 + l * H, B, N_NODES);
    graphnorm_kernel<<<N_GRAPH, 256, 0, stream>>>(B, A, starts, gn_w + l * H, gn_b + l * H,
                                                  gn_ms + l * H, (l == 2) ? out_hg : nullptr);
  }

  // heads via 64x64-tile GEMM, 2-way batched (fewer launches)
  dim3 hgrid2(N_GRAPH / 64, ZIC / 64, 2);
  gemm64x2_kernel<H, true, false, float><<<hgrid2, 256, 0, stream>>>(
      out_hg, fT1, finv_b1, tmp1, out_hg, sT1, fspu_b1, tmp2, N_GRAPH, ZIC);
  gemm64x2_kernel<ZIC, false, true, bf16_t><<<hgrid2, 256, 0, stream>>>(
      tmp1, fT2, finv_b2, out_zi, tmp2, sT2, fspu_b2, out_zs, N_GRAPH, ZIC);
  gemm64x2_kernel<ZIC, true, false, float><<<hgrid2, 256, 0, stream>>>(
      out_zi, pT1, pred_b1, tmp1, out_zi, aT1, adv_b1, tmp2, N_GRAPH, ZIC);
  head_out2_kernel<<<(N_GRAPH * (1 + NE) + 255) / 256, 256, 0, stream>>>(
      tmp1, pred_W2, pred_b2, out_yh, tmp2, adv_W2, adv_b2, out_ev, N_GRAPH);
}

// Round 8
// 722.508 us; speedup vs baseline: 1.0458x; 1.0174x over previous
//
#include <hip/hip_runtime.h>
#include <hip/hip_bf16.h>

typedef __bf16 bf16_t;
typedef __bf16 bf16x8 __attribute__((ext_vector_type(8)));
typedef __bf16 bf16x4 __attribute__((ext_vector_type(4)));
typedef float  f32x4  __attribute__((ext_vector_type(4)));

static constexpr int N_NODES = 100000;
static constexpr int N_EDGES = 300000;
static constexpr int N_GRAPH = 4096;
static constexpr int H  = 256;
static constexpr int ND = 64;
static constexpr int ZIC = 128;
static constexpr int NE = 8;
static constexpr int SCAN_B = 1024;

__device__ __forceinline__ int clampi(int v, int lo, int hi) {
  return v < lo ? lo : (v > hi ? hi : v);
}

// async 16B global -> LDS (wave-uniform LDS base + lane*16)
__device__ __forceinline__ void dma16(const bf16_t* g, bf16_t* lds_base) {
  __builtin_amdgcn_global_load_lds(
      (const __attribute__((address_space(1))) void*)g,
      (__attribute__((address_space(3))) void*)lds_base, 16, 0, 0);
}

// ------- graph segment starts (batch sorted) + zero counts/cursor --------
__global__ void compute_starts_kernel(const int* __restrict__ batch,
                                      int* __restrict__ starts,
                                      int* __restrict__ counts,
                                      int* __restrict__ cursor, int N, int G) {
  int i = blockIdx.x * blockDim.x + threadIdx.x;
  if (i >= N) return;
  counts[i] = 0;
  cursor[i] = 0;
  int b = clampi(batch[i], 0, G - 1);
  if (i == 0) {
    for (int g = 0; g <= b; ++g) starts[g] = 0;
  } else {
    int p = clampi(batch[i - 1], 0, G - 1);
    for (int g = p + 1; g <= b; ++g) starts[g] = i;
  }
  if (i == N - 1) {
    for (int g = b + 1; g <= G; ++g) starts[g] = N;
  }
}

// ---------------- CSR build ----------------
__global__ void count_deg_kernel(const int* __restrict__ dst, int* __restrict__ counts, int E, int N) {
  int e = blockIdx.x * blockDim.x + threadIdx.x;
  if (e < E) atomicAdd(&counts[clampi(dst[e], 0, N - 1)], 1);
}

__global__ __launch_bounds__(SCAN_B) void scan1_kernel(const int* __restrict__ counts,
                                                       int* __restrict__ offs,
                                                       int* __restrict__ bsum, int N) {
  __shared__ int tmp[SCAN_B];
  int i = blockIdx.x * SCAN_B + threadIdx.x;
  int v = (i < N) ? counts[i] : 0;
  tmp[threadIdx.x] = v;
  __syncthreads();
  for (int d = 1; d < SCAN_B; d <<= 1) {
    int t = (threadIdx.x >= d) ? tmp[threadIdx.x - d] : 0;
    __syncthreads();
    tmp[threadIdx.x] += t;
    __syncthreads();
  }
  if (i < N) offs[i + 1] = tmp[threadIdx.x];
  if (threadIdx.x == SCAN_B - 1) bsum[blockIdx.x] = tmp[SCAN_B - 1];
  if (i == 0) offs[0] = 0;
}

__global__ void scan2_kernel(int* __restrict__ bsum, int nblk) {
  if (blockIdx.x == 0 && threadIdx.x == 0) {
    int run = 0;
    for (int b = 0; b < nblk; ++b) { int v = bsum[b]; bsum[b] = run; run += v; }
  }
}

__global__ __launch_bounds__(SCAN_B) void scan3_kernel(int* __restrict__ offs,
                                                       const int* __restrict__ bsum, int N) {
  int i = blockIdx.x * SCAN_B + threadIdx.x;
  if (i < N) offs[i + 1] += bsum[blockIdx.x];
}

// fused: compute position AND scatter src_sorted + eattr(bf16) in one pass
__global__ void fill_scatter_kernel(const int* __restrict__ src, const int* __restrict__ dst,
                                    const float* __restrict__ eattr,
                                    const int* __restrict__ offs, int* __restrict__ cursor,
                                    int* __restrict__ src_srt, bf16_t* __restrict__ eat16,
                                    int E, int N) {
  int e = blockIdx.x * blockDim.x + threadIdx.x;
  if (e >= E) return;
  int d = clampi(dst[e], 0, N - 1);
  int pos = offs[d] + atomicAdd(&cursor[d], 1);
  if ((unsigned)pos >= (unsigned)E) return;
  int s = src[e];
  src_srt[pos] = ((unsigned)s < (unsigned)N_NODES) ? s : 0;
  const float* ea = eattr + (size_t)e * 16;
  union { bf16_t b[16]; uint4 u[2]; } pk;
#pragma unroll
  for (int k = 0; k < 16; ++k) pk.b[k] = (bf16_t)ea[k];
  uint4* dst16 = (uint4*)(eat16 + ((size_t)pos << 4));
  dst16[0] = pk.u[0];
  dst16[1] = pk.u[1];
}

// edge_W[l] (16 x 256) -> eWt[l] (256 rows x 16 cols), bf16  (v6 layout)
__global__ void build_ewt16_kernel(const float* __restrict__ edge_W,
                                   bf16_t* __restrict__ ewt) {
  int idx = blockIdx.x * blockDim.x + threadIdx.x;
  if (idx >= 3 * 256 * 16) return;
  int l = idx / (256 * 16);
  int rem = idx - l * 256 * 16;
  int n = rem >> 4, k = rem & 15;
  ewt[idx] = (bf16_t)edge_W[(size_t)l * 16 * 256 + k * 256 + n];
}

// -------- fp32 transpose + bf16 cast: W[K x Nc] -> Wt[Nc x K] (bf16) ------
__global__ void transpose_kernel(const float* __restrict__ W,
                                 bf16_t* __restrict__ Wt, int K, int Nc,
                                 size_t srcStride, size_t dstStride) {
  __shared__ float tile[32][33];
  const float* Wz = W + (size_t)blockIdx.z * srcStride;
  bf16_t* Wtz = Wt + (size_t)blockIdx.z * dstStride;
  int n0 = blockIdx.x * 32, k0 = blockIdx.y * 32;
  int tx = threadIdx.x, ty = threadIdx.y;
  for (int i = ty; i < 32; i += 8)
    tile[i][tx] = Wz[(size_t)(k0 + i) * Nc + n0 + tx];
  __syncthreads();
  for (int i = ty; i < 32; i += 8)
    Wtz[(size_t)(n0 + i) * K + k0 + tx] = (bf16_t)tile[tx][i];
}

// ---- staging loaders: 8 contiguous elements -> 8 bf16 (16B) in LDS ----
__device__ __forceinline__ void load8_to_lds(const bf16_t* p, bool valid, uint4* dst) {
  uint4 v = make_uint4(0u, 0u, 0u, 0u);
  if (valid) v = *(const uint4*)p;
  *dst = v;
}
__device__ __forceinline__ void load8_to_lds(const float* p, bool valid, uint4* dst) {
  float4 f0 = make_float4(0.f, 0.f, 0.f, 0.f), f1 = f0;
  if (valid) { f0 = *(const float4*)p; f1 = *(const float4*)(p + 4); }
  union { bf16_t b[8]; uint4 u; } pk;
  pk.b[0] = (bf16_t)f0.x; pk.b[1] = (bf16_t)f0.y;
  pk.b[2] = (bf16_t)f0.z; pk.b[3] = (bf16_t)f0.w;
  pk.b[4] = (bf16_t)f1.x; pk.b[5] = (bf16_t)f1.y;
  pk.b[6] = (bf16_t)f1.z; pk.b[7] = (bf16_t)f1.w;
  *dst = pk.u;
}

// ---------------- MFMA GEMM 128x128 (VGPR staging; fp32 or bf16 in) ------
template<int K, bool RELU, bool OUTF32, typename TIN>
__global__ __launch_bounds__(256) void gemm128_kernel(
    const TIN* __restrict__ U, const bf16_t* __restrict__ Wt,
    const float* __restrict__ bias, void* __restrict__ Out, int M, int Nc) {
  constexpr int LDT = 72;
  __shared__ bf16_t Ut[128 * LDT];
  __shared__ bf16_t Wl[128 * LDT];
  const int m0 = blockIdx.x * 128;
  const int n0 = blockIdx.y * 128;
  const int t = threadIdx.x;
  const int lane = t & 63;
  const int wave = t >> 6;
  const int wm = (wave >> 1) * 64;
  const int wn = (wave & 1) * 64;
  const int srow = t >> 1;
  const int sk = (t & 1) * 32;
  const int lr = lane & 15;
  const int lq = lane >> 4;
  const bool aok = (m0 + srow) < M;
  f32x4 acc[4][4] = {};

  for (int k0 = 0; k0 < K; k0 += 64) {
    const TIN* up = U + (size_t)(m0 + srow) * K + k0 + sk;
    const bf16_t* wp = Wt + (size_t)(n0 + srow) * K + k0 + sk;
#pragma unroll
    for (int q = 0; q < 4; ++q) {
      load8_to_lds(up + q * 8, aok, (uint4*)&Ut[srow * LDT + sk + q * 8]);
      load8_to_lds(wp + q * 8, true, (uint4*)&Wl[srow * LDT + sk + q * 8]);
    }
    __syncthreads();
#pragma unroll
    for (int s = 0; s < 2; ++s) {
      bf16x8 a[4], b[4];
#pragma unroll
      for (int mt = 0; mt < 4; ++mt)
        a[mt] = *(const bf16x8*)(&Ut[(wm + mt * 16 + lr) * LDT + s * 32 + lq * 8]);
#pragma unroll
      for (int nt = 0; nt < 4; ++nt)
        b[nt] = *(const bf16x8*)(&Wl[(wn + nt * 16 + lr) * LDT + s * 32 + lq * 8]);
#pragma unroll
      for (int mt = 0; mt < 4; ++mt)
#pragma unroll
        for (int nt = 0; nt < 4; ++nt)
          acc[mt][nt] = __builtin_amdgcn_mfma_f32_16x16x32_bf16(
              a[mt], b[nt], acc[mt][nt], 0, 0, 0);
    }
    __syncthreads();
  }

#pragma unroll
  for (int mt = 0; mt < 4; ++mt)
#pragma unroll
    for (int nt = 0; nt < 4; ++nt) {
      int col = n0 + wn + nt * 16 + lr;
      float bcol = bias[col];
#pragma unroll
      for (int r = 0; r < 4; ++r) {
        int row = m0 + wm + mt * 16 + lq * 4 + r;
        if (row < M) {
          float vv = acc[mt][nt][r] + bcol;
          if (RELU) vv = vv > 0.f ? vv : 0.f;
          if (OUTF32) ((float*)Out)[(size_t)row * Nc + col] = vv;
          else        ((bf16_t*)Out)[(size_t)row * Nc + col] = (bf16_t)vv;
        }
      }
    }
}

// ------- MFMA GEMM 128x256 (full-H tile), bf16 in, dma16 + XOR swizzle ----
// 512 threads / 8 waves (2 M x 4 N). Reads A once per GEMM. (round-5 proven)
template<int K, bool RELU>
__global__ __launch_bounds__(512) void gemm256_dma_kernel(
    const bf16_t* __restrict__ U, const bf16_t* __restrict__ Wt,
    const float* __restrict__ bias, bf16_t* __restrict__ Out, int M) {
  __shared__ bf16_t Ut[128 * 64];   // 16 KB
  __shared__ bf16_t Wl[256 * 64];   // 32 KB
  const int t = threadIdx.x;
  const int lane = t & 63;
  const int wave = t >> 6;                 // 0..7
  const int m0 = blockIdx.x * 128;
  const int wm = (wave >> 2) * 64;         // 0,64
  const int wn = (wave & 3) * 64;          // 0,64,128,192
  const int lr = lane & 15;
  const int lq = lane >> 4;
  const int subrow = lane >> 3;            // 0..7 within 8-row group
  const int lchunk = (lane & 7) ^ subrow;  // pre-swizzled col chunk
  f32x4 acc[4][4] = {};

  for (int k0 = 0; k0 < K; k0 += 64) {
#pragma unroll
    for (int c = 0; c < 2; ++c) {
      int urow = m0 + c * 64 + wave * 8 + subrow;
      if (urow >= M) urow = M - 1;
      dma16(U + (size_t)urow * K + k0 + lchunk * 8, &Ut[(c * 64 + wave * 8) * 64]);
    }
#pragma unroll
    for (int c = 0; c < 4; ++c) {
      int wrow = c * 64 + wave * 8 + subrow;
      dma16(Wt + (size_t)wrow * K + k0 + lchunk * 8, &Wl[(c * 64 + wave * 8) * 64]);
    }
    __syncthreads();
#pragma unroll
    for (int s = 0; s < 2; ++s) {
      bf16x8 a[4], b[4];
#pragma unroll
      for (int mt = 0; mt < 4; ++mt)
        a[mt] = *(const bf16x8*)(&Ut[(wm + mt * 16 + lr) * 64 + (((s * 4 + lq) ^ (lr & 7)) << 3)]);
#pragma unroll
      for (int nt = 0; nt < 4; ++nt)
        b[nt] = *(const bf16x8*)(&Wl[(wn + nt * 16 + lr) * 64 + (((s * 4 + lq) ^ (lr & 7)) << 3)]);
#pragma unroll
      for (int mt = 0; mt < 4; ++mt)
#pragma unroll
        for (int nt = 0; nt < 4; ++nt)
          acc[mt][nt] = __builtin_amdgcn_mfma_f32_16x16x32_bf16(
              a[mt], b[nt], acc[mt][nt], 0, 0, 0);
    }
    __syncthreads();
  }

#pragma unroll
  for (int mt = 0; mt < 4; ++mt)
#pragma unroll
    for (int nt = 0; nt < 4; ++nt) {
      int col = wn + nt * 16 + lr;
      float bcol = bias[col];
#pragma unroll
      for (int r = 0; r < 4; ++r) {
        int row = m0 + wm + mt * 16 + lq * 4 + r;
        if (row < M) {
          float vv = acc[mt][nt][r] + bcol;
          if (RELU) vv = vv > 0.f ? vv : 0.f;
          Out[(size_t)row * H + col] = (bf16_t)vv;
        }
      }
    }
}

// ---------------- fused GINE gather with MFMA edge-linear (v6) -----------
// v6 = proven best (64 us): 4 nodes/block cooperative, bias as inner-loop
// ebv adds, pre-barrier prefetch of the first gather group.
__global__ __launch_bounds__(256) void gine_gather_mfma_kernel(
    const bf16_t* __restrict__ h, const bf16_t* __restrict__ eat16,
    const int* __restrict__ src_sorted, const int* __restrict__ offs,
    const bf16_t* __restrict__ ewt, const float* __restrict__ eb,
    const float* __restrict__ eps_p, bf16_t* __restrict__ u) {
  constexpr int HP = H + 8;
  __shared__ bf16_t slin[2][16 * HP];  // 16.9 KB
  const int t = threadIdx.x;
  const int wave = t >> 6;
  const int lane = t & 63;
  const int lr = lane & 15;
  const int lq = lane >> 4;
  const int lane4 = lane * 4;
  const int n0 = blockIdx.x * 4;
  const int nodeN = n0 + wave;

  bf16x4 hs = *(const bf16x4*)(h + (size_t)nodeN * H + lane4);

  bf16x8 bfrag[4];
#pragma unroll
  for (int nt = 0; nt < 4; ++nt) {
    bf16x8 bv = {};
    if (lq < 2)
      bv = *(const bf16x8*)(ewt + ((wave * 64 + nt * 16 + lr) << 4) + (lq << 3));
    bfrag[nt] = bv;
  }
  float ebv[4];
#pragma unroll
  for (int i = 0; i < 4; ++i) ebv[i] = eb[lane4 + i];

  int bs = offs[n0], be = offs[n0 + 4];
  bs = clampi(bs, 0, N_EDGES);
  be = clampi(be, bs, N_EDGES);
  int ns = offs[nodeN], ne = offs[nodeN + 1];
  ns = clampi(ns, bs, be);
  ne = clampi(ne, ns, be);

  float acc[4] = {0.f, 0.f, 0.f, 0.f};
  int parity = 0;

  for (int cb = bs; cb < be; cb += 16, parity ^= 1) {
    int arow = cb + lr;
    if (arow >= N_EDGES) arow = N_EDGES - 1;
    bf16x8 afrag = {};
    if (lq < 2)
      afrag = *(const bf16x8*)(eat16 + ((size_t)arow << 4) + (lq << 3));

    int j0 = ns > cb ? ns : cb;
    int j1 = ne < cb + 16 ? ne : cb + 16;
    int sidx[4];
    bf16x4 hv[4];
    if (j0 < j1) {
#pragma unroll
      for (int q = 0; q < 4; ++q) {
        int jj = j0 + q; if (jj > j1 - 1) jj = j1 - 1;
        sidx[q] = src_sorted[jj];
      }
    }

    f32x4 c[4];
#pragma unroll
    for (int nt = 0; nt < 4; ++nt) {
      f32x4 z = {};
      c[nt] = __builtin_amdgcn_mfma_f32_16x16x32_bf16(afrag, bfrag[nt], z, 0, 0, 0);
    }
#pragma unroll
    for (int nt = 0; nt < 4; ++nt)
#pragma unroll
      for (int r = 0; r < 4; ++r)
        slin[parity][(lq * 4 + r) * HP + wave * 64 + nt * 16 + lr] = (bf16_t)c[nt][r];

    if (j0 < j1) {
#pragma unroll
      for (int q = 0; q < 4; ++q)
        hv[q] = *(const bf16x4*)(h + (size_t)sidx[q] * H + lane4);
    }

    __syncthreads();

    for (int jb = j0; jb < j1; jb += 4) {
      if (jb != j0) {
#pragma unroll
        for (int q = 0; q < 4; ++q) {
          int jj = jb + q; if (jj > j1 - 1) jj = j1 - 1;
          sidx[q] = src_sorted[jj];
        }
#pragma unroll
        for (int q = 0; q < 4; ++q)
          hv[q] = *(const bf16x4*)(h + (size_t)sidx[q] * H + lane4);
      }
#pragma unroll
      for (int q = 0; q < 4; ++q) {
        if (jb + q < j1) {
          bf16x4 lv = *(const bf16x4*)(&slin[parity][(jb + q - cb) * HP + lane4]);
#pragma unroll
          for (int i = 0; i < 4; ++i)
            acc[i] += fmaxf((float)hv[q][i] + (float)lv[i] + ebv[i], 0.f);
        }
      }
    }
  }

  const float sc = 1.0f + eps_p[0];
  union { bf16x4 v; uint2 b; } o;
#pragma unroll
  for (int i = 0; i < 4; ++i) o.v[i] = (bf16_t)(sc * (float)hs[i] + acc[i]);
  *(uint2*)(u + (size_t)nodeN * H + lane4) = o.b;
}

// --- GraphNorm (+relu, + optional fused mean-pool) -----------------------
__global__ __launch_bounds__(256) void graphnorm_kernel(
    const bf16_t* __restrict__ v, bf16_t* __restrict__ hout,
    const int* __restrict__ starts,
    const float* __restrict__ w, const float* __restrict__ b,
    const float* __restrict__ ms, float* __restrict__ hg) {
  constexpr int RS = 9;    // red stride (floats) - odd to spread banks
  constexpr int PS = 13;   // prm stride (floats)
  __shared__ float red[4 * 64 * RS];   // 9.2 KB
  __shared__ float prm[64 * PS];       // 3.3 KB
  const int g = blockIdx.x;
  const int t = threadIdx.x;
  const int lane = t & 63;
  const int wave = t >> 6;
  const int c0 = lane * 4;
  int s = starts[g], e = starts[g + 1];
  s = clampi(s, 0, N_NODES);
  e = clampi(e, s, N_NODES);
  const float cnt = (float)((e - s) > 1 ? (e - s) : 1);

  float sx[4] = {0.f, 0.f, 0.f, 0.f}, sxx[4] = {0.f, 0.f, 0.f, 0.f};
  {
    int i = s + wave;
    for (; i + 4 < e; i += 8) {
      bf16x4 x0 = *(const bf16x4*)(v + (size_t)i * H + c0);
      bf16x4 x1 = *(const bf16x4*)(v + (size_t)(i + 4) * H + c0);
#pragma unroll
      for (int j = 0; j < 4; ++j) {
        float f0 = (float)x0[j], f1 = (float)x1[j];
        sx[j] += f0 + f1; sxx[j] += f0 * f0 + f1 * f1;
      }
    }
    if (i < e) {
      bf16x4 x0 = *(const bf16x4*)(v + (size_t)i * H + c0);
#pragma unroll
      for (int j = 0; j < 4; ++j) {
        float f0 = (float)x0[j];
        sx[j] += f0; sxx[j] += f0 * f0;
      }
    }
  }
  float* myred = &red[(wave * 64 + lane) * RS];
#pragma unroll
  for (int j = 0; j < 4; ++j) { myred[j] = sx[j]; myred[4 + j] = sxx[j]; }
  __syncthreads();

  if (wave == 0) {
#pragma unroll
    for (int j = 0; j < 4; ++j) {
      float fsx = red[lane * RS + j] + red[(64 + lane) * RS + j] +
                  red[(128 + lane) * RS + j] + red[(192 + lane) * RS + j];
      float fsxx = red[lane * RS + 4 + j] + red[(64 + lane) * RS + 4 + j] +
                   red[(128 + lane) * RS + 4 + j] + red[(192 + lane) * RS + 4 + j];
      float mean = fsx / cnt;
      float sub = ms[c0 + j] * mean;
      float var = fsxx / cnt - 2.f * sub * mean + sub * sub;
      var = fmaxf(var, 0.f);
      prm[lane * PS + j] = sub;
      prm[lane * PS + 4 + j] = rsqrtf(var + 1e-5f) * w[c0 + j];
      prm[lane * PS + 8 + j] = b[c0 + j];
    }
  }
  __syncthreads();
  float sub[4], inv[4], bb[4];
#pragma unroll
  for (int j = 0; j < 4; ++j) {
    sub[j] = prm[lane * PS + j];
    inv[j] = prm[lane * PS + 4 + j];
    bb[j] = prm[lane * PS + 8 + j];
  }

  float psum[4] = {0.f, 0.f, 0.f, 0.f};
  {
    int i = s + wave;
    for (; i + 4 < e; i += 8) {
      bf16x4 x0 = *(const bf16x4*)(v + (size_t)i * H + c0);
      bf16x4 x1 = *(const bf16x4*)(v + (size_t)(i + 4) * H + c0);
      union { bf16x4 o; uint2 u; } p0, p1;
#pragma unroll
      for (int j = 0; j < 4; ++j) {
        float o0 = ((float)x0[j] - sub[j]) * inv[j] + bb[j];
        float o1 = ((float)x1[j] - sub[j]) * inv[j] + bb[j];
        o0 = o0 > 0.f ? o0 : 0.f;
        o1 = o1 > 0.f ? o1 : 0.f;
        psum[j] += o0 + o1;
        p0.o[j] = (bf16_t)o0; p1.o[j] = (bf16_t)o1;
      }
      *(uint2*)(hout + (size_t)i * H + c0) = p0.u;
      *(uint2*)(hout + (size_t)(i + 4) * H + c0) = p1.u;
    }
    if (i < e) {
      bf16x4 x0 = *(const bf16x4*)(v + (size_t)i * H + c0);
      union { bf16x4 o; uint2 u; } p0;
#pragma unroll
      for (int j = 0; j < 4; ++j) {
        float o0 = ((float)x0[j] - sub[j]) * inv[j] + bb[j];
        o0 = o0 > 0.f ? o0 : 0.f;
        psum[j] += o0;
        p0.o[j] = (bf16_t)o0;
      }
      *(uint2*)(hout + (size_t)i * H + c0) = p0.u;
    }
  }

  if (hg) {
#pragma unroll
    for (int j = 0; j < 4; ++j) myred[j] = psum[j];
    __syncthreads();
    if (wave == 0) {
#pragma unroll
      for (int j = 0; j < 4; ++j) {
        float p = red[lane * RS + j] + red[(64 + lane) * RS + j] +
                  red[(128 + lane) * RS + j] + red[(192 + lane) * RS + j];
        hg[(size_t)g * H + c0 + j] = p / cnt;
      }
    }
  }
}

// ---------- fully fused heads: hg -> zi, zs, yhat, envhat (1 launch) -----
// Every head op is row-local (each graph-row's chain is independent), so a
// 64-row block runs the whole chain with weights from L2 and intermediates
// in LDS. Numerically identical to the old 4-dispatch chain: t1/t2 bf16,
// zi/zs f32 out (zi ALSO rounded to bf16 for the next stage, exactly like
// the old load8_to_lds(float) conversion did), p1/a1 bf16, f32 tail.
__global__ __launch_bounds__(256) void heads_fused_kernel(
    const float* __restrict__ hg,
    const bf16_t* __restrict__ fT1, const float* __restrict__ fb1,
    const bf16_t* __restrict__ fT2, const float* __restrict__ fb2,
    const bf16_t* __restrict__ sT1, const float* __restrict__ sb1,
    const bf16_t* __restrict__ sT2, const float* __restrict__ sb2,
    const bf16_t* __restrict__ pT1, const float* __restrict__ pb1,
    const bf16_t* __restrict__ aT1, const float* __restrict__ ab1,
    const float* __restrict__ pW2, const float* __restrict__ pb2,
    const float* __restrict__ aW2, const float* __restrict__ ab2,
    float* __restrict__ out_zi, float* __restrict__ out_zs,
    float* __restrict__ out_yh, float* __restrict__ out_ev) {
  constexpr int LDS_S = 264;            // 256 + 8 pad (bf16)
  constexpr int LDZ = 136;              // 128 + 8 pad
  __shared__ bf16_t BufA[64 * LDS_S];   // Hg (stages 0-1), then PA (3-4)
  __shared__ bf16_t BufB[64 * LDS_S];   // T12 = [t1 | t2]
  __shared__ bf16_t Z[64 * LDZ];        // zi (bf16)
  const int t = threadIdx.x;
  const int lane = t & 63;
  const int wave = t >> 6;              // 0..3
  const int m0 = blockIdx.x * 64;
  const int lr = lane & 15;
  const int lq = lane >> 4;

  // ---- stage 0: hg (f32) -> BufA (bf16) --------------------------------
  {
    int r = t >> 2, cb = (t & 3) * 64;
    const float* src = hg + (size_t)(m0 + r) * H + cb;
#pragma unroll
    for (int q = 0; q < 8; ++q)
      load8_to_lds(src + q * 8, true, (uint4*)&BufA[r * LDS_S + cb + q * 8]);
  }
  __syncthreads();

  f32x4 acc[4][4];

  // ---- stage 1: T12 = relu(Hg @ [fT1|sT1] + b1)   (K=256) ---------------
  {
    const bf16_t* W = (wave < 2) ? fT1 : sT1;
    const float* bb = (wave < 2) ? fb1 : sb1;
    const int wnl = (wave & 1) * 64;
    const int wcol = wave * 64;
#pragma unroll
    for (int mt = 0; mt < 4; ++mt)
#pragma unroll
      for (int nt = 0; nt < 4; ++nt) { f32x4 z = {}; acc[mt][nt] = z; }
    for (int k0 = 0; k0 < 256; k0 += 32) {
      bf16x8 a[4], b[4];
#pragma unroll
      for (int nt = 0; nt < 4; ++nt)
        b[nt] = *(const bf16x8*)(W + (size_t)(wnl + nt * 16 + lr) * 256 + k0 + lq * 8);
#pragma unroll
      for (int mt = 0; mt < 4; ++mt)
        a[mt] = *(const bf16x8*)(&BufA[(mt * 16 + lr) * LDS_S + k0 + lq * 8]);
#pragma unroll
      for (int mt = 0; mt < 4; ++mt)
#pragma unroll
        for (int nt = 0; nt < 4; ++nt)
          acc[mt][nt] = __builtin_amdgcn_mfma_f32_16x16x32_bf16(
              a[mt], b[nt], acc[mt][nt], 0, 0, 0);
    }
    __syncthreads();   // everyone done reading BufA region for this stage
#pragma unroll
    for (int nt = 0; nt < 4; ++nt) {
      float bv = bb[wnl + nt * 16 + lr];
      int col = wcol + nt * 16 + lr;
#pragma unroll
      for (int mt = 0; mt < 4; ++mt)
#pragma unroll
        for (int r = 0; r < 4; ++r) {
          int row = mt * 16 + lq * 4 + r;
          float vv = acc[mt][nt][r] + bv;
          BufB[row * LDS_S + col] = (bf16_t)(vv > 0.f ? vv : 0.f);
        }
    }
  }
  __syncthreads();

  // ---- stage 2: zi|zs = T12 @ [fT2|sT2] + b2   (K=128, f32 out) ---------
  {
    const bf16_t* W = (wave < 2) ? fT2 : sT2;
    const float* bb = (wave < 2) ? fb2 : sb2;
    float* outp = (wave < 2) ? out_zi : out_zs;
    const int wnl = (wave & 1) * 64;
    const int kin = (wave < 2) ? 0 : 128;
#pragma unroll
    for (int mt = 0; mt < 4; ++mt)
#pragma unroll
      for (int nt = 0; nt < 4; ++nt) { f32x4 z = {}; acc[mt][nt] = z; }
    for (int k0 = 0; k0 < 128; k0 += 32) {
      bf16x8 a[4], b[4];
#pragma unroll
      for (int nt = 0; nt < 4; ++nt)
        b[nt] = *(const bf16x8*)(W + (size_t)(wnl + nt * 16 + lr) * 128 + k0 + lq * 8);
#pragma unroll
      for (int mt = 0; mt < 4; ++mt)
        a[mt] = *(const bf16x8*)(&BufB[(mt * 16 + lr) * LDS_S + kin + k0 + lq * 8]);
#pragma unroll
      for (int mt = 0; mt < 4; ++mt)
#pragma unroll
        for (int nt = 0; nt < 4; ++nt)
          acc[mt][nt] = __builtin_amdgcn_mfma_f32_16x16x32_bf16(
              a[mt], b[nt], acc[mt][nt], 0, 0, 0);
    }
#pragma unroll
    for (int nt = 0; nt < 4; ++nt) {
      int col = wnl + nt * 16 + lr;
      float bv = bb[col];
#pragma unroll
      for (int mt = 0; mt < 4; ++mt)
#pragma unroll
        for (int r = 0; r < 4; ++r) {
          int row = mt * 16 + lq * 4 + r;
          float vv = acc[mt][nt][r] + bv;
          outp[(size_t)(m0 + row) * ZIC + col] = vv;
          if (wave < 2) Z[row * LDZ + col] = (bf16_t)vv;
        }
    }
  }
  __syncthreads();

  // ---- stage 3: PA = relu(Z @ [pT1|aT1] + b)   (K=128) into BufA --------
  {
    const bf16_t* W = (wave < 2) ? pT1 : aT1;
    const float* bb = (wave < 2) ? pb1 : ab1;
    const int wnl = (wave & 1) * 64;
    const int wcol = wave * 64;
#pragma unroll
    for (int mt = 0; mt < 4; ++mt)
#pragma unroll
      for (int nt = 0; nt < 4; ++nt) { f32x4 z = {}; acc[mt][nt] = z; }
    for (int k0 = 0; k0 < 128; k0 += 32) {
      bf16x8 a[4], b[4];
#pragma unroll
      for (int nt = 0; nt < 4; ++nt)
        b[nt] = *(const bf16x8*)(W + (size_t)(wnl + nt * 16 + lr) * 128 + k0 + lq * 8);
#pragma unroll
      for (int mt = 0; mt < 4; ++mt)
        a[mt] = *(const bf16x8*)(&Z[(mt * 16 + lr) * LDZ + k0 + lq * 8]);
#pragma unroll
      for (int mt = 0; mt < 4; ++mt)
#pragma unroll
        for (int nt = 0; nt < 4; ++nt)
          acc[mt][nt] = __builtin_amdgcn_mfma_f32_16x16x32_bf16(
              a[mt], b[nt], acc[mt][nt], 0, 0, 0);
    }
#pragma unroll
    for (int nt = 0; nt < 4; ++nt) {
      float bv = bb[wnl + nt * 16 + lr];
      int col = wcol + nt * 16 + lr;
#pragma unroll
      for (int mt = 0; mt < 4; ++mt)
#pragma unroll
        for (int r = 0; r < 4; ++r) {
          int row = mt * 16 + lq * 4 + r;
          float vv = acc[mt][nt][r] + bv;
          BufA[row * LDS_S + col] = (bf16_t)(vv > 0.f ? vv : 0.f);
        }
    }
  }
  __syncthreads();

  // ---- stage 4: yh = p1 @ pW2 + pb2 ; ev = a1 @ aW2 + ab2 ---------------
  if (t < 64) {
    float a4 = pb2[0];
    for (int k = 0; k < 128; ++k)
      a4 += (float)BufA[t * LDS_S + k] * pW2[k];
    out_yh[m0 + t] = a4;
  }
#pragma unroll
  for (int pass = 0; pass < 2; ++pass) {
    int j = pass * 256 + t;
    int r = j >> 3, n = j & 7;
    float a4 = ab2[n];
    for (int k = 0; k < 128; ++k)
      a4 += (float)BufA[r * LDS_S + 128 + k] * aW2[k * 8 + n];
    out_ev[(size_t)(m0 + r) * NE + n] = a4;
  }
}

extern "C" void kernel_launch(void* const* d_in, const int* in_sizes, int n_in,
                              void* d_out, int out_size, void* d_ws, size_t ws_size,
                              hipStream_t stream) {
  (void)in_sizes; (void)n_in; (void)out_size; (void)ws_size;
  const float* x        = (const float*)d_in[0];
  const int*   eidx     = (const int*)d_in[1];
  const float* eattr    = (const float*)d_in[2];
  const int*   batch    = (const int*)d_in[3];
  const float* node_W   = (const float*)d_in[4];
  const float* node_b   = (const float*)d_in[5];
  const float* conv_eps = (const float*)d_in[6];
  const float* edge_W   = (const float*)d_in[7];
  const float* edge_b   = (const float*)d_in[8];
  const float* mlp_W1   = (const float*)d_in[9];
  const float* mlp_b1   = (const float*)d_in[10];
  const float* mlp_W2   = (const float*)d_in[11];
  const float* mlp_b2   = (const float*)d_in[12];
  const float* gn_w     = (const float*)d_in[13];
  const float* gn_b     = (const float*)d_in[14];
  const float* gn_ms    = (const float*)d_in[15];
  const float* finv_W1  = (const float*)d_in[16];
  const float* finv_b1  = (const float*)d_in[17];
  const float* finv_W2  = (const float*)d_in[18];
  const float* finv_b2  = (const float*)d_in[19];
  const float* fspu_W1  = (const float*)d_in[20];
  const float* fspu_b1  = (const float*)d_in[21];
  const float* fspu_W2  = (const float*)d_in[22];
  const float* fspu_b2  = (const float*)d_in[23];
  const float* pred_W1  = (const float*)d_in[24];
  const float* pred_b1  = (const float*)d_in[25];
  const float* pred_W2  = (const float*)d_in[26];
  const float* pred_b2  = (const float*)d_in[27];
  const float* adv_W1   = (const float*)d_in[28];
  const float* adv_b1   = (const float*)d_in[29];
  const float* adv_W2   = (const float*)d_in[30];
  const float* adv_b2   = (const float*)d_in[31];
  float* out = (float*)d_out;

  float* out_hg = out;                                  // [G,H]
  float* out_zi = out + (size_t)N_GRAPH * H;            // [G,ZI]
  float* out_zs = out_zi + (size_t)N_GRAPH * ZIC;       // [G,ZS]
  float* out_yh = out_zs + (size_t)N_GRAPH * ZIC;       // [G]
  float* out_ev = out_yh + N_GRAPH;                     // [G,NE]

  // workspace carve-up (~118 MiB total)
  char* wp = (char*)d_ws;
  auto alloc = [&](size_t bytes) { char* p = wp; wp += (bytes + 255) & ~(size_t)255; return p; };
  bf16_t* A        = (bf16_t*)alloc((size_t)N_NODES * H * 2);   // h / t
  bf16_t* B        = (bf16_t*)alloc((size_t)N_NODES * H * 2);   // u / v
  bf16_t* Wt       = (bf16_t*)alloc((size_t)(H * ND + 6 * H * H) * 2);
  bf16_t* WtH      = (bf16_t*)alloc((size_t)(2 * ZIC * H + 4 * ZIC * ZIC) * 2);
  bf16_t* ewt16    = (bf16_t*)alloc((size_t)3 * 256 * 16 * 2);
  bf16_t* eat16    = (bf16_t*)alloc((size_t)N_EDGES * 16 * 2);
  int*    starts   = (int*)alloc((size_t)(N_GRAPH + 1) * 4);
  int*    counts   = (int*)alloc((size_t)N_NODES * 4);
  int*    cursor   = (int*)alloc((size_t)N_NODES * 4);
  int*    offs     = (int*)alloc((size_t)(N_NODES + 1) * 4);
  int*    bsum     = (int*)alloc((size_t)SCAN_B * 4);
  int*    src_srt  = (int*)alloc((size_t)N_EDGES * 4);

  const int* srcp = eidx;
  const int* dstp = eidx + N_EDGES;
  const int nscan = (N_NODES + SCAN_B - 1) / SCAN_B;

  compute_starts_kernel<<<(N_NODES + 255) / 256, 256, 0, stream>>>(
      batch, starts, counts, cursor, N_NODES, N_GRAPH);
  count_deg_kernel<<<(N_EDGES + 255) / 256, 256, 0, stream>>>(dstp, counts, N_EDGES, N_NODES);
  scan1_kernel<<<nscan, SCAN_B, 0, stream>>>(counts, offs, bsum, N_NODES);
  scan2_kernel<<<1, 64, 0, stream>>>(bsum, nscan);
  scan3_kernel<<<nscan, SCAN_B, 0, stream>>>(offs, bsum, N_NODES);
  fill_scatter_kernel<<<(N_EDGES + 255) / 256, 256, 0, stream>>>(
      srcp, dstp, eattr, offs, cursor, src_srt, eat16, N_EDGES, N_NODES);
  build_ewt16_kernel<<<(3 * 256 * 16 + 255) / 256, 256, 0, stream>>>(edge_W, ewt16);

  bf16_t* WtN = Wt;
  bf16_t* Wt1base = Wt + H * ND;                      // l-th at stride 2*H*H
  bf16_t* Wt2base = Wt + H * ND + (size_t)H * H;      // l-th at stride 2*H*H
  auto Wt1l = [&](int l) { return Wt1base + (size_t)(2 * l) * H * H; };
  auto Wt2l = [&](int l) { return Wt2base + (size_t)(2 * l) * H * H; };
  transpose_kernel<<<dim3(H / 32, ND / 32, 1), dim3(32, 8), 0, stream>>>(node_W, WtN, ND, H, 0, 0);
  transpose_kernel<<<dim3(H / 32, H / 32, 3), dim3(32, 8), 0, stream>>>(
      mlp_W1, Wt1base, H, H, (size_t)H * H, (size_t)2 * H * H);
  transpose_kernel<<<dim3(H / 32, H / 32, 3), dim3(32, 8), 0, stream>>>(
      mlp_W2, Wt2base, H, H, (size_t)H * H, (size_t)2 * H * H);

  bf16_t* fT1 = WtH;                          // [128 x 256]
  bf16_t* fT2 = fT1 + ZIC * H;                // [128 x 128]
  bf16_t* sT1 = fT2 + ZIC * ZIC;              // [128 x 256]
  bf16_t* sT2 = sT1 + ZIC * H;                // [128 x 128]
  bf16_t* pT1 = sT2 + ZIC * ZIC;              // [128 x 128]
  bf16_t* aT1 = pT1 + ZIC * ZIC;              // [128 x 128]
  transpose_kernel<<<dim3(ZIC / 32, H / 32, 1), dim3(32, 8), 0, stream>>>(finv_W1, fT1, H, ZIC, 0, 0);
  transpose_kernel<<<dim3(ZIC / 32, ZIC / 32, 1), dim3(32, 8), 0, stream>>>(finv_W2, fT2, ZIC, ZIC, 0, 0);
  transpose_kernel<<<dim3(ZIC / 32, H / 32, 1), dim3(32, 8), 0, stream>>>(fspu_W1, sT1, H, ZIC, 0, 0);
  transpose_kernel<<<dim3(ZIC / 32, ZIC / 32, 1), dim3(32, 8), 0, stream>>>(fspu_W2, sT2, ZIC, ZIC, 0, 0);
  transpose_kernel<<<dim3(ZIC / 32, ZIC / 32, 1), dim3(32, 8), 0, stream>>>(pred_W1, pT1, ZIC, ZIC, 0, 0);
  transpose_kernel<<<dim3(ZIC / 32, ZIC / 32, 1), dim3(32, 8), 0, stream>>>(adv_W1, aT1, ZIC, ZIC, 0, 0);

  dim3 ggrid((N_NODES + 127) / 128, H / 128);
  // h = x @ node_W + node_b (fp32 input -> VGPR-staging kernel)
  gemm128_kernel<ND, false, false><<<ggrid, 256, 0, stream>>>(x, WtN, node_b, A, N_NODES, H);

  const int mblocks = (N_NODES + 127) / 128;
  for (int l = 0; l < 3; ++l) {
    gine_gather_mfma_kernel<<<N_NODES / 4, 256, 0, stream>>>(
        A, eat16, src_srt, offs, ewt16 + (size_t)l * 256 * 16,
        edge_b + l * H, conv_eps + l, B);
    gemm256_dma_kernel<H, true ><<<mblocks, 512, 0, stream>>>(B, Wt1l(l), mlp_b1 + l * H, A, N_NODES);
    gemm256_dma_kernel<H, false><<<mblocks, 512, 0, stream>>>(A, Wt2l(l), mlp_b2 + l * H, B, N_NODES);
    graphnorm_kernel<<<N_GRAPH, 256, 0, stream>>>(B, A, starts, gn_w + l * H, gn_b + l * H,
                                                  gn_ms + l * H, (l == 2) ? out_hg : nullptr);
  }

  // all four head stages in one launch (row-local chain)
  heads_fused_kernel<<<N_GRAPH / 64, 256, 0, stream>>>(
      out_hg,
      fT1, finv_b1, fT2, finv_b2,
      sT1, fspu_b1, sT2, fspu_b2,
      pT1, pred_b1, aT1, adv_b1,
      pred_W2, pred_b2, adv_W2, adv_b2,
      out_zi, out_zs, out_yh, out_ev);
}

// Round 9
// 691.745 us; speedup vs baseline: 1.0923x; 1.0445x over previous
//
#include <hip/hip_runtime.h>
#include <hip/hip_bf16.h>

typedef __bf16 bf16_t;
typedef __bf16 bf16x8 __attribute__((ext_vector_type(8)));
typedef __bf16 bf16x4 __attribute__((ext_vector_type(4)));
typedef float  f32x4  __attribute__((ext_vector_type(4)));

static constexpr int N_NODES = 100000;
static constexpr int N_EDGES = 300000;
static constexpr int N_GRAPH = 4096;
static constexpr int H  = 256;
static constexpr int ND = 64;
static constexpr int ZIC = 128;
static constexpr int NE = 8;
static constexpr int SCAN_B = 1024;

__device__ __forceinline__ int clampi(int v, int lo, int hi) {
  return v < lo ? lo : (v > hi ? hi : v);
}

// async 16B global -> LDS (wave-uniform LDS base + lane*16)
__device__ __forceinline__ void dma16(const bf16_t* g, bf16_t* lds_base) {
  __builtin_amdgcn_global_load_lds(
      (const __attribute__((address_space(1))) void*)g,
      (__attribute__((address_space(3))) void*)lds_base, 16, 0, 0);
}

// ------- graph segment starts (batch sorted) + zero counts/cursor --------
__global__ void compute_starts_kernel(const int* __restrict__ batch,
                                      int* __restrict__ starts,
                                      int* __restrict__ counts,
                                      int* __restrict__ cursor, int N, int G) {
  int i = blockIdx.x * blockDim.x + threadIdx.x;
  if (i >= N) return;
  counts[i] = 0;
  cursor[i] = 0;
  int b = clampi(batch[i], 0, G - 1);
  if (i == 0) {
    for (int g = 0; g <= b; ++g) starts[g] = 0;
  } else {
    int p = clampi(batch[i - 1], 0, G - 1);
    for (int g = p + 1; g <= b; ++g) starts[g] = i;
  }
  if (i == N - 1) {
    for (int g = b + 1; g <= G; ++g) starts[g] = N;
  }
}

// ---------------- CSR build ----------------
__global__ void count_deg_kernel(const int* __restrict__ dst, int* __restrict__ counts, int E, int N) {
  int e = blockIdx.x * blockDim.x + threadIdx.x;
  if (e < E) atomicAdd(&counts[clampi(dst[e], 0, N - 1)], 1);
}

__global__ __launch_bounds__(SCAN_B) void scan1_kernel(const int* __restrict__ counts,
                                                       int* __restrict__ offs,
                                                       int* __restrict__ bsum, int N) {
  __shared__ int tmp[SCAN_B];
  int i = blockIdx.x * SCAN_B + threadIdx.x;
  int v = (i < N) ? counts[i] : 0;
  tmp[threadIdx.x] = v;
  __syncthreads();
  for (int d = 1; d < SCAN_B; d <<= 1) {
    int t = (threadIdx.x >= d) ? tmp[threadIdx.x - d] : 0;
    __syncthreads();
    tmp[threadIdx.x] += t;
    __syncthreads();
  }
  if (i < N) offs[i + 1] = tmp[threadIdx.x];
  if (threadIdx.x == SCAN_B - 1) bsum[blockIdx.x] = tmp[SCAN_B - 1];
  if (i == 0) offs[0] = 0;
}

__global__ void scan2_kernel(int* __restrict__ bsum, int nblk) {
  if (blockIdx.x == 0 && threadIdx.x == 0) {
    int run = 0;
    for (int b = 0; b < nblk; ++b) { int v = bsum[b]; bsum[b] = run; run += v; }
  }
}

__global__ __launch_bounds__(SCAN_B) void scan3_kernel(int* __restrict__ offs,
                                                       const int* __restrict__ bsum, int N) {
  int i = blockIdx.x * SCAN_B + threadIdx.x;
  if (i < N) offs[i + 1] += bsum[blockIdx.x];
}

// fused: compute position AND scatter src_sorted + eattr(bf16) in one pass
__global__ void fill_scatter_kernel(const int* __restrict__ src, const int* __restrict__ dst,
                                    const float* __restrict__ eattr,
                                    const int* __restrict__ offs, int* __restrict__ cursor,
                                    int* __restrict__ src_srt, bf16_t* __restrict__ eat16,
                                    int E, int N) {
  int e = blockIdx.x * blockDim.x + threadIdx.x;
  if (e >= E) return;
  int d = clampi(dst[e], 0, N - 1);
  int pos = offs[d] + atomicAdd(&cursor[d], 1);
  if ((unsigned)pos >= (unsigned)E) return;
  int s = src[e];
  src_srt[pos] = ((unsigned)s < (unsigned)N_NODES) ? s : 0;
  const float* ea = eattr + (size_t)e * 16;
  union { bf16_t b[16]; uint4 u[2]; } pk;
#pragma unroll
  for (int k = 0; k < 16; ++k) pk.b[k] = (bf16_t)ea[k];
  uint4* dst16 = (uint4*)(eat16 + ((size_t)pos << 4));
  dst16[0] = pk.u[0];
  dst16[1] = pk.u[1];
}

// edge_W[l] (16 x 256) -> eWt[l] (256 rows x 16 cols), bf16  (v6 layout)
__global__ void build_ewt16_kernel(const float* __restrict__ edge_W,
                                   bf16_t* __restrict__ ewt) {
  int idx = blockIdx.x * blockDim.x + threadIdx.x;
  if (idx >= 3 * 256 * 16) return;
  int l = idx / (256 * 16);
  int rem = idx - l * 256 * 16;
  int n = rem >> 4, k = rem & 15;
  ewt[idx] = (bf16_t)edge_W[(size_t)l * 16 * 256 + k * 256 + n];
}

// -------- fp32 transpose + bf16 cast: W[K x Nc] -> Wt[Nc x K] (bf16) ------
__global__ void transpose_kernel(const float* __restrict__ W,
                                 bf16_t* __restrict__ Wt, int K, int Nc,
                                 size_t srcStride, size_t dstStride) {
  __shared__ float tile[32][33];
  const float* Wz = W + (size_t)blockIdx.z * srcStride;
  bf16_t* Wtz = Wt + (size_t)blockIdx.z * dstStride;
  int n0 = blockIdx.x * 32, k0 = blockIdx.y * 32;
  int tx = threadIdx.x, ty = threadIdx.y;
  for (int i = ty; i < 32; i += 8)
    tile[i][tx] = Wz[(size_t)(k0 + i) * Nc + n0 + tx];
  __syncthreads();
  for (int i = ty; i < 32; i += 8)
    Wtz[(size_t)(n0 + i) * K + k0 + tx] = (bf16_t)tile[tx][i];
}

// ---- staging loaders: 8 contiguous elements -> 8 bf16 (16B) in LDS ----
__device__ __forceinline__ void load8_to_lds(const bf16_t* p, bool valid, uint4* dst) {
  uint4 v = make_uint4(0u, 0u, 0u, 0u);
  if (valid) v = *(const uint4*)p;
  *dst = v;
}
__device__ __forceinline__ void load8_to_lds(const float* p, bool valid, uint4* dst) {
  float4 f0 = make_float4(0.f, 0.f, 0.f, 0.f), f1 = f0;
  if (valid) { f0 = *(const float4*)p; f1 = *(const float4*)(p + 4); }
  union { bf16_t b[8]; uint4 u; } pk;
  pk.b[0] = (bf16_t)f0.x; pk.b[1] = (bf16_t)f0.y;
  pk.b[2] = (bf16_t)f0.z; pk.b[3] = (bf16_t)f0.w;
  pk.b[4] = (bf16_t)f1.x; pk.b[5] = (bf16_t)f1.y;
  pk.b[6] = (bf16_t)f1.z; pk.b[7] = (bf16_t)f1.w;
  *dst = pk.u;
}

// ------- node linear: 128x256 tile, K=64, f32 input, single K-step -------
// Replaces the old 128x128-tile gemm128 (which read x twice, once per
// N-tile). A staged f32->bf16 into padded-LDT LDS (no conflicts); W staged
// via the proven dma16 + pre-swizzled-source + XOR-read path.
template<int K>   // K == ND == 64
__global__ __launch_bounds__(512) void gemm_node_kernel(
    const float* __restrict__ U, const bf16_t* __restrict__ Wt,
    const float* __restrict__ bias, bf16_t* __restrict__ Out, int M) {
  constexpr int LDT = 72;
  __shared__ bf16_t Ut[128 * LDT];   // 18 KB padded
  __shared__ bf16_t Wl[256 * 64];    // 32 KB dma16-swizzled
  const int t = threadIdx.x;
  const int lane = t & 63;
  const int wave = t >> 6;                 // 0..7
  const int m0 = blockIdx.x * 128;
  const int wm = (wave >> 2) * 64;         // 0,64
  const int wn = (wave & 3) * 64;          // 0,64,128,192
  const int lr = lane & 15;
  const int lq = lane >> 4;
  const int subrow = lane >> 3;            // 0..7
  const int lchunk = (lane & 7) ^ subrow;  // pre-swizzled col chunk
  f32x4 acc[4][4] = {};

  // stage A: thread t covers row t>>2, cols (t&3)*16 .. +15 (f32 -> bf16)
  {
    int r = t >> 2, c0 = (t & 3) * 16;
    int ur = m0 + r;
    bool ok = ur < M;
    const float* up = U + (size_t)ur * K + c0;
    load8_to_lds(up,     ok, (uint4*)&Ut[r * LDT + c0]);
    load8_to_lds(up + 8, ok, (uint4*)&Ut[r * LDT + c0 + 8]);
  }
  // stage W (256 rows x 64 cols) via dma16
#pragma unroll
  for (int c = 0; c < 4; ++c) {
    int wrow = c * 64 + wave * 8 + subrow;
    dma16(Wt + (size_t)wrow * K + lchunk * 8, &Wl[(c * 64 + wave * 8) * 64]);
  }
  __syncthreads();
#pragma unroll
  for (int s = 0; s < 2; ++s) {
    bf16x8 a[4], b[4];
#pragma unroll
    for (int mt = 0; mt < 4; ++mt)
      a[mt] = *(const bf16x8*)(&Ut[(wm + mt * 16 + lr) * LDT + s * 32 + lq * 8]);
#pragma unroll
    for (int nt = 0; nt < 4; ++nt)
      b[nt] = *(const bf16x8*)(&Wl[(wn + nt * 16 + lr) * 64 + (((s * 4 + lq) ^ (lr & 7)) << 3)]);
#pragma unroll
    for (int mt = 0; mt < 4; ++mt)
#pragma unroll
      for (int nt = 0; nt < 4; ++nt)
        acc[mt][nt] = __builtin_amdgcn_mfma_f32_16x16x32_bf16(
            a[mt], b[nt], acc[mt][nt], 0, 0, 0);
  }

#pragma unroll
  for (int mt = 0; mt < 4; ++mt)
#pragma unroll
    for (int nt = 0; nt < 4; ++nt) {
      int col = wn + nt * 16 + lr;
      float bcol = bias[col];
#pragma unroll
      for (int r = 0; r < 4; ++r) {
        int row = m0 + wm + mt * 16 + lq * 4 + r;
        if (row < M) {
          float vv = acc[mt][nt][r] + bcol;
          Out[(size_t)row * H + col] = (bf16_t)vv;
        }
      }
    }
}

// ------- MFMA GEMM 128x256 (full-H tile), bf16 in, dma16 + XOR swizzle ----
// 512 threads / 8 waves (2 M x 4 N). Reads A once per GEMM. (round-5 proven)
template<int K, bool RELU>
__global__ __launch_bounds__(512) void gemm256_dma_kernel(
    const bf16_t* __restrict__ U, const bf16_t* __restrict__ Wt,
    const float* __restrict__ bias, bf16_t* __restrict__ Out, int M) {
  __shared__ bf16_t Ut[128 * 64];   // 16 KB
  __shared__ bf16_t Wl[256 * 64];   // 32 KB
  const int t = threadIdx.x;
  const int lane = t & 63;
  const int wave = t >> 6;                 // 0..7
  const int m0 = blockIdx.x * 128;
  const int wm = (wave >> 2) * 64;         // 0,64
  const int wn = (wave & 3) * 64;          // 0,64,128,192
  const int lr = lane & 15;
  const int lq = lane >> 4;
  const int subrow = lane >> 3;            // 0..7 within 8-row group
  const int lchunk = (lane & 7) ^ subrow;  // pre-swizzled col chunk
  f32x4 acc[4][4] = {};

  for (int k0 = 0; k0 < K; k0 += 64) {
#pragma unroll
    for (int c = 0; c < 2; ++c) {
      int urow = m0 + c * 64 + wave * 8 + subrow;
      if (urow >= M) urow = M - 1;
      dma16(U + (size_t)urow * K + k0 + lchunk * 8, &Ut[(c * 64 + wave * 8) * 64]);
    }
#pragma unroll
    for (int c = 0; c < 4; ++c) {
      int wrow = c * 64 + wave * 8 + subrow;
      dma16(Wt + (size_t)wrow * K + k0 + lchunk * 8, &Wl[(c * 64 + wave * 8) * 64]);
    }
    __syncthreads();
#pragma unroll
    for (int s = 0; s < 2; ++s) {
      bf16x8 a[4], b[4];
#pragma unroll
      for (int mt = 0; mt < 4; ++mt)
        a[mt] = *(const bf16x8*)(&Ut[(wm + mt * 16 + lr) * 64 + (((s * 4 + lq) ^ (lr & 7)) << 3)]);
#pragma unroll
      for (int nt = 0; nt < 4; ++nt)
        b[nt] = *(const bf16x8*)(&Wl[(wn + nt * 16 + lr) * 64 + (((s * 4 + lq) ^ (lr & 7)) << 3)]);
#pragma unroll
      for (int mt = 0; mt < 4; ++mt)
#pragma unroll
        for (int nt = 0; nt < 4; ++nt)
          acc[mt][nt] = __builtin_amdgcn_mfma_f32_16x16x32_bf16(
              a[mt], b[nt], acc[mt][nt], 0, 0, 0);
    }
    __syncthreads();
  }

#pragma unroll
  for (int mt = 0; mt < 4; ++mt)
#pragma unroll
    for (int nt = 0; nt < 4; ++nt) {
      int col = wn + nt * 16 + lr;
      float bcol = bias[col];
#pragma unroll
      for (int r = 0; r < 4; ++r) {
        int row = m0 + wm + mt * 16 + lq * 4 + r;
        if (row < M) {
          float vv = acc[mt][nt][r] + bcol;
          if (RELU) vv = vv > 0.f ? vv : 0.f;
          Out[(size_t)row * H + col] = (bf16_t)vv;
        }
      }
    }
}

// ---------------- fused GINE gather with MFMA edge-linear (v9) -----------
// v9 = v6 + edge bias folded into the slin WRITE: slin = bf16(c + eb[col]).
// Removes one f32 add per channel from the VALU-bound consume loop (6->5
// ops). Unlike the failed v5 C-in fold this costs only 4 scalar floats
// (ebw[4] replaces ebv[4], net-zero VGPR), not 16 live f32x4 registers.
__global__ __launch_bounds__(256) void gine_gather_mfma_kernel(
    const bf16_t* __restrict__ h, const bf16_t* __restrict__ eat16,
    const int* __restrict__ src_sorted, const int* __restrict__ offs,
    const bf16_t* __restrict__ ewt, const float* __restrict__ eb,
    const float* __restrict__ eps_p, bf16_t* __restrict__ u) {
  constexpr int HP = H + 8;
  __shared__ bf16_t slin[2][16 * HP];  // 16.9 KB
  const int t = threadIdx.x;
  const int wave = t >> 6;
  const int lane = t & 63;
  const int lr = lane & 15;
  const int lq = lane >> 4;
  const int lane4 = lane * 4;
  const int n0 = blockIdx.x * 4;
  const int nodeN = n0 + wave;

  bf16x4 hs = *(const bf16x4*)(h + (size_t)nodeN * H + lane4);

  bf16x8 bfrag[4];
  float ebw[4];
#pragma unroll
  for (int nt = 0; nt < 4; ++nt) {
    bf16x8 bv = {};
    if (lq < 2)
      bv = *(const bf16x8*)(ewt + ((wave * 64 + nt * 16 + lr) << 4) + (lq << 3));
    bfrag[nt] = bv;
    ebw[nt] = eb[wave * 64 + nt * 16 + lr];   // bias of this lane's write-col
  }

  int bs = offs[n0], be = offs[n0 + 4];
  bs = clampi(bs, 0, N_EDGES);
  be = clampi(be, bs, N_EDGES);
  int ns = offs[nodeN], ne = offs[nodeN + 1];
  ns = clampi(ns, bs, be);
  ne = clampi(ne, ns, be);

  float acc[4] = {0.f, 0.f, 0.f, 0.f};
  int parity = 0;

  for (int cb = bs; cb < be; cb += 16, parity ^= 1) {
    int arow = cb + lr;
    if (arow >= N_EDGES) arow = N_EDGES - 1;
    bf16x8 afrag = {};
    if (lq < 2)
      afrag = *(const bf16x8*)(eat16 + ((size_t)arow << 4) + (lq << 3));

    int j0 = ns > cb ? ns : cb;
    int j1 = ne < cb + 16 ? ne : cb + 16;
    int sidx[4];
    bf16x4 hv[4];
    if (j0 < j1) {
#pragma unroll
      for (int q = 0; q < 4; ++q) {
        int jj = j0 + q; if (jj > j1 - 1) jj = j1 - 1;
        sidx[q] = src_sorted[jj];
      }
    }

    f32x4 c[4];
#pragma unroll
    for (int nt = 0; nt < 4; ++nt) {
      f32x4 z = {};
      c[nt] = __builtin_amdgcn_mfma_f32_16x16x32_bf16(afrag, bfrag[nt], z, 0, 0, 0);
    }
#pragma unroll
    for (int nt = 0; nt < 4; ++nt)
#pragma unroll
      for (int r = 0; r < 4; ++r)
        slin[parity][(lq * 4 + r) * HP + wave * 64 + nt * 16 + lr] =
            (bf16_t)(c[nt][r] + ebw[nt]);

    if (j0 < j1) {
#pragma unroll
      for (int q = 0; q < 4; ++q)
        hv[q] = *(const bf16x4*)(h + (size_t)sidx[q] * H + lane4);
    }

    __syncthreads();

    for (int jb = j0; jb < j1; jb += 4) {
      if (jb != j0) {
#pragma unroll
        for (int q = 0; q < 4; ++q) {
          int jj = jb + q; if (jj > j1 - 1) jj = j1 - 1;
          sidx[q] = src_sorted[jj];
        }
#pragma unroll
        for (int q = 0; q < 4; ++q)
          hv[q] = *(const bf16x4*)(h + (size_t)sidx[q] * H + lane4);
      }
#pragma unroll
      for (int q = 0; q < 4; ++q) {
        if (jb + q < j1) {
          bf16x4 lv = *(const bf16x4*)(&slin[parity][(jb + q - cb) * HP + lane4]);
#pragma unroll
          for (int i = 0; i < 4; ++i)
            acc[i] += fmaxf((float)hv[q][i] + (float)lv[i], 0.f);
        }
      }
    }
  }

  const float sc = 1.0f + eps_p[0];
  union { bf16x4 v; uint2 b; } o;
#pragma unroll
  for (int i = 0; i < 4; ++i) o.v[i] = (bf16_t)(sc * (float)hs[i] + acc[i]);
  *(uint2*)(u + (size_t)nodeN * H + lane4) = o.b;
}

// --- GraphNorm (+relu, + optional fused mean-pool) -----------------------
__global__ __launch_bounds__(256) void graphnorm_kernel(
    const bf16_t* __restrict__ v, bf16_t* __restrict__ hout,
    const int* __restrict__ starts,
    const float* __restrict__ w, const float* __restrict__ b,
    const float* __restrict__ ms, float* __restrict__ hg) {
  constexpr int RS = 9;    // red stride (floats) - odd to spread banks
  constexpr int PS = 13;   // prm stride (floats)
  __shared__ float red[4 * 64 * RS];   // 9.2 KB
  __shared__ float prm[64 * PS];       // 3.3 KB
  const int g = blockIdx.x;
  const int t = threadIdx.x;
  const int lane = t & 63;
  const int wave = t >> 6;
  const int c0 = lane * 4;
  int s = starts[g], e = starts[g + 1];
  s = clampi(s, 0, N_NODES);
  e = clampi(e, s, N_NODES);
  const float cnt = (float)((e - s) > 1 ? (e - s) : 1);

  float sx[4] = {0.f, 0.f, 0.f, 0.f}, sxx[4] = {0.f, 0.f, 0.f, 0.f};
  {
    int i = s + wave;
    for (; i + 4 < e; i += 8) {
      bf16x4 x0 = *(const bf16x4*)(v + (size_t)i * H + c0);
      bf16x4 x1 = *(const bf16x4*)(v + (size_t)(i + 4) * H + c0);
#pragma unroll
      for (int j = 0; j < 4; ++j) {
        float f0 = (float)x0[j], f1 = (float)x1[j];
        sx[j] += f0 + f1; sxx[j] += f0 * f0 + f1 * f1;
      }
    }
    if (i < e) {
      bf16x4 x0 = *(const bf16x4*)(v + (size_t)i * H + c0);
#pragma unroll
      for (int j = 0; j < 4; ++j) {
        float f0 = (float)x0[j];
        sx[j] += f0; sxx[j] += f0 * f0;
      }
    }
  }
  float* myred = &red[(wave * 64 + lane) * RS];
#pragma unroll
  for (int j = 0; j < 4; ++j) { myred[j] = sx[j]; myred[4 + j] = sxx[j]; }
  __syncthreads();

  if (wave == 0) {
#pragma unroll
    for (int j = 0; j < 4; ++j) {
      float fsx = red[lane * RS + j] + red[(64 + lane) * RS + j] +
                  red[(128 + lane) * RS + j] + red[(192 + lane) * RS + j];
      float fsxx = red[lane * RS + 4 + j] + red[(64 + lane) * RS + 4 + j] +
                   red[(128 + lane) * RS + 4 + j] + red[(192 + lane) * RS + 4 + j];
      float mean = fsx / cnt;
      float sub = ms[c0 + j] * mean;
      float var = fsxx / cnt - 2.f * sub * mean + sub * sub;
      var = fmaxf(var, 0.f);
      prm[lane * PS + j] = sub;
      prm[lane * PS + 4 + j] = rsqrtf(var + 1e-5f) * w[c0 + j];
      prm[lane * PS + 8 + j] = b[c0 + j];
    }
  }
  __syncthreads();
  float sub[4], inv[4], bb[4];
#pragma unroll
  for (int j = 0; j < 4; ++j) {
    sub[j] = prm[lane * PS + j];
    inv[j] = prm[lane * PS + 4 + j];
    bb[j] = prm[lane * PS + 8 + j];
  }

  float psum[4] = {0.f, 0.f, 0.f, 0.f};
  {
    int i = s + wave;
    for (; i + 4 < e; i += 8) {
      bf16x4 x0 = *(const bf16x4*)(v + (size_t)i * H + c0);
      bf16x4 x1 = *(const bf16x4*)(v + (size_t)(i + 4) * H + c0);
      union { bf16x4 o; uint2 u; } p0, p1;
#pragma unroll
      for (int j = 0; j < 4; ++j) {
        float o0 = ((float)x0[j] - sub[j]) * inv[j] + bb[j];
        float o1 = ((float)x1[j] - sub[j]) * inv[j] + bb[j];
        o0 = o0 > 0.f ? o0 : 0.f;
        o1 = o1 > 0.f ? o1 : 0.f;
        psum[j] += o0 + o1;
        p0.o[j] = (bf16_t)o0; p1.o[j] = (bf16_t)o1;
      }
      *(uint2*)(hout + (size_t)i * H + c0) = p0.u;
      *(uint2*)(hout + (size_t)(i + 4) * H + c0) = p1.u;
    }
    if (i < e) {
      bf16x4 x0 = *(const bf16x4*)(v + (size_t)i * H + c0);
      union { bf16x4 o; uint2 u; } p0;
#pragma unroll
      for (int j = 0; j < 4; ++j) {
        float o0 = ((float)x0[j] - sub[j]) * inv[j] + bb[j];
        o0 = o0 > 0.f ? o0 : 0.f;
        psum[j] += o0;
        p0.o[j] = (bf16_t)o0;
      }
      *(uint2*)(hout + (size_t)i * H + c0) = p0.u;
    }
  }

  if (hg) {
#pragma unroll
    for (int j = 0; j < 4; ++j) myred[j] = psum[j];
    __syncthreads();
    if (wave == 0) {
#pragma unroll
      for (int j = 0; j < 4; ++j) {
        float p = red[lane * RS + j] + red[(64 + lane) * RS + j] +
                  red[(128 + lane) * RS + j] + red[(192 + lane) * RS + j];
        hg[(size_t)g * H + c0 + j] = p / cnt;
      }
    }
  }
}

// ---------- fully fused heads: hg -> zi, zs, yhat, envhat (1 launch) -----
__global__ __launch_bounds__(256) void heads_fused_kernel(
    const float* __restrict__ hg,
    const bf16_t* __restrict__ fT1, const float* __restrict__ fb1,
    const bf16_t* __restrict__ fT2, const float* __restrict__ fb2,
    const bf16_t* __restrict__ sT1, const float* __restrict__ sb1,
    const bf16_t* __restrict__ sT2, const float* __restrict__ sb2,
    const bf16_t* __restrict__ pT1, const float* __restrict__ pb1,
    const bf16_t* __restrict__ aT1, const float* __restrict__ ab1,
    const float* __restrict__ pW2, const float* __restrict__ pb2,
    const float* __restrict__ aW2, const float* __restrict__ ab2,
    float* __restrict__ out_zi, float* __restrict__ out_zs,
    float* __restrict__ out_yh, float* __restrict__ out_ev) {
  constexpr int LDS_S = 264;            // 256 + 8 pad (bf16)
  constexpr int LDZ = 136;              // 128 + 8 pad
  __shared__ bf16_t BufA[64 * LDS_S];   // Hg (stages 0-1), then PA (3-4)
  __shared__ bf16_t BufB[64 * LDS_S];   // T12 = [t1 | t2]
  __shared__ bf16_t Z[64 * LDZ];        // zi (bf16)
  const int t = threadIdx.x;
  const int lane = t & 63;
  const int wave = t >> 6;              // 0..3
  const int m0 = blockIdx.x * 64;
  const int lr = lane & 15;
  const int lq = lane >> 4;

  // ---- stage 0: hg (f32) -> BufA (bf16) --------------------------------
  {
    int r = t >> 2, cb = (t & 3) * 64;
    const float* src = hg + (size_t)(m0 + r) * H + cb;
#pragma unroll
    for (int q = 0; q < 8; ++q)
      load8_to_lds(src + q * 8, true, (uint4*)&BufA[r * LDS_S + cb + q * 8]);
  }
  __syncthreads();

  f32x4 acc[4][4];

  // ---- stage 1: T12 = relu(Hg @ [fT1|sT1] + b1)   (K=256) ---------------
  {
    const bf16_t* W = (wave < 2) ? fT1 : sT1;
    const float* bb = (wave < 2) ? fb1 : sb1;
    const int wnl = (wave & 1) * 64;
    const int wcol = wave * 64;
#pragma unroll
    for (int mt = 0; mt < 4; ++mt)
#pragma unroll
      for (int nt = 0; nt < 4; ++nt) { f32x4 z = {}; acc[mt][nt] = z; }
    for (int k0 = 0; k0 < 256; k0 += 32) {
      bf16x8 a[4], b[4];
#pragma unroll
      for (int nt = 0; nt < 4; ++nt)
        b[nt] = *(const bf16x8*)(W + (size_t)(wnl + nt * 16 + lr) * 256 + k0 + lq * 8);
#pragma unroll
      for (int mt = 0; mt < 4; ++mt)
        a[mt] = *(const bf16x8*)(&BufA[(mt * 16 + lr) * LDS_S + k0 + lq * 8]);
#pragma unroll
      for (int mt = 0; mt < 4; ++mt)
#pragma unroll
        for (int nt = 0; nt < 4; ++nt)
          acc[mt][nt] = __builtin_amdgcn_mfma_f32_16x16x32_bf16(
              a[mt], b[nt], acc[mt][nt], 0, 0, 0);
    }
    __syncthreads();   // everyone done reading BufA region for this stage
#pragma unroll
    for (int nt = 0; nt < 4; ++nt) {
      float bv = bb[wnl + nt * 16 + lr];
      int col = wcol + nt * 16 + lr;
#pragma unroll
      for (int mt = 0; mt < 4; ++mt)
#pragma unroll
        for (int r = 0; r < 4; ++r) {
          int row = mt * 16 + lq * 4 + r;
          float vv = acc[mt][nt][r] + bv;
          BufB[row * LDS_S + col] = (bf16_t)(vv > 0.f ? vv : 0.f);
        }
    }
  }
  __syncthreads();

  // ---- stage 2: zi|zs = T12 @ [fT2|sT2] + b2   (K=128, f32 out) ---------
  {
    const bf16_t* W = (wave < 2) ? fT2 : sT2;
    const float* bb = (wave < 2) ? fb2 : sb2;
    float* outp = (wave < 2) ? out_zi : out_zs;
    const int wnl = (wave & 1) * 64;
    const int kin = (wave < 2) ? 0 : 128;
#pragma unroll
    for (int mt = 0; mt < 4; ++mt)
#pragma unroll
      for (int nt = 0; nt < 4; ++nt) { f32x4 z = {}; acc[mt][nt] = z; }
    for (int k0 = 0; k0 < 128; k0 += 32) {
      bf16x8 a[4], b[4];
#pragma unroll
      for (int nt = 0; nt < 4; ++nt)
        b[nt] = *(const bf16x8*)(W + (size_t)(wnl + nt * 16 + lr) * 128 + k0 + lq * 8);
#pragma unroll
      for (int mt = 0; mt < 4; ++mt)
        a[mt] = *(const bf16x8*)(&BufB[(mt * 16 + lr) * LDS_S + kin + k0 + lq * 8]);
#pragma unroll
      for (int mt = 0; mt < 4; ++mt)
#pragma unroll
        for (int nt = 0; nt < 4; ++nt)
          acc[mt][nt] = __builtin_amdgcn_mfma_f32_16x16x32_bf16(
              a[mt], b[nt], acc[mt][nt], 0, 0, 0);
    }
#pragma unroll
    for (int nt = 0; nt < 4; ++nt) {
      int col = wnl + nt * 16 + lr;
      float bv = bb[col];
#pragma unroll
      for (int mt = 0; mt < 4; ++mt)
#pragma unroll
        for (int r = 0; r < 4; ++r) {
          int row = mt * 16 + lq * 4 + r;
          float vv = acc[mt][nt][r] + bv;
          outp[(size_t)(m0 + row) * ZIC + col] = vv;
          if (wave < 2) Z[row * LDZ + col] = (bf16_t)vv;
        }
    }
  }
  __syncthreads();

  // ---- stage 3: PA = relu(Z @ [pT1|aT1] + b)   (K=128) into BufA --------
  {
    const bf16_t* W = (wave < 2) ? pT1 : aT1;
    const float* bb = (wave < 2) ? pb1 : ab1;
    const int wnl = (wave & 1) * 64;
    const int wcol = wave * 64;
#pragma unroll
    for (int mt = 0; mt < 4; ++mt)
#pragma unroll
      for (int nt = 0; nt < 4; ++nt) { f32x4 z = {}; acc[mt][nt] = z; }
    for (int k0 = 0; k0 < 128; k0 += 32) {
      bf16x8 a[4], b[4];
#pragma unroll
      for (int nt = 0; nt < 4; ++nt)
        b[nt] = *(const bf16x8*)(W + (size_t)(wnl + nt * 16 + lr) * 128 + k0 + lq * 8);
#pragma unroll
      for (int mt = 0; mt < 4; ++mt)
        a[mt] = *(const bf16x8*)(&Z[(mt * 16 + lr) * LDZ + k0 + lq * 8]);
#pragma unroll
      for (int mt = 0; mt < 4; ++mt)
#pragma unroll
        for (int nt = 0; nt < 4; ++nt)
          acc[mt][nt] = __builtin_amdgcn_mfma_f32_16x16x32_bf16(
              a[mt], b[nt], acc[mt][nt], 0, 0, 0);
    }
#pragma unroll
    for (int nt = 0; nt < 4; ++nt) {
      float bv = bb[wnl + nt * 16 + lr];
      int col = wcol + nt * 16 + lr;
#pragma unroll
      for (int mt = 0; mt < 4; ++mt)
#pragma unroll
        for (int r = 0; r < 4; ++r) {
          int row = mt * 16 + lq * 4 + r;
          float vv = acc[mt][nt][r] + bv;
          BufA[row * LDS_S + col] = (bf16_t)(vv > 0.f ? vv : 0.f);
        }
    }
  }
  __syncthreads();

  // ---- stage 4: yh = p1 @ pW2 + pb2 ; ev = a1 @ aW2 + ab2 ---------------
  if (t < 64) {
    float a4 = pb2[0];
    for (int k = 0; k < 128; ++k)
      a4 += (float)BufA[t * LDS_S + k] * pW2[k];
    out_yh[m0 + t] = a4;
  }
#pragma unroll
  for (int pass = 0; pass < 2; ++pass) {
    int j = pass * 256 + t;
    int r = j >> 3, n = j & 7;
    float a4 = ab2[n];
    for (int k = 0; k < 128; ++k)
      a4 += (float)BufA[r * LDS_S + 128 + k] * aW2[k * 8 + n];
    out_ev[(size_t)(m0 + r) * NE + n] = a4;
  }
}

extern "C" void kernel_launch(void* const* d_in, const int* in_sizes, int n_in,
                              void* d_out, int out_size, void* d_ws, size_t ws_size,
                              hipStream_t stream) {
  (void)in_sizes; (void)n_in; (void)out_size; (void)ws_size;
  const float* x        = (const float*)d_in[0];
  const int*   eidx     = (const int*)d_in[1];
  const float* eattr    = (const float*)d_in[2];
  const int*   batch    = (const int*)d_in[3];
  const float* node_W   = (const float*)d_in[4];
  const float* node_b   = (const float*)d_in[5];
  const float* conv_eps = (const float*)d_in[6];
  const float* edge_W   = (const float*)d_in[7];
  const float* edge_b   = (const float*)d_in[8];
  const float* mlp_W1   = (const float*)d_in[9];
  const float* mlp_b1   = (const float*)d_in[10];
  const float* mlp_W2   = (const float*)d_in[11];
  const float* mlp_b2   = (const float*)d_in[12];
  const float* gn_w     = (const float*)d_in[13];
  const float* gn_b     = (const float*)d_in[14];
  const float* gn_ms    = (const float*)d_in[15];
  const float* finv_W1  = (const float*)d_in[16];
  const float* finv_b1  = (const float*)d_in[17];
  const float* finv_W2  = (const float*)d_in[18];
  const float* finv_b2  = (const float*)d_in[19];
  const float* fspu_W1  = (const float*)d_in[20];
  const float* fspu_b1  = (const float*)d_in[21];
  const float* fspu_W2  = (const float*)d_in[22];
  const float* fspu_b2  = (const float*)d_in[23];
  const float* pred_W1  = (const float*)d_in[24];
  const float* pred_b1  = (const float*)d_in[25];
  const float* pred_W2  = (const float*)d_in[26];
  const float* pred_b2  = (const float*)d_in[27];
  const float* adv_W1   = (const float*)d_in[28];
  const float* adv_b1   = (const float*)d_in[29];
  const float* adv_W2   = (const float*)d_in[30];
  const float* adv_b2   = (const float*)d_in[31];
  float* out = (float*)d_out;

  float* out_hg = out;                                  // [G,H]
  float* out_zi = out + (size_t)N_GRAPH * H;            // [G,ZI]
  float* out_zs = out_zi + (size_t)N_GRAPH * ZIC;       // [G,ZS]
  float* out_yh = out_zs + (size_t)N_GRAPH * ZIC;       // [G]
  float* out_ev = out_yh + N_GRAPH;                     // [G,NE]

  // workspace carve-up (~118 MiB total)
  char* wp = (char*)d_ws;
  auto alloc = [&](size_t bytes) { char* p = wp; wp += (bytes + 255) & ~(size_t)255; return p; };
  bf16_t* A        = (bf16_t*)alloc((size_t)N_NODES * H * 2);   // h / t
  bf16_t* B        = (bf16_t*)alloc((size_t)N_NODES * H * 2);   // u / v
  bf16_t* Wt       = (bf16_t*)alloc((size_t)(H * ND + 6 * H * H) * 2);
  bf16_t* WtH      = (bf16_t*)alloc((size_t)(2 * ZIC * H + 4 * ZIC * ZIC) * 2);
  bf16_t* ewt16    = (bf16_t*)alloc((size_t)3 * 256 * 16 * 2);
  bf16_t* eat16    = (bf16_t*)alloc((size_t)N_EDGES * 16 * 2);
  int*    starts   = (int*)alloc((size_t)(N_GRAPH + 1) * 4);
  int*    counts   = (int*)alloc((size_t)N_NODES * 4);
  int*    cursor   = (int*)alloc((size_t)N_NODES * 4);
  int*    offs     = (int*)alloc((size_t)(N_NODES + 1) * 4);
  int*    bsum     = (int*)alloc((size_t)SCAN_B * 4);
  int*    src_srt  = (int*)alloc((size_t)N_EDGES * 4);

  const int* srcp = eidx;
  const int* dstp = eidx + N_EDGES;
  const int nscan = (N_NODES + SCAN_B - 1) / SCAN_B;

  compute_starts_kernel<<<(N_NODES + 255) / 256, 256, 0, stream>>>(
      batch, starts, counts, cursor, N_NODES, N_GRAPH);
  count_deg_kernel<<<(N_EDGES + 255) / 256, 256, 0, stream>>>(dstp, counts, N_EDGES, N_NODES);
  scan1_kernel<<<nscan, SCAN_B, 0, stream>>>(counts, offs, bsum, N_NODES);
  scan2_kernel<<<1, 64, 0, stream>>>(bsum, nscan);
  scan3_kernel<<<nscan, SCAN_B, 0, stream>>>(offs, bsum, N_NODES);
  fill_scatter_kernel<<<(N_EDGES + 255) / 256, 256, 0, stream>>>(
      srcp, dstp, eattr, offs, cursor, src_srt, eat16, N_EDGES, N_NODES);
  build_ewt16_kernel<<<(3 * 256 * 16 + 255) / 256, 256, 0, stream>>>(edge_W, ewt16);

  bf16_t* WtN = Wt;
  bf16_t* Wt1base = Wt + H * ND;                      // l-th at stride 2*H*H
  bf16_t* Wt2base = Wt + H * ND + (size_t)H * H;      // l-th at stride 2*H*H
  auto Wt1l = [&](int l) { return Wt1base + (size_t)(2 * l) * H * H; };
  auto Wt2l = [&](int l) { return Wt2base + (size_t)(2 * l) * H * H; };
  transpose_kernel<<<dim3(H / 32, ND / 32, 1), dim3(32, 8), 0, stream>>>(node_W, WtN, ND, H, 0, 0);
  transpose_kernel<<<dim3(H / 32, H / 32, 3), dim3(32, 8), 0, stream>>>(
      mlp_W1, Wt1base, H, H, (size_t)H * H, (size_t)2 * H * H);
  transpose_kernel<<<dim3(H / 32, H / 32, 3), dim3(32, 8), 0, stream>>>(
      mlp_W2, Wt2base, H, H, (size_t)H * H, (size_t)2 * H * H);

  bf16_t* fT1 = WtH;                          // [128 x 256]
  bf16_t* fT2 = fT1 + ZIC * H;                // [128 x 128]
  bf16_t* sT1 = fT2 + ZIC * ZIC;              // [128 x 256]
  bf16_t* sT2 = sT1 + ZIC * H;                // [128 x 128]
  bf16_t* pT1 = sT2 + ZIC * ZIC;              // [128 x 128]
  bf16_t* aT1 = pT1 + ZIC * ZIC;              // [128 x 128]
  transpose_kernel<<<dim3(ZIC / 32, H / 32, 1), dim3(32, 8), 0, stream>>>(finv_W1, fT1, H, ZIC, 0, 0);
  transpose_kernel<<<dim3(ZIC / 32, ZIC / 32, 1), dim3(32, 8), 0, stream>>>(finv_W2, fT2, ZIC, ZIC, 0, 0);
  transpose_kernel<<<dim3(ZIC / 32, H / 32, 1), dim3(32, 8), 0, stream>>>(fspu_W1, sT1, H, ZIC, 0, 0);
  transpose_kernel<<<dim3(ZIC / 32, ZIC / 32, 1), dim3(32, 8), 0, stream>>>(fspu_W2, sT2, ZIC, ZIC, 0, 0);
  transpose_kernel<<<dim3(ZIC / 32, ZIC / 32, 1), dim3(32, 8), 0, stream>>>(pred_W1, pT1, ZIC, ZIC, 0, 0);
  transpose_kernel<<<dim3(ZIC / 32, ZIC / 32, 1), dim3(32, 8), 0, stream>>>(adv_W1, aT1, ZIC, ZIC, 0, 0);

  const int mblocks = (N_NODES + 127) / 128;
  // h = x @ node_W + node_b (f32 input, full-H tile, reads x once)
  gemm_node_kernel<ND><<<mblocks, 512, 0, stream>>>(x, WtN, node_b, A, N_NODES);

  for (int l = 0; l < 3; ++l) {
    gine_gather_mfma_kernel<<<N_NODES / 4, 256, 0, stream>>>(
        A, eat16, src_srt, offs, ewt16 + (size_t)l * 256 * 16,
        edge_b + l * H, conv_eps + l, B);
    gemm256_dma_kernel<H, true ><<<mblocks, 512, 0, stream>>>(B, Wt1l(l), mlp_b1 + l * H, A, N_NODES);
    gemm256_dma_kernel<H, false><<<mblocks, 512, 0, stream>>>(A, Wt2l(l), mlp_b2 + l * H, B, N_NODES);
    graphnorm_kernel<<<N_GRAPH, 256, 0, stream>>>(B, A, starts, gn_w + l * H, gn_b + l * H,
                                                  gn_ms + l * H, (l == 2) ? out_hg : nullptr);
  }

  // all four head stages in one launch (row-local chain)
  heads_fused_kernel<<<N_GRAPH / 64, 256, 0, stream>>>(
      out_hg,
      fT1, finv_b1, fT2, finv_b2,
      sT1, fspu_b1, sT2, fspu_b2,
      pT1, pred_b1, aT1, adv_b1,
      pred_W2, pred_b2, adv_W2, adv_b2,
      out_zi, out_zs, out_yh, out_ev);
}

// Round 10
// 674.501 us; speedup vs baseline: 1.1202x; 1.0256x over previous
//
#include <hip/hip_runtime.h>
#include <hip/hip_bf16.h>

typedef __bf16 bf16_t;
typedef __bf16 bf16x8 __attribute__((ext_vector_type(8)));
typedef __bf16 bf16x4 __attribute__((ext_vector_type(4)));
typedef float  f32x4  __attribute__((ext_vector_type(4)));

static constexpr int N_NODES = 100000;
static constexpr int N_EDGES = 300000;
static constexpr int N_GRAPH = 4096;
static constexpr int H  = 256;
static constexpr int ND = 64;
static constexpr int ZIC = 128;
static constexpr int NE = 8;
static constexpr int SCAN_B = 1024;

__device__ __forceinline__ int clampi(int v, int lo, int hi) {
  return v < lo ? lo : (v > hi ? hi : v);
}

// async 16B global -> LDS (wave-uniform LDS base + lane*16)
__device__ __forceinline__ void dma16(const bf16_t* g, bf16_t* lds_base) {
  __builtin_amdgcn_global_load_lds(
      (const __attribute__((address_space(1))) void*)g,
      (__attribute__((address_space(3))) void*)lds_base, 16, 0, 0);
}

// ------- graph segment starts (batch sorted) + zero counts/cursor --------
__global__ void compute_starts_kernel(const int* __restrict__ batch,
                                      int* __restrict__ starts,
                                      int* __restrict__ counts,
                                      int* __restrict__ cursor, int N, int G) {
  int i = blockIdx.x * blockDim.x + threadIdx.x;
  if (i >= N) return;
  counts[i] = 0;
  cursor[i] = 0;
  int b = clampi(batch[i], 0, G - 1);
  if (i == 0) {
    for (int g = 0; g <= b; ++g) starts[g] = 0;
  } else {
    int p = clampi(batch[i - 1], 0, G - 1);
    for (int g = p + 1; g <= b; ++g) starts[g] = i;
  }
  if (i == N - 1) {
    for (int g = b + 1; g <= G; ++g) starts[g] = N;
  }
}

// ---------------- CSR build ----------------
__global__ void count_deg_kernel(const int* __restrict__ dst, int* __restrict__ counts, int E, int N) {
  int e = blockIdx.x * blockDim.x + threadIdx.x;
  if (e < E) atomicAdd(&counts[clampi(dst[e], 0, N - 1)], 1);
}

__global__ __launch_bounds__(SCAN_B) void scan1_kernel(const int* __restrict__ counts,
                                                       int* __restrict__ offs,
                                                       int* __restrict__ bsum, int N) {
  __shared__ int tmp[SCAN_B];
  int i = blockIdx.x * SCAN_B + threadIdx.x;
  int v = (i < N) ? counts[i] : 0;
  tmp[threadIdx.x] = v;
  __syncthreads();
  for (int d = 1; d < SCAN_B; d <<= 1) {
    int t = (threadIdx.x >= d) ? tmp[threadIdx.x - d] : 0;
    __syncthreads();
    tmp[threadIdx.x] += t;
    __syncthreads();
  }
  if (i < N) offs[i + 1] = tmp[threadIdx.x];
  if (threadIdx.x == SCAN_B - 1) bsum[blockIdx.x] = tmp[SCAN_B - 1];
  if (i == 0) offs[0] = 0;
}

__global__ void scan2_kernel(int* __restrict__ bsum, int nblk) {
  if (blockIdx.x == 0 && threadIdx.x == 0) {
    int run = 0;
    for (int b = 0; b < nblk; ++b) { int v = bsum[b]; bsum[b] = run; run += v; }
  }
}

__global__ __launch_bounds__(SCAN_B) void scan3_kernel(int* __restrict__ offs,
                                                       const int* __restrict__ bsum, int N) {
  int i = blockIdx.x * SCAN_B + threadIdx.x;
  if (i < N) offs[i + 1] += bsum[blockIdx.x];
}

// fused: compute position AND scatter src_sorted + eattr(bf16) in one pass
__global__ void fill_scatter_kernel(const int* __restrict__ src, const int* __restrict__ dst,
                                    const float* __restrict__ eattr,
                                    const int* __restrict__ offs, int* __restrict__ cursor,
                                    int* __restrict__ src_srt, bf16_t* __restrict__ eat16,
                                    int E, int N) {
  int e = blockIdx.x * blockDim.x + threadIdx.x;
  if (e >= E) return;
  int d = clampi(dst[e], 0, N - 1);
  int pos = offs[d] + atomicAdd(&cursor[d], 1);
  if ((unsigned)pos >= (unsigned)E) return;
  int s = src[e];
  src_srt[pos] = ((unsigned)s < (unsigned)N_NODES) ? s : 0;
  const float* ea = eattr + (size_t)e * 16;
  union { bf16_t b[16]; uint4 u[2]; } pk;
#pragma unroll
  for (int k = 0; k < 16; ++k) pk.b[k] = (bf16_t)ea[k];
  uint4* dst16 = (uint4*)(eat16 + ((size_t)pos << 4));
  dst16[0] = pk.u[0];
  dst16[1] = pk.u[1];
}

// edge_W[l] (16 x 256) -> eWt[l] (256 rows x 16 cols), bf16  (v6 layout)
__global__ void build_ewt16_kernel(const float* __restrict__ edge_W,
                                   bf16_t* __restrict__ ewt) {
  int idx = blockIdx.x * blockDim.x + threadIdx.x;
  if (idx >= 3 * 256 * 16) return;
  int l = idx / (256 * 16);
  int rem = idx - l * 256 * 16;
  int n = rem >> 4, k = rem & 15;
  ewt[idx] = (bf16_t)edge_W[(size_t)l * 16 * 256 + k * 256 + n];
}

// -------- fp32 transpose + bf16 cast: W[K x Nc] -> Wt[Nc x K] (bf16) ------
__global__ void transpose_kernel(const float* __restrict__ W,
                                 bf16_t* __restrict__ Wt, int K, int Nc,
                                 size_t srcStride, size_t dstStride) {
  __shared__ float tile[32][33];
  const float* Wz = W + (size_t)blockIdx.z * srcStride;
  bf16_t* Wtz = Wt + (size_t)blockIdx.z * dstStride;
  int n0 = blockIdx.x * 32, k0 = blockIdx.y * 32;
  int tx = threadIdx.x, ty = threadIdx.y;
  for (int i = ty; i < 32; i += 8)
    tile[i][tx] = Wz[(size_t)(k0 + i) * Nc + n0 + tx];
  __syncthreads();
  for (int i = ty; i < 32; i += 8)
    Wtz[(size_t)(n0 + i) * K + k0 + tx] = (bf16_t)tile[tx][i];
}

// both MLP weight transposes (W1 x3 layers + W2 x3 layers) in ONE launch:
// z in [0,6): l = z%3, which = z/3 (0=W1, 1=W2). 256x256 each.
__global__ void transpose_mlp_kernel(const float* __restrict__ W1,
                                     const float* __restrict__ W2,
                                     bf16_t* __restrict__ Wt1base,
                                     bf16_t* __restrict__ Wt2base) {
  __shared__ float tile[32][33];
  int z = blockIdx.z;
  int l = z < 3 ? z : z - 3;
  const float* Wz = (z < 3 ? W1 : W2) + (size_t)l * H * H;
  bf16_t* Wtz = (z < 3 ? Wt1base : Wt2base) + (size_t)(2 * l) * H * H;
  int n0 = blockIdx.x * 32, k0 = blockIdx.y * 32;
  int tx = threadIdx.x, ty = threadIdx.y;
  for (int i = ty; i < 32; i += 8)
    tile[i][tx] = Wz[(size_t)(k0 + i) * H + n0 + tx];
  __syncthreads();
  for (int i = ty; i < 32; i += 8)
    Wtz[(size_t)(n0 + i) * H + k0 + tx] = (bf16_t)tile[tx][i];
}

// all six head weight transposes in ONE launch (z selects the matrix).
// z=0: finv_W1 (256x128), z=1: fspu_W1 (256x128),
// z=2..5: finv_W2 / fspu_W2 / pred_W1 / adv_W1 (128x128).
__global__ void transpose_heads_kernel(
    const float* __restrict__ fW1, const float* __restrict__ sW1,
    const float* __restrict__ fW2, const float* __restrict__ sW2,
    const float* __restrict__ pW1, const float* __restrict__ aW1,
    bf16_t* __restrict__ fT1, bf16_t* __restrict__ sT1,
    bf16_t* __restrict__ fT2, bf16_t* __restrict__ sT2,
    bf16_t* __restrict__ pT1, bf16_t* __restrict__ aT1) {
  __shared__ float tile[32][33];
  int z = blockIdx.z;
  const float* W; bf16_t* Wt; int K;
  switch (z) {
    case 0: W = fW1; Wt = fT1; K = H;   break;
    case 1: W = sW1; Wt = sT1; K = H;   break;
    case 2: W = fW2; Wt = fT2; K = ZIC; break;
    case 3: W = sW2; Wt = sT2; K = ZIC; break;
    case 4: W = pW1; Wt = pT1; K = ZIC; break;
    default: W = aW1; Wt = aT1; K = ZIC; break;
  }
  int n0 = blockIdx.x * 32, k0 = blockIdx.y * 32;
  if (k0 >= K) return;   // uniform per block (small shapes skip)
  int tx = threadIdx.x, ty = threadIdx.y;
  for (int i = ty; i < 32; i += 8)
    tile[i][tx] = W[(size_t)(k0 + i) * ZIC + n0 + tx];
  __syncthreads();
  for (int i = ty; i < 32; i += 8)
    Wt[(size_t)(n0 + i) * K + k0 + tx] = (bf16_t)tile[tx][i];
}

// ---- staging loaders: 8 contiguous elements -> 8 bf16 (16B) in LDS ----
__device__ __forceinline__ void load8_to_lds(const bf16_t* p, bool valid, uint4* dst) {
  uint4 v = make_uint4(0u, 0u, 0u, 0u);
  if (valid) v = *(const uint4*)p;
  *dst = v;
}
__device__ __forceinline__ void load8_to_lds(const float* p, bool valid, uint4* dst) {
  float4 f0 = make_float4(0.f, 0.f, 0.f, 0.f), f1 = f0;
  if (valid) { f0 = *(const float4*)p; f1 = *(const float4*)(p + 4); }
  union { bf16_t b[8]; uint4 u; } pk;
  pk.b[0] = (bf16_t)f0.x; pk.b[1] = (bf16_t)f0.y;
  pk.b[2] = (bf16_t)f0.z; pk.b[3] = (bf16_t)f0.w;
  pk.b[4] = (bf16_t)f1.x; pk.b[5] = (bf16_t)f1.y;
  pk.b[6] = (bf16_t)f1.z; pk.b[7] = (bf16_t)f1.w;
  *dst = pk.u;
}

// ------- node linear: 128x256 tile, K=64, f32 input, single K-step -------
template<int K>   // K == ND == 64
__global__ __launch_bounds__(512) void gemm_node_kernel(
    const float* __restrict__ U, const bf16_t* __restrict__ Wt,
    const float* __restrict__ bias, bf16_t* __restrict__ Out, int M) {
  constexpr int LDT = 72;
  __shared__ bf16_t Ut[128 * LDT];   // 18 KB padded
  __shared__ bf16_t Wl[256 * 64];    // 32 KB dma16-swizzled
  const int t = threadIdx.x;
  const int lane = t & 63;
  const int wave = t >> 6;                 // 0..7
  const int m0 = blockIdx.x * 128;
  const int wm = (wave >> 2) * 64;         // 0,64
  const int wn = (wave & 3) * 64;          // 0,64,128,192
  const int lr = lane & 15;
  const int lq = lane >> 4;
  const int subrow = lane >> 3;            // 0..7
  const int lchunk = (lane & 7) ^ subrow;  // pre-swizzled col chunk
  f32x4 acc[4][4] = {};

  // stage A: thread t covers row t>>2, cols (t&3)*16 .. +15 (f32 -> bf16)
  {
    int r = t >> 2, c0 = (t & 3) * 16;
    int ur = m0 + r;
    bool ok = ur < M;
    const float* up = U + (size_t)ur * K + c0;
    load8_to_lds(up,     ok, (uint4*)&Ut[r * LDT + c0]);
    load8_to_lds(up + 8, ok, (uint4*)&Ut[r * LDT + c0 + 8]);
  }
  // stage W (256 rows x 64 cols) via dma16
#pragma unroll
  for (int c = 0; c < 4; ++c) {
    int wrow = c * 64 + wave * 8 + subrow;
    dma16(Wt + (size_t)wrow * K + lchunk * 8, &Wl[(c * 64 + wave * 8) * 64]);
  }
  __syncthreads();
#pragma unroll
  for (int s = 0; s < 2; ++s) {
    bf16x8 a[4], b[4];
#pragma unroll
    for (int mt = 0; mt < 4; ++mt)
      a[mt] = *(const bf16x8*)(&Ut[(wm + mt * 16 + lr) * LDT + s * 32 + lq * 8]);
#pragma unroll
    for (int nt = 0; nt < 4; ++nt)
      b[nt] = *(const bf16x8*)(&Wl[(wn + nt * 16 + lr) * 64 + (((s * 4 + lq) ^ (lr & 7)) << 3)]);
#pragma unroll
    for (int mt = 0; mt < 4; ++mt)
#pragma unroll
      for (int nt = 0; nt < 4; ++nt)
        acc[mt][nt] = __builtin_amdgcn_mfma_f32_16x16x32_bf16(
            a[mt], b[nt], acc[mt][nt], 0, 0, 0);
  }

#pragma unroll
  for (int mt = 0; mt < 4; ++mt)
#pragma unroll
    for (int nt = 0; nt < 4; ++nt) {
      int col = wn + nt * 16 + lr;
      float bcol = bias[col];
#pragma unroll
      for (int r = 0; r < 4; ++r) {
        int row = m0 + wm + mt * 16 + lq * 4 + r;
        if (row < M) {
          float vv = acc[mt][nt][r] + bcol;
          Out[(size_t)row * H + col] = (bf16_t)vv;
        }
      }
    }
}

// ------- MFMA GEMM 128x256 (full-H tile), bf16 in, dma16 + XOR swizzle ----
template<int K, bool RELU>
__global__ __launch_bounds__(512) void gemm256_dma_kernel(
    const bf16_t* __restrict__ U, const bf16_t* __restrict__ Wt,
    const float* __restrict__ bias, bf16_t* __restrict__ Out, int M) {
  __shared__ bf16_t Ut[128 * 64];   // 16 KB
  __shared__ bf16_t Wl[256 * 64];   // 32 KB
  const int t = threadIdx.x;
  const int lane = t & 63;
  const int wave = t >> 6;                 // 0..7
  const int m0 = blockIdx.x * 128;
  const int wm = (wave >> 2) * 64;         // 0,64
  const int wn = (wave & 3) * 64;          // 0,64,128,192
  const int lr = lane & 15;
  const int lq = lane >> 4;
  const int subrow = lane >> 3;            // 0..7 within 8-row group
  const int lchunk = (lane & 7) ^ subrow;  // pre-swizzled col chunk
  f32x4 acc[4][4] = {};

  for (int k0 = 0; k0 < K; k0 += 64) {
#pragma unroll
    for (int c = 0; c < 2; ++c) {
      int urow = m0 + c * 64 + wave * 8 + subrow;
      if (urow >= M) urow = M - 1;
      dma16(U + (size_t)urow * K + k0 + lchunk * 8, &Ut[(c * 64 + wave * 8) * 64]);
    }
#pragma unroll
    for (int c = 0; c < 4; ++c) {
      int wrow = c * 64 + wave * 8 + subrow;
      dma16(Wt + (size_t)wrow * K + k0 + lchunk * 8, &Wl[(c * 64 + wave * 8) * 64]);
    }
    __syncthreads();
#pragma unroll
    for (int s = 0; s < 2; ++s) {
      bf16x8 a[4], b[4];
#pragma unroll
      for (int mt = 0; mt < 4; ++mt)
        a[mt] = *(const bf16x8*)(&Ut[(wm + mt * 16 + lr) * 64 + (((s * 4 + lq) ^ (lr & 7)) << 3)]);
#pragma unroll
      for (int nt = 0; nt < 4; ++nt)
        b[nt] = *(const bf16x8*)(&Wl[(wn + nt * 16 + lr) * 64 + (((s * 4 + lq) ^ (lr & 7)) << 3)]);
#pragma unroll
      for (int mt = 0; mt < 4; ++mt)
#pragma unroll
        for (int nt = 0; nt < 4; ++nt)
          acc[mt][nt] = __builtin_amdgcn_mfma_f32_16x16x32_bf16(
              a[mt], b[nt], acc[mt][nt], 0, 0, 0);
    }
    __syncthreads();
  }

#pragma unroll
  for (int mt = 0; mt < 4; ++mt)
#pragma unroll
    for (int nt = 0; nt < 4; ++nt) {
      int col = wn + nt * 16 + lr;
      float bcol = bias[col];
#pragma unroll
      for (int r = 0; r < 4; ++r) {
        int row = m0 + wm + mt * 16 + lq * 4 + r;
        if (row < M) {
          float vv = acc[mt][nt][r] + bcol;
          if (RELU) vv = vv > 0.f ? vv : 0.f;
          Out[(size_t)row * H + col] = (bf16_t)vv;
        }
      }
    }
}

// ---------------- fused GINE gather with MFMA edge-linear (v6) -----------
// v6 = proven best (64 us). v9's bias-fold-into-write REGRESSED (+2 us):
// it added 16 adds/window/thread in the (unconditional) write path while
// saving only ~12 in the (sparse) consume path. Bias stays in consume.
__global__ __launch_bounds__(256) void gine_gather_mfma_kernel(
    const bf16_t* __restrict__ h, const bf16_t* __restrict__ eat16,
    const int* __restrict__ src_sorted, const int* __restrict__ offs,
    const bf16_t* __restrict__ ewt, const float* __restrict__ eb,
    const float* __restrict__ eps_p, bf16_t* __restrict__ u) {
  constexpr int HP = H + 8;
  __shared__ bf16_t slin[2][16 * HP];  // 16.9 KB
  const int t = threadIdx.x;
  const int wave = t >> 6;
  const int lane = t & 63;
  const int lr = lane & 15;
  const int lq = lane >> 4;
  const int lane4 = lane * 4;
  const int n0 = blockIdx.x * 4;
  const int nodeN = n0 + wave;

  bf16x4 hs = *(const bf16x4*)(h + (size_t)nodeN * H + lane4);

  bf16x8 bfrag[4];
#pragma unroll
  for (int nt = 0; nt < 4; ++nt) {
    bf16x8 bv = {};
    if (lq < 2)
      bv = *(const bf16x8*)(ewt + ((wave * 64 + nt * 16 + lr) << 4) + (lq << 3));
    bfrag[nt] = bv;
  }
  float ebv[4];
#pragma unroll
  for (int i = 0; i < 4; ++i) ebv[i] = eb[lane4 + i];

  int bs = offs[n0], be = offs[n0 + 4];
  bs = clampi(bs, 0, N_EDGES);
  be = clampi(be, bs, N_EDGES);
  int ns = offs[nodeN], ne = offs[nodeN + 1];
  ns = clampi(ns, bs, be);
  ne = clampi(ne, ns, be);

  float acc[4] = {0.f, 0.f, 0.f, 0.f};
  int parity = 0;

  for (int cb = bs; cb < be; cb += 16, parity ^= 1) {
    int arow = cb + lr;
    if (arow >= N_EDGES) arow = N_EDGES - 1;
    bf16x8 afrag = {};
    if (lq < 2)
      afrag = *(const bf16x8*)(eat16 + ((size_t)arow << 4) + (lq << 3));

    int j0 = ns > cb ? ns : cb;
    int j1 = ne < cb + 16 ? ne : cb + 16;
    int sidx[4];
    bf16x4 hv[4];
    if (j0 < j1) {
#pragma unroll
      for (int q = 0; q < 4; ++q) {
        int jj = j0 + q; if (jj > j1 - 1) jj = j1 - 1;
        sidx[q] = src_sorted[jj];
      }
    }

    f32x4 c[4];
#pragma unroll
    for (int nt = 0; nt < 4; ++nt) {
      f32x4 z = {};
      c[nt] = __builtin_amdgcn_mfma_f32_16x16x32_bf16(afrag, bfrag[nt], z, 0, 0, 0);
    }
#pragma unroll
    for (int nt = 0; nt < 4; ++nt)
#pragma unroll
      for (int r = 0; r < 4; ++r)
        slin[parity][(lq * 4 + r) * HP + wave * 64 + nt * 16 + lr] = (bf16_t)c[nt][r];

    if (j0 < j1) {
#pragma unroll
      for (int q = 0; q < 4; ++q)
        hv[q] = *(const bf16x4*)(h + (size_t)sidx[q] * H + lane4);
    }

    __syncthreads();

    for (int jb = j0; jb < j1; jb += 4) {
      if (jb != j0) {
#pragma unroll
        for (int q = 0; q < 4; ++q) {
          int jj = jb + q; if (jj > j1 - 1) jj = j1 - 1;
          sidx[q] = src_sorted[jj];
        }
#pragma unroll
        for (int q = 0; q < 4; ++q)
          hv[q] = *(const bf16x4*)(h + (size_t)sidx[q] * H + lane4);
      }
#pragma unroll
      for (int q = 0; q < 4; ++q) {
        if (jb + q < j1) {
          bf16x4 lv = *(const bf16x4*)(&slin[parity][(jb + q - cb) * HP + lane4]);
#pragma unroll
          for (int i = 0; i < 4; ++i)
            acc[i] += fmaxf((float)hv[q][i] + (float)lv[i] + ebv[i], 0.f);
        }
      }
    }
  }

  const float sc = 1.0f + eps_p[0];
  union { bf16x4 v; uint2 b; } o;
#pragma unroll
  for (int i = 0; i < 4; ++i) o.v[i] = (bf16_t)(sc * (float)hs[i] + acc[i]);
  *(uint2*)(u + (size_t)nodeN * H + lane4) = o.b;
}

// --- GraphNorm (+relu, + optional fused mean-pool) -----------------------
__global__ __launch_bounds__(256) void graphnorm_kernel(
    const bf16_t* __restrict__ v, bf16_t* __restrict__ hout,
    const int* __restrict__ starts,
    const float* __restrict__ w, const float* __restrict__ b,
    const float* __restrict__ ms, float* __restrict__ hg) {
  constexpr int RS = 9;    // red stride (floats) - odd to spread banks
  constexpr int PS = 13;   // prm stride (floats)
  __shared__ float red[4 * 64 * RS];   // 9.2 KB
  __shared__ float prm[64 * PS];       // 3.3 KB
  const int g = blockIdx.x;
  const int t = threadIdx.x;
  const int lane = t & 63;
  const int wave = t >> 6;
  const int c0 = lane * 4;
  int s = starts[g], e = starts[g + 1];
  s = clampi(s, 0, N_NODES);
  e = clampi(e, s, N_NODES);
  const float cnt = (float)((e - s) > 1 ? (e - s) : 1);

  float sx[4] = {0.f, 0.f, 0.f, 0.f}, sxx[4] = {0.f, 0.f, 0.f, 0.f};
  {
    int i = s + wave;
    for (; i + 4 < e; i += 8) {
      bf16x4 x0 = *(const bf16x4*)(v + (size_t)i * H + c0);
      bf16x4 x1 = *(const bf16x4*)(v + (size_t)(i + 4) * H + c0);
#pragma unroll
      for (int j = 0; j < 4; ++j) {
        float f0 = (float)x0[j], f1 = (float)x1[j];
        sx[j] += f0 + f1; sxx[j] += f0 * f0 + f1 * f1;
      }
    }
    if (i < e) {
      bf16x4 x0 = *(const bf16x4*)(v + (size_t)i * H + c0);
#pragma unroll
      for (int j = 0; j < 4; ++j) {
        float f0 = (float)x0[j];
        sx[j] += f0; sxx[j] += f0 * f0;
      }
    }
  }
  float* myred = &red[(wave * 64 + lane) * RS];
#pragma unroll
  for (int j = 0; j < 4; ++j) { myred[j] = sx[j]; myred[4 + j] = sxx[j]; }
  __syncthreads();

  if (wave == 0) {
#pragma unroll
    for (int j = 0; j < 4; ++j) {
      float fsx = red[lane * RS + j] + red[(64 + lane) * RS + j] +
                  red[(128 + lane) * RS + j] + red[(192 + lane) * RS + j];
      float fsxx = red[lane * RS + 4 + j] + red[(64 + lane) * RS + 4 + j] +
                   red[(128 + lane) * RS + 4 + j] + red[(192 + lane) * RS + 4 + j];
      float mean = fsx / cnt;
      float sub = ms[c0 + j] * mean;
      float var = fsxx / cnt - 2.f * sub * mean + sub * sub;
      var = fmaxf(var, 0.f);
      prm[lane * PS + j] = sub;
      prm[lane * PS + 4 + j] = rsqrtf(var + 1e-5f) * w[c0 + j];
      prm[lane * PS + 8 + j] = b[c0 + j];
    }
  }
  __syncthreads();
  float sub[4], inv[4], bb[4];
#pragma unroll
  for (int j = 0; j < 4; ++j) {
    sub[j] = prm[lane * PS + j];
    inv[j] = prm[lane * PS + 4 + j];
    bb[j] = prm[lane * PS + 8 + j];
  }

  float psum[4] = {0.f, 0.f, 0.f, 0.f};
  {
    int i = s + wave;
    for (; i + 4 < e; i += 8) {
      bf16x4 x0 = *(const bf16x4*)(v + (size_t)i * H + c0);
      bf16x4 x1 = *(const bf16x4*)(v + (size_t)(i + 4) * H + c0);
      union { bf16x4 o; uint2 u; } p0, p1;
#pragma unroll
      for (int j = 0; j < 4; ++j) {
        float o0 = ((float)x0[j] - sub[j]) * inv[j] + bb[j];
        float o1 = ((float)x1[j] - sub[j]) * inv[j] + bb[j];
        o0 = o0 > 0.f ? o0 : 0.f;
        o1 = o1 > 0.f ? o1 : 0.f;
        psum[j] += o0 + o1;
        p0.o[j] = (bf16_t)o0; p1.o[j] = (bf16_t)o1;
      }
      *(uint2*)(hout + (size_t)i * H + c0) = p0.u;
      *(uint2*)(hout + (size_t)(i + 4) * H + c0) = p1.u;
    }
    if (i < e) {
      bf16x4 x0 = *(const bf16x4*)(v + (size_t)i * H + c0);
      union { bf16x4 o; uint2 u; } p0;
#pragma unroll
      for (int j = 0; j < 4; ++j) {
        float o0 = ((float)x0[j] - sub[j]) * inv[j] + bb[j];
        o0 = o0 > 0.f ? o0 : 0.f;
        psum[j] += o0;
        p0.o[j] = (bf16_t)o0;
      }
      *(uint2*)(hout + (size_t)i * H + c0) = p0.u;
    }
  }

  if (hg) {
#pragma unroll
    for (int j = 0; j < 4; ++j) myred[j] = psum[j];
    __syncthreads();
    if (wave == 0) {
#pragma unroll
      for (int j = 0; j < 4; ++j) {
        float p = red[lane * RS + j] + red[(64 + lane) * RS + j] +
                  red[(128 + lane) * RS + j] + red[(192 + lane) * RS + j];
        hg[(size_t)g * H + c0 + j] = p / cnt;
      }
    }
  }
}

// ---------- fully fused heads: hg -> zi, zs, yhat, envhat (1 launch) -----
__global__ __launch_bounds__(256) void heads_fused_kernel(
    const float* __restrict__ hg,
    const bf16_t* __restrict__ fT1, const float* __restrict__ fb1,
    const bf16_t* __restrict__ fT2, const float* __restrict__ fb2,
    const bf16_t* __restrict__ sT1, const float* __restrict__ sb1,
    const bf16_t* __restrict__ sT2, const float* __restrict__ sb2,
    const bf16_t* __restrict__ pT1, const float* __restrict__ pb1,
    const bf16_t* __restrict__ aT1, const float* __restrict__ ab1,
    const float* __restrict__ pW2, const float* __restrict__ pb2,
    const float* __restrict__ aW2, const float* __restrict__ ab2,
    float* __restrict__ out_zi, float* __restrict__ out_zs,
    float* __restrict__ out_yh, float* __restrict__ out_ev) {
  constexpr int LDS_S = 264;            // 256 + 8 pad (bf16)
  constexpr int LDZ = 136;              // 128 + 8 pad
  __shared__ bf16_t BufA[64 * LDS_S];   // Hg (stages 0-1), then PA (3-4)
  __shared__ bf16_t BufB[64 * LDS_S];   // T12 = [t1 | t2]
  __shared__ bf16_t Z[64 * LDZ];        // zi (bf16)
  const int t = threadIdx.x;
  const int lane = t & 63;
  const int wave = t >> 6;              // 0..3
  const int m0 = blockIdx.x * 64;
  const int lr = lane & 15;
  const int lq = lane >> 4;

  // ---- stage 0: hg (f32) -> BufA (bf16) --------------------------------
  {
    int r = t >> 2, cb = (t & 3) * 64;
    const float* src = hg + (size_t)(m0 + r) * H + cb;
#pragma unroll
    for (int q = 0; q < 8; ++q)
      load8_to_lds(src + q * 8, true, (uint4*)&BufA[r * LDS_S + cb + q * 8]);
  }
  __syncthreads();

  f32x4 acc[4][4];

  // ---- stage 1: T12 = relu(Hg @ [fT1|sT1] + b1)   (K=256) ---------------
  {
    const bf16_t* W = (wave < 2) ? fT1 : sT1;
    const float* bb = (wave < 2) ? fb1 : sb1;
    const int wnl = (wave & 1) * 64;
    const int wcol = wave * 64;
#pragma unroll
    for (int mt = 0; mt < 4; ++mt)
#pragma unroll
      for (int nt = 0; nt < 4; ++nt) { f32x4 z = {}; acc[mt][nt] = z; }
    for (int k0 = 0; k0 < 256; k0 += 32) {
      bf16x8 a[4], b[4];
#pragma unroll
      for (int nt = 0; nt < 4; ++nt)
        b[nt] = *(const bf16x8*)(W + (size_t)(wnl + nt * 16 + lr) * 256 + k0 + lq * 8);
#pragma unroll
      for (int mt = 0; mt < 4; ++mt)
        a[mt] = *(const bf16x8*)(&BufA[(mt * 16 + lr) * LDS_S + k0 + lq * 8]);
#pragma unroll
      for (int mt = 0; mt < 4; ++mt)
#pragma unroll
        for (int nt = 0; nt < 4; ++nt)
          acc[mt][nt] = __builtin_amdgcn_mfma_f32_16x16x32_bf16(
              a[mt], b[nt], acc[mt][nt], 0, 0, 0);
    }
    __syncthreads();   // everyone done reading BufA region for this stage
#pragma unroll
    for (int nt = 0; nt < 4; ++nt) {
      float bv = bb[wnl + nt * 16 + lr];
      int col = wcol + nt * 16 + lr;
#pragma unroll
      for (int mt = 0; mt < 4; ++mt)
#pragma unroll
        for (int r = 0; r < 4; ++r) {
          int row = mt * 16 + lq * 4 + r;
          float vv = acc[mt][nt][r] + bv;
          BufB[row * LDS_S + col] = (bf16_t)(vv > 0.f ? vv : 0.f);
        }
    }
  }
  __syncthreads();

  // ---- stage 2: zi|zs = T12 @ [fT2|sT2] + b2   (K=128, f32 out) ---------
  {
    const bf16_t* W = (wave < 2) ? fT2 : sT2;
    const float* bb = (wave < 2) ? fb2 : sb2;
    float* outp = (wave < 2) ? out_zi : out_zs;
    const int wnl = (wave & 1) * 64;
    const int kin = (wave < 2) ? 0 : 128;
#pragma unroll
    for (int mt = 0; mt < 4; ++mt)
#pragma unroll
      for (int nt = 0; nt < 4; ++nt) { f32x4 z = {}; acc[mt][nt] = z; }
    for (int k0 = 0; k0 < 128; k0 += 32) {
      bf16x8 a[4], b[4];
#pragma unroll
      for (int nt = 0; nt < 4; ++nt)
        b[nt] = *(const bf16x8*)(W + (size_t)(wnl + nt * 16 + lr) * 128 + k0 + lq * 8);
#pragma unroll
      for (int mt = 0; mt < 4; ++mt)
        a[mt] = *(const bf16x8*)(&BufB[(mt * 16 + lr) * LDS_S + kin + k0 + lq * 8]);
#pragma unroll
      for (int mt = 0; mt < 4; ++mt)
#pragma unroll
        for (int nt = 0; nt < 4; ++nt)
          acc[mt][nt] = __builtin_amdgcn_mfma_f32_16x16x32_bf16(
              a[mt], b[nt], acc[mt][nt], 0, 0, 0);
    }
#pragma unroll
    for (int nt = 0; nt < 4; ++nt) {
      int col = wnl + nt * 16 + lr;
      float bv = bb[col];
#pragma unroll
      for (int mt = 0; mt < 4; ++mt)
#pragma unroll
        for (int r = 0; r < 4; ++r) {
          int row = mt * 16 + lq * 4 + r;
          float vv = acc[mt][nt][r] + bv;
          outp[(size_t)(m0 + row) * ZIC + col] = vv;
          if (wave < 2) Z[row * LDZ + col] = (bf16_t)vv;
        }
    }
  }
  __syncthreads();

  // ---- stage 3: PA = relu(Z @ [pT1|aT1] + b)   (K=128) into BufA --------
  {
    const bf16_t* W = (wave < 2) ? pT1 : aT1;
    const float* bb = (wave < 2) ? pb1 : ab1;
    const int wnl = (wave & 1) * 64;
    const int wcol = wave * 64;
#pragma unroll
    for (int mt = 0; mt < 4; ++mt)
#pragma unroll
      for (int nt = 0; nt < 4; ++nt) { f32x4 z = {}; acc[mt][nt] = z; }
    for (int k0 = 0; k0 < 128; k0 += 32) {
      bf16x8 a[4], b[4];
#pragma unroll
      for (int nt = 0; nt < 4; ++nt)
        b[nt] = *(const bf16x8*)(W + (size_t)(wnl + nt * 16 + lr) * 128 + k0 + lq * 8);
#pragma unroll
      for (int mt = 0; mt < 4; ++mt)
        a[mt] = *(const bf16x8*)(&Z[(mt * 16 + lr) * LDZ + k0 + lq * 8]);
#pragma unroll
      for (int mt = 0; mt < 4; ++mt)
#pragma unroll
        for (int nt = 0; nt < 4; ++nt)
          acc[mt][nt] = __builtin_amdgcn_mfma_f32_16x16x32_bf16(
              a[mt], b[nt], acc[mt][nt], 0, 0, 0);
    }
#pragma unroll
    for (int nt = 0; nt < 4; ++nt) {
      float bv = bb[wnl + nt * 16 + lr];
      int col = wcol + nt * 16 + lr;
#pragma unroll
      for (int mt = 0; mt < 4; ++mt)
#pragma unroll
        for (int r = 0; r < 4; ++r) {
          int row = mt * 16 + lq * 4 + r;
          float vv = acc[mt][nt][r] + bv;
          BufA[row * LDS_S + col] = (bf16_t)(vv > 0.f ? vv : 0.f);
        }
    }
  }
  __syncthreads();

  // ---- stage 4: yh = p1 @ pW2 + pb2 ; ev = a1 @ aW2 + ab2 ---------------
  if (t < 64) {
    float a4 = pb2[0];
    for (int k = 0; k < 128; ++k)
      a4 += (float)BufA[t * LDS_S + k] * pW2[k];
    out_yh[m0 + t] = a4;
  }
#pragma unroll
  for (int pass = 0; pass < 2; ++pass) {
    int j = pass * 256 + t;
    int r = j >> 3, n = j & 7;
    float a4 = ab2[n];
    for (int k = 0; k < 128; ++k)
      a4 += (float)BufA[r * LDS_S + 128 + k] * aW2[k * 8 + n];
    out_ev[(size_t)(m0 + r) * NE + n] = a4;
  }
}

extern "C" void kernel_launch(void* const* d_in, const int* in_sizes, int n_in,
                              void* d_out, int out_size, void* d_ws, size_t ws_size,
                              hipStream_t stream) {
  (void)in_sizes; (void)n_in; (void)out_size; (void)ws_size;
  const float* x        = (const float*)d_in[0];
  const int*   eidx     = (const int*)d_in[1];
  const float* eattr    = (const float*)d_in[2];
  const int*   batch    = (const int*)d_in[3];
  const float* node_W   = (const float*)d_in[4];
  const float* node_b   = (const float*)d_in[5];
  const float* conv_eps = (const float*)d_in[6];
  const float* edge_W   = (const float*)d_in[7];
  const float* edge_b   = (const float*)d_in[8];
  const float* mlp_W1   = (const float*)d_in[9];
  const float* mlp_b1   = (const float*)d_in[10];
  const float* mlp_W2   = (const float*)d_in[11];
  const float* mlp_b2   = (const float*)d_in[12];
  const float* gn_w     = (const float*)d_in[13];
  const float* gn_b     = (const float*)d_in[14];
  const float* gn_ms    = (const float*)d_in[15];
  const float* finv_W1  = (const float*)d_in[16];
  const float* finv_b1  = (const float*)d_in[17];
  const float* finv_W2  = (const float*)d_in[18];
  const float* finv_b2  = (const float*)d_in[19];
  const float* fspu_W1  = (const float*)d_in[20];
  const float* fspu_b1  = (const float*)d_in[21];
  const float* fspu_W2  = (const float*)d_in[22];
  const float* fspu_b2  = (const float*)d_in[23];
  const float* pred_W1  = (const float*)d_in[24];
  const float* pred_b1  = (const float*)d_in[25];
  const float* pred_W2  = (const float*)d_in[26];
  const float* pred_b2  = (const float*)d_in[27];
  const float* adv_W1   = (const float*)d_in[28];
  const float* adv_b1   = (const float*)d_in[29];
  const float* adv_W2   = (const float*)d_in[30];
  const float* adv_b2   = (const float*)d_in[31];
  float* out = (float*)d_out;

  float* out_hg = out;                                  // [G,H]
  float* out_zi = out + (size_t)N_GRAPH * H;            // [G,ZI]
  float* out_zs = out_zi + (size_t)N_GRAPH * ZIC;       // [G,ZS]
  float* out_yh = out_zs + (size_t)N_GRAPH * ZIC;       // [G]
  float* out_ev = out_yh + N_GRAPH;                     // [G,NE]

  // workspace carve-up (~118 MiB total)
  char* wp = (char*)d_ws;
  auto alloc = [&](size_t bytes) { char* p = wp; wp += (bytes + 255) & ~(size_t)255; return p; };
  bf16_t* A        = (bf16_t*)alloc((size_t)N_NODES * H * 2);   // h / t
  bf16_t* B        = (bf16_t*)alloc((size_t)N_NODES * H * 2);   // u / v
  bf16_t* Wt       = (bf16_t*)alloc((size_t)(H * ND + 6 * H * H) * 2);
  bf16_t* WtH      = (bf16_t*)alloc((size_t)(2 * ZIC * H + 4 * ZIC * ZIC) * 2);
  bf16_t* ewt16    = (bf16_t*)alloc((size_t)3 * 256 * 16 * 2);
  bf16_t* eat16    = (bf16_t*)alloc((size_t)N_EDGES * 16 * 2);
  int*    starts   = (int*)alloc((size_t)(N_GRAPH + 1) * 4);
  int*    counts   = (int*)alloc((size_t)N_NODES * 4);
  int*    cursor   = (int*)alloc((size_t)N_NODES * 4);
  int*    offs     = (int*)alloc((size_t)(N_NODES + 1) * 4);
  int*    bsum     = (int*)alloc((size_t)SCAN_B * 4);
  int*    src_srt  = (int*)alloc((size_t)N_EDGES * 4);

  const int* srcp = eidx;
  const int* dstp = eidx + N_EDGES;
  const int nscan = (N_NODES + SCAN_B - 1) / SCAN_B;

  compute_starts_kernel<<<(N_NODES + 255) / 256, 256, 0, stream>>>(
      batch, starts, counts, cursor, N_NODES, N_GRAPH);
  count_deg_kernel<<<(N_EDGES + 255) / 256, 256, 0, stream>>>(dstp, counts, N_EDGES, N_NODES);
  scan1_kernel<<<nscan, SCAN_B, 0, stream>>>(counts, offs, bsum, N_NODES);
  scan2_kernel<<<1, 64, 0, stream>>>(bsum, nscan);
  scan3_kernel<<<nscan, SCAN_B, 0, stream>>>(offs, bsum, N_NODES);
  fill_scatter_kernel<<<(N_EDGES + 255) / 256, 256, 0, stream>>>(
      srcp, dstp, eattr, offs, cursor, src_srt, eat16, N_EDGES, N_NODES);
  build_ewt16_kernel<<<(3 * 256 * 16 + 255) / 256, 256, 0, stream>>>(edge_W, ewt16);

  bf16_t* WtN = Wt;
  bf16_t* Wt1base = Wt + H * ND;                      // l-th at stride 2*H*H
  bf16_t* Wt2base = Wt + H * ND + (size_t)H * H;      // l-th at stride 2*H*H
  auto Wt1l = [&](int l) { return Wt1base + (size_t)(2 * l) * H * H; };
  auto Wt2l = [&](int l) { return Wt2base + (size_t)(2 * l) * H * H; };
  transpose_kernel<<<dim3(H / 32, ND / 32, 1), dim3(32, 8), 0, stream>>>(node_W, WtN, ND, H, 0, 0);
  transpose_mlp_kernel<<<dim3(H / 32, H / 32, 6), dim3(32, 8), 0, stream>>>(
      mlp_W1, mlp_W2, Wt1base, Wt2base);

  bf16_t* fT1 = WtH;                          // [128 x 256]
  bf16_t* fT2 = fT1 + ZIC * H;                // [128 x 128]
  bf16_t* sT1 = fT2 + ZIC * ZIC;              // [128 x 256]
  bf16_t* sT2 = sT1 + ZIC * H;                // [128 x 128]
  bf16_t* pT1 = sT2 + ZIC * ZIC;              // [128 x 128]
  bf16_t* aT1 = pT1 + ZIC * ZIC;              // [128 x 128]
  transpose_heads_kernel<<<dim3(ZIC / 32, H / 32, 6), dim3(32, 8), 0, stream>>>(
      finv_W1, fspu_W1, finv_W2, fspu_W2, pred_W1, adv_W1,
      fT1, sT1, fT2, sT2, pT1, aT1);

  const int mblocks = (N_NODES + 127) / 128;
  // h = x @ node_W + node_b (f32 input, full-H tile, reads x once)
  gemm_node_kernel<ND><<<mblocks, 512, 0, stream>>>(x, WtN, node_b, A, N_NODES);

  for (int l = 0; l < 3; ++l) {
    gine_gather_mfma_kernel<<<N_NODES / 4, 256, 0, stream>>>(
        A, eat16, src_srt, offs, ewt16 + (size_t)l * 256 * 16,
        edge_b + l * H, conv_eps + l, B);
    gemm256_dma_kernel<H, true ><<<mblocks, 512, 0, stream>>>(B, Wt1l(l), mlp_b1 + l * H, A, N_NODES);
    gemm256_dma_kernel<H, false><<<mblocks, 512, 0, stream>>>(A, Wt2l(l), mlp_b2 + l * H, B, N_NODES);
    graphnorm_kernel<<<N_GRAPH, 256, 0, stream>>>(B, A, starts, gn_w + l * H, gn_b + l * H,
                                                  gn_ms + l * H, (l == 2) ? out_hg : nullptr);
  }

  // all four head stages in one launch (row-local chain)
  heads_fused_kernel<<<N_GRAPH / 64, 256, 0, stream>>>(
      out_hg,
      fT1, finv_b1, fT2, finv_b2,
      sT1, fspu_b1, sT2, fspu_b2,
      pT1, pred_b1, aT1, adv_b1,
      pred_W2, pred_b2, adv_W2, adv_b2,
      out_zi, out_zs, out_yh, out_ev);
}